// Round 2
// baseline (7521.249 us; speedup 1.0000x reference)
//
#include <hip/hip_runtime.h>
#include <hip/hip_bf16.h>
#include <math.h>

typedef __hip_bfloat16 bf16;
typedef short v8s __attribute__((ext_vector_type(8)));
typedef float v4f __attribute__((ext_vector_type(4)));

#define NB   1024   // batch
#define NT   128    // encode steps
#define NDEC 64     // decode steps (incl. step 0 = last)
#define NH   128    // H
#define HE   256    // H_ENC
#define HD   132    // H_DEC
#define HDP  160    // padded K for decoder (5 * 32)
#define GDP  144    // padded per-gate col count for decoder (9 * 16)
#define NS   8      // elbo samples
#define SB   8192   // NS * NB
#define KX   32     // padded encoder input dim (2 + 16 -> 32)
#define EBLOCKS 208

namespace wsoff {
constexpr size_t al(size_t x){ return (x + 255) & ~size_t(255); }
constexpr size_t FLAG  = 0;
constexpr size_t BAR   = 128;   // two ints: arrive counter, generation
constexpr size_t XS    = 256;
constexpr size_t WIH0  = al(XS    + (size_t)NT*NB*KX*2);
constexpr size_t WHH0  = al(WIH0  + 768*32*2);
constexpr size_t WIH1  = al(WHH0  + 768*256*2);
constexpr size_t WHH1  = al(WIH1  + 768*256*2);
constexpr size_t BIH0  = al(WHH1  + 768*256*2);
constexpr size_t BHH0  = al(BIH0  + 768*4);
constexpr size_t BIH1  = al(BHH0  + 768*4);
constexpr size_t BHH1  = al(BIH1  + 768*4);
constexpr size_t WDHH0 = al(BHH1  + 768*4);
constexpr size_t WDIH1 = al(WDHH0 + 432*160*2);
constexpr size_t WDHH1 = al(WDIH1 + 432*160*2);
constexpr size_t WDIH0F= al(WDHH1 + 432*160*2);
constexpr size_t BDIH0 = al(WDIH0F+ 792*4);
constexpr size_t BDHH0 = al(BDIH0 + 396*4);
constexpr size_t BDIH1 = al(BDHH0 + 396*4);
constexpr size_t BDHH1 = al(BDIH1 + 396*4);
constexpr size_t W1B   = al(BDHH1 + 396*4);
constexpr size_t B1F   = al(W1B   + 64*128*2);
constexpr size_t W2F   = al(B1F   + 64*4);
constexpr size_t B2F   = al(W2F   + 128*4);
constexpr size_t H0F0  = al(B2F   + 2*4);
constexpr size_t H0F1  = al(H0F0  + (size_t)NB*HE*4);
constexpr size_t H0B0  = al(H0F1  + (size_t)NB*HE*4);
constexpr size_t H0B1  = al(H0B0  + (size_t)NB*HE*2);
constexpr size_t H1F0  = al(H0B1  + (size_t)NB*HE*2);
constexpr size_t H1F1  = al(H1F0  + (size_t)NB*HE*4);
constexpr size_t H1B0  = al(H1F1  + (size_t)NB*HE*4);
constexpr size_t H1B1  = al(H1B0  + (size_t)NB*HE*2);
constexpr size_t ENCP  = al(H1B1  + (size_t)NB*HE*2);        // fp32 [128][1024][2]
constexpr size_t DH0F0 = al(ENCP  + (size_t)NB*NT*2*4);
constexpr size_t DH0F1 = al(DH0F0 + (size_t)SB*HDP*4);
constexpr size_t DH0B0 = al(DH0F1 + (size_t)SB*HDP*4);
constexpr size_t DH0B1 = al(DH0B0 + (size_t)SB*HDP*2);
constexpr size_t DH1F0 = al(DH0B1 + (size_t)SB*HDP*2);
constexpr size_t DH1F1 = al(DH1F0 + (size_t)SB*HDP*4);
constexpr size_t DH1B0 = al(DH1F1 + (size_t)SB*HDP*4);
constexpr size_t DH1B1 = al(DH1B0 + (size_t)SB*HDP*2);
constexpr size_t INP   = al(DH1B1 + (size_t)SB*HDP*2);       // fp32 [SB][2]
}

// ---------- device helpers ----------
__device__ __forceinline__ float ld_any(const void* p, size_t i, int isbf){
  return isbf ? __bfloat162float(((const bf16*)p)[i]) : ((const float*)p)[i];
}
__device__ __forceinline__ float sigm(float x){ return 1.0f/(1.0f+expf(-x)); }
__device__ __forceinline__ float softplusf(float x){ return x>20.f ? x : log1pf(expf(x)); }
__device__ __forceinline__ v4f mfma16(v8s a, v8s b, v4f c){
  return __builtin_amdgcn_mfma_f32_16x16x32_bf16(a,b,c,0,0,0);
}
__device__ __forceinline__ v8s fragld(const bf16* base, size_t elem_off){
  return *reinterpret_cast<const v8s*>(base + elem_off);
}
__device__ __forceinline__ v8s ldsfrag(const short* sm, int unit, int lane){
  return *reinterpret_cast<const v8s*>(sm + (unit<<9) + (lane<<3));
}
__device__ __forceinline__ float*  f32p(char* ws, size_t off){ return (float*)(ws+off); }
__device__ __forceinline__ bf16*   bfp (char* ws, size_t off){ return (bf16*)(ws+off); }
__device__ __forceinline__ float*  H0Fp(char* ws,int p){ return f32p(ws, p?wsoff::H0F1:wsoff::H0F0); }
__device__ __forceinline__ bf16*   H0Bp(char* ws,int p){ return bfp (ws, p?wsoff::H0B1:wsoff::H0B0); }
__device__ __forceinline__ float*  H1Fp(char* ws,int p){ return f32p(ws, p?wsoff::H1F1:wsoff::H1F0); }
__device__ __forceinline__ bf16*   H1Bp(char* ws,int p){ return bfp (ws, p?wsoff::H1B1:wsoff::H1B0); }
__device__ __forceinline__ float*  DH0Fp(char* ws,int p){ return f32p(ws, p?wsoff::DH0F1:wsoff::DH0F0); }
__device__ __forceinline__ bf16*   DH0Bp(char* ws,int p){ return bfp (ws, p?wsoff::DH0B1:wsoff::DH0B0); }
__device__ __forceinline__ float*  DH1Fp(char* ws,int p){ return f32p(ws, p?wsoff::DH1F1:wsoff::DH1F0); }
__device__ __forceinline__ bf16*   DH1Bp(char* ws,int p){ return bfp (ws, p?wsoff::DH1B1:wsoff::DH1B0); }

// ---------- manual grid barrier (all EBLOCKS blocks co-resident: 208 <= 256 CUs) ----
__device__ __forceinline__ void grid_barrier(char* ws, int nblk, int& gen){
  __syncthreads();
  if (threadIdx.x == 0){
    __threadfence();   // flush this block's stores (agent scope; all waves drained by syncthreads)
    int* cnt = (int*)(ws + wsoff::BAR);
    int* gp  = (int*)(ws + wsoff::BAR + 4);
    if (__hip_atomic_fetch_add(cnt, 1, __ATOMIC_ACQ_REL, __HIP_MEMORY_SCOPE_AGENT) == nblk-1){
      __hip_atomic_store(cnt, 0, __ATOMIC_RELAXED, __HIP_MEMORY_SCOPE_AGENT);
      __hip_atomic_fetch_add(gp, 1, __ATOMIC_RELEASE, __HIP_MEMORY_SCOPE_AGENT);
    } else {
      while (__hip_atomic_load(gp, __ATOMIC_RELAXED, __HIP_MEMORY_SCOPE_AGENT) == gen){
        __builtin_amdgcn_s_sleep(2);
      }
    }
    gen++;
    __threadfence();   // acquire: invalidate stale cached lines for this CU
  }
  __syncthreads();
}

// ---------- dtype detection ----------
__global__ void k_detect(char* ws, const void* eps){
  const unsigned short* p = (const unsigned short*)eps;
  int lane = threadIdx.x;
  unsigned short u = p[2*lane];
  int e = (u>>7)&0xFF;
  bool pl = (e>=118 && e<=130);
  unsigned long long m = __ballot(pl);
  if (lane==0) *(int*)(ws+wsoff::FLAG) = (__popcll(m) >= 32) ? 1 : 0;
}

// ---------- staging ----------
__global__ void k_stage_xs(char* ws, const void* x, const void* feat){
  int isbf = *(const int*)(ws+wsoff::FLAG);
  size_t i = (size_t)blockIdx.x*blockDim.x + threadIdx.x;
  if (i >= (size_t)NT*NB*KX) return;
  int c = i % KX; size_t q = i / KX; int b = q % NB; int t = q / NB;
  float v = 0.f;
  if (c < 2)        v = ld_any(x,    ((size_t)b*NT + t)*2 + c, isbf);
  else if (c < 18)  v = ld_any(feat, ((size_t)b*192 + t)*16 + (c-2), isbf);
  ((bf16*)(ws+wsoff::XS))[i] = __float2bfloat16(v);
}
__global__ void k_stage_pad(char* ws, const void* src, size_t dstoff, int R, int SC, int DC){
  int isbf = *(const int*)(ws+wsoff::FLAG);
  size_t i = (size_t)blockIdx.x*blockDim.x + threadIdx.x;
  if (i >= (size_t)R*DC) return;
  int r = i / DC, c = i % DC;
  float v = (c < SC) ? ld_any(src, (size_t)r*SC + c, isbf) : 0.f;
  ((bf16*)(ws+dstoff))[i] = __float2bfloat16(v);
}
__global__ void k_stage_dec(char* ws, const void* src, size_t dstoff){
  int isbf = *(const int*)(ws+wsoff::FLAG);
  size_t i = (size_t)blockIdx.x*blockDim.x + threadIdx.x;
  if (i >= (size_t)432*HDP) return;
  int R = i / HDP, c = i % HDP;
  int g = R / GDP, ii = R % GDP;
  float v = (ii < HD && c < HD) ? ld_any(src, ((size_t)(g*HD+ii))*HD + c, isbf) : 0.f;
  ((bf16*)(ws+dstoff))[i] = __float2bfloat16(v);
}
struct SmallSegs { const void* src[12]; int dstoff[12]; int n[12]; };
__global__ void k_stage_small(char* ws, SmallSegs segs){
  int isbf = *(const int*)(ws+wsoff::FLAG);
  int s = blockIdx.x;
  float* dst = (float*)(ws + (size_t)segs.dstoff[s]);
  for (int i = threadIdx.x; i < segs.n[s]; i += blockDim.x)
    dst[i] = ld_any(segs.src[s], i, isbf);
}

// ================= persistent encoder =================
// blocks 0..63: layer0 (rb=bid>>3 rows rb*128, cb=bid&7 dims cb*32)
// blocks 64..191: layer1 (rb=(bid-64)>>4, cb=(bid-64)&15 dims cb*16)
// blocks 192..207: mlp (rows (bid-192)*64)
__global__ __launch_bounds__(256,1) void k_encoder(char* ws, const int* mask){
  __shared__ __align__(16) short smem[27648];   // 54 KB max (layer0)
  const int bid = blockIdx.x, tid = threadIdx.x;
  const int lane = tid & 63, w = tid >> 6, lr = lane & 15, q = lane >> 4;
  int gen = 0;

  if (bid < 64){
    // ---- LAYER0 ----
    const int rb = bid >> 3, cb = bid & 7;
    const short* WH = (const short*)(ws + wsoff::WHH0);
    const short* WI = (const short*)(ws + wsoff::WIH0);
    for (int idx = tid; idx < 54*512; idx += 256){
      int u = idx >> 9, le = idx & 511;
      int ln = le >> 3, e = le & 7, qq = ln >> 4, lrr = ln & 15;
      short v;
      if (u < 48){
        int g = u >> 4, rem = u & 15, c = rem >> 3, kb = rem & 7;
        v = WH[(size_t)(g*HE + cb*32 + c*16 + lrr)*256 + kb*32 + qq*8 + e];
      } else {
        int u2 = u - 48; int g = u2 >> 1, c = u2 & 1;
        v = WI[(size_t)(g*HE + cb*32 + c*16 + lrr)*32 + qq*8 + e];
      }
      smem[idx] = v;
    }
    __syncthreads();
    const float* bih = f32p(ws,wsoff::BIH0);
    const float* bhh = f32p(ws,wsoff::BHH0);
    const int rowbase = rb*128 + w*32;
    for (int t = 0; t <= 129; ++t){
      if (t <= 127){
        const bf16* Xs = bfp(ws,wsoff::XS) + (size_t)t*NB*KX;
        const bf16* Aold = H0Bp(ws, t&1);
        const float* hfOld = H0Fp(ws, t&1);
        float* hfNew = H0Fp(ws,(t+1)&1);
        bf16* hbNew = H0Bp(ws,(t+1)&1);
        v4f ax[3][2][2], ah[3][2][2];
        #pragma unroll
        for (int g=0;g<3;g++)
          #pragma unroll
          for (int c=0;c<2;c++)
            #pragma unroll
            for (int rt=0;rt<2;rt++){ ax[g][c][rt]=(v4f){0,0,0,0}; ah[g][c][rt]=(v4f){0,0,0,0}; }
        { // input K=32
          v8s a0 = fragld(Xs, (size_t)(rowbase+lr)*KX + q*8);
          v8s a1 = fragld(Xs, (size_t)(rowbase+16+lr)*KX + q*8);
          #pragma unroll
          for (int g=0;g<3;g++)
            #pragma unroll
            for (int c=0;c<2;c++){
              v8s b = ldsfrag(smem, 48 + g*2 + c, lane);
              ax[g][c][0] = mfma16(a0,b,ax[g][c][0]);
              ax[g][c][1] = mfma16(a1,b,ax[g][c][1]);
            }
        }
        #pragma unroll
        for (int kb=0;kb<8;kb++){
          v8s a0 = fragld(Aold, (size_t)(rowbase+lr)*HE + kb*32 + q*8);
          v8s a1 = fragld(Aold, (size_t)(rowbase+16+lr)*HE + kb*32 + q*8);
          #pragma unroll
          for (int g=0;g<3;g++)
            #pragma unroll
            for (int c=0;c<2;c++){
              v8s b = ldsfrag(smem, (g*2+c)*8 + kb, lane);
              ah[g][c][0] = mfma16(a0,b,ah[g][c][0]);
              ah[g][c][1] = mfma16(a1,b,ah[g][c][1]);
            }
        }
        #pragma unroll
        for (int c=0;c<2;c++){
          const int d = cb*32 + c*16 + lr;
          const float bir = bih[d]+bhh[d];
          const float biz = bih[HE+d]+bhh[HE+d];
          const float bin = bih[2*HE+d];
          const float bhn = bhh[2*HE+d];
          #pragma unroll
          for (int rt=0;rt<2;rt++){
            #pragma unroll
            for (int r=0;r<4;r++){
              const int row = rowbase + rt*16 + q*4 + r;
              float rr = sigm(ax[0][c][rt][r]+ah[0][c][rt][r]+bir);
              float zz = sigm(ax[1][c][rt][r]+ah[1][c][rt][r]+biz);
              float nn = tanhf(ax[2][c][rt][r]+bin + rr*(ah[2][c][rt][r]+bhn));
              float ho = hfOld[(size_t)row*HE + d];
              float hv = (1.f-zz)*nn + zz*ho;
              float hout = mask[(size_t)row*NT + t] ? hv : ho;
              hfNew[(size_t)row*HE+d] = hout;
              hbNew[(size_t)row*HE+d] = __float2bfloat16(hout);
            }
          }
        }
      }
      grid_barrier(ws, EBLOCKS, gen);
    }
  } else if (bid < 192){
    // ---- LAYER1 ----
    const int idx0 = bid - 64;
    const int rb = idx0 >> 4, cb = idx0 & 15;
    const short* WX = (const short*)(ws + wsoff::WIH1);
    const short* WHs = (const short*)(ws + wsoff::WHH1);
    for (int idx = tid; idx < 48*512; idx += 256){
      int u = idx >> 9, le = idx & 511;
      int ln = le >> 3, e = le & 7, qq = ln >> 4, lrr = ln & 15;
      int u2 = (u < 24) ? u : (u - 24);
      int g = u2 >> 3, kb = u2 & 7;
      const short* S = (u < 24) ? WX : WHs;
      smem[idx] = S[(size_t)(g*HE + cb*16 + lrr)*256 + kb*32 + qq*8 + e];
    }
    __syncthreads();
    const float* bih = f32p(ws,wsoff::BIH1);
    const float* bhh = f32p(ws,wsoff::BHH1);
    const int rowbase = rb*128 + w*32;
    for (int t = 0; t <= 129; ++t){
      if (t >= 1 && t <= 128){
        const int s = t-1;
        const bf16* Ax = H0Bp(ws, t&1);
        const bf16* Ah = H1Bp(ws, s&1);
        const float* hfOld = H1Fp(ws, s&1);
        float* hfNew = H1Fp(ws, t&1);
        bf16* hbNew = H1Bp(ws, t&1);
        v4f ax[3][2], ah[3][2];
        #pragma unroll
        for (int g=0;g<3;g++)
          #pragma unroll
          for (int rt=0;rt<2;rt++){ ax[g][rt]=(v4f){0,0,0,0}; ah[g][rt]=(v4f){0,0,0,0}; }
        #pragma unroll
        for (int kb=0;kb<8;kb++){
          v8s x0 = fragld(Ax, (size_t)(rowbase+lr)*HE + kb*32 + q*8);
          v8s x1 = fragld(Ax, (size_t)(rowbase+16+lr)*HE + kb*32 + q*8);
          v8s h0 = fragld(Ah, (size_t)(rowbase+lr)*HE + kb*32 + q*8);
          v8s h1 = fragld(Ah, (size_t)(rowbase+16+lr)*HE + kb*32 + q*8);
          #pragma unroll
          for (int g=0;g<3;g++){
            v8s bx = ldsfrag(smem, g*8 + kb, lane);
            v8s bh = ldsfrag(smem, 24 + g*8 + kb, lane);
            ax[g][0] = mfma16(x0,bx,ax[g][0]);
            ax[g][1] = mfma16(x1,bx,ax[g][1]);
            ah[g][0] = mfma16(h0,bh,ah[g][0]);
            ah[g][1] = mfma16(h1,bh,ah[g][1]);
          }
        }
        const int d = cb*16 + lr;
        const float bir = bih[d]+bhh[d];
        const float biz = bih[HE+d]+bhh[HE+d];
        const float bin = bih[2*HE+d];
        const float bhn = bhh[2*HE+d];
        #pragma unroll
        for (int rt=0;rt<2;rt++){
          #pragma unroll
          for (int r=0;r<4;r++){
            const int row = rowbase + rt*16 + q*4 + r;
            float rr = sigm(ax[0][rt][r]+ah[0][rt][r]+bir);
            float zz = sigm(ax[1][rt][r]+ah[1][rt][r]+biz);
            float nn = tanhf(ax[2][rt][r]+bin + rr*(ah[2][rt][r]+bhn));
            float ho = hfOld[(size_t)row*HE + d];
            float hv = (1.f-zz)*nn + zz*ho;
            float hout = mask[(size_t)row*NT + s] ? hv : ho;
            hfNew[(size_t)row*HE+d] = hout;
            hbNew[(size_t)row*HE+d] = __float2bfloat16(hout);
          }
        }
      }
      grid_barrier(ws, EBLOCKS, gen);
    }
  } else {
    // ---- MLP ----
    const int mb = bid - 192;
    const short* W1s = (const short*)(ws + wsoff::W1B);
    for (int idx = tid; idx < 16*512; idx += 256){
      int u = idx >> 9, le = idx & 511;
      int ln = le >> 3, e = le & 7, qq = ln >> 4, lrr = ln & 15;
      int c = u >> 2, kb = u & 3;
      smem[idx] = W1s[(size_t)(c*16 + lrr)*NH + kb*32 + qq*8 + e];
    }
    __syncthreads();
    float b1v[4], w20[4], w21[4];
    const float* B1 = f32p(ws,wsoff::B1F);
    const float* W2 = f32p(ws,wsoff::W2F);
    const float* B2 = f32p(ws,wsoff::B2F);
    #pragma unroll
    for (int c=0;c<4;c++){ int col=c*16+lr; b1v[c]=B1[col]; w20[c]=W2[col]; w21[c]=W2[64+col]; }
    const float b20 = B2[0], b21 = B2[1];
    const int rowbase = mb*64 + w*16;
    const int rowA = rowbase + lr;
    for (int t = 0; t <= 129; ++t){
      if (t >= 2){
        const int s = t-2;
        const bf16* A = H1Bp(ws, (t-1)&1);
        const bool valid = mask[(size_t)rowA*NT + s] != 0;
        v4f acc[4];
        #pragma unroll
        for (int c=0;c<4;c++) acc[c]=(v4f){0,0,0,0};
        #pragma unroll
        for (int kb=0;kb<4;kb++){
          v8s a = valid ? fragld(A, (size_t)rowA*HE + kb*32 + q*8) : (v8s){0,0,0,0,0,0,0,0};
          #pragma unroll
          for (int c=0;c<4;c++){
            v8s b = ldsfrag(smem, c*4 + kb, lane);
            acc[c] = mfma16(a,b,acc[c]);
          }
        }
        float* outp = f32p(ws,wsoff::ENCP) + (size_t)s*NB*2;
        #pragma unroll
        for (int r=0;r<4;r++){
          float p0 = 0.f, p1 = 0.f;
          #pragma unroll
          for (int c=0;c<4;c++){
            float hvv = acc[c][r] + b1v[c]; hvv = hvv > 0.f ? hvv : 0.f;
            p0 += hvv*w20[c]; p1 += hvv*w21[c];
          }
          #pragma unroll
          for (int m=1;m<16;m<<=1){ p0 += __shfl_xor(p0,m,64); p1 += __shfl_xor(p1,m,64); }
          if (lr == 0){
            const int grow = rowbase + q*4 + r;
            outp[(size_t)grow*2]   = softplusf(p0+b20);
            outp[(size_t)grow*2+1] = softplusf(p1+b21);
          }
        }
      }
      grid_barrier(ws, EBLOCKS, gen);
    }
  }
}

// ================= decoder: row-parallel, no grid sync =================
__global__ __launch_bounds__(256,1) void k_decoder(char* ws, const void* eps, const void* feat, void* out){
  const int isbf = *(const int*)(ws+wsoff::FLAG);
  const int bid = blockIdx.x, tid = threadIdx.x;
  const int lane = tid & 63, w = tid >> 6, lr = lane & 15, q = lane >> 4;
  const int rowbase = bid*32;
  constexpr size_t N0v = (size_t)NS*NB*127*2;

  // init z / fc / inp / out[k=0]
  for (int idx = tid; idx < 32*160*2; idx += 256){
    int l = idx >= 32*160 ? 1 : 0; int rem = idx - l*32*160;
    int r0 = rem / 160, d = rem % 160;
    int sb = rowbase + r0, s = sb >> 10, b = sb & 1023;
    const float* hT = f32p(ws, l ? wsoff::H1F0 : wsoff::H0F0);
    float v = 0.f;
    if (d < NH){
      float mean = hT[(size_t)b*HE + d], lv = hT[(size_t)b*HE + NH + d];
      float e = ld_any(eps, ((size_t)(s*2+l)*NB + b)*NH + d, isbf);
      v = e*expf(0.5f*lv) + mean;
    } else if (d < HD){
      v = ld_any(feat, (size_t)b*3072 + 2048 + (d-NH), isbf);
    }
    f32p(ws, l?wsoff::DH1F0:wsoff::DH0F0)[(size_t)sb*HDP + d] = v;
    bfp (ws, l?wsoff::DH1B0:wsoff::DH0B0)[(size_t)sb*HDP + d] = __float2bfloat16(v);
  }
  for (int idx = tid; idx < 64; idx += 256){
    int r0 = idx >> 1, c = idx & 1;
    int sb = rowbase + r0, b = sb & 1023;
    float v = f32p(ws,wsoff::ENCP)[((size_t)127*NB + b)*2 + c];
    f32p(ws,wsoff::INP)[(size_t)sb*2 + c] = v;
    size_t oo = N0v + ((size_t)sb*64)*2 + c;
    if (isbf) ((bf16*)out)[oo] = __float2bfloat16(v); else ((float*)out)[oo] = v;
  }
  __threadfence_block(); __syncthreads();

  const bf16* W0  = bfp(ws,wsoff::WDHH0);
  const bf16* WX1 = bfp(ws,wsoff::WDIH1);
  const bf16* WH1 = bfp(ws,wsoff::WDHH1);
  const float* WIH = f32p(ws,wsoff::WDIH0F);
  const float* bi0 = f32p(ws,wsoff::BDIH0);
  const float* bh0 = f32p(ws,wsoff::BDHH0);
  const float* bi1 = f32p(ws,wsoff::BDIH1);
  const float* bh1 = f32p(ws,wsoff::BDHH1);
  float* inp = f32p(ws,wsoff::INP);
  const bf16* W1g = bfp(ws,wsoff::W1B);
  float b1v[4], w20[4], w21[4];
  { const float* B1 = f32p(ws,wsoff::B1F); const float* W2 = f32p(ws,wsoff::W2F);
    #pragma unroll
    for (int c=0;c<4;c++){ int col=c*16+lr; b1v[c]=B1[col]; w20[c]=W2[col]; w21[c]=W2[64+col]; } }
  const float b20 = f32p(ws,wsoff::B2F)[0], b21 = f32p(ws,wsoff::B2F)[1];

  for (int k = 0; k < 63; ++k){
    { // ---- d0 ----
      const bf16* Ah = DH0Bp(ws, k&1);
      const float* hfOld = DH0Fp(ws, k&1);
      float* hfNew = DH0Fp(ws,(k+1)&1);
      bf16* hbNew = DH0Bp(ws,(k+1)&1);
      for (int cc = w; cc < 9; cc += 4){
        v4f acc[3][2];
        #pragma unroll
        for (int g=0;g<3;g++){ acc[g][0]=(v4f){0,0,0,0}; acc[g][1]=(v4f){0,0,0,0}; }
        #pragma unroll
        for (int kb=0;kb<5;kb++){
          v8s a0 = fragld(Ah, (size_t)(rowbase+lr)*HDP + kb*32 + q*8);
          v8s a1 = fragld(Ah, (size_t)(rowbase+16+lr)*HDP + kb*32 + q*8);
          #pragma unroll
          for (int g=0;g<3;g++){
            v8s b = fragld(W0, (size_t)(g*GDP + cc*16 + lr)*HDP + kb*32 + q*8);
            acc[g][0] = mfma16(a0,b,acc[g][0]);
            acc[g][1] = mfma16(a1,b,acc[g][1]);
          }
        }
        const int d = cc*16 + lr;
        if (d < HD){
          const float wr0=WIH[(0*HD+d)*2], wr1=WIH[(0*HD+d)*2+1];
          const float wz0=WIH[(1*HD+d)*2], wz1=WIH[(1*HD+d)*2+1];
          const float wn0=WIH[(2*HD+d)*2], wn1=WIH[(2*HD+d)*2+1];
          const float bir=bi0[d], bhr=bh0[d], biz=bi0[HD+d], bhz=bh0[HD+d], bin=bi0[2*HD+d], bhn=bh0[2*HD+d];
          #pragma unroll
          for (int rt=0;rt<2;rt++){
            #pragma unroll
            for (int r=0;r<4;r++){
              const int row = rowbase + rt*16 + q*4 + r;
              const float i0 = inp[(size_t)row*2], i1 = inp[(size_t)row*2+1];
              float rr = sigm(i0*wr0+i1*wr1+bir + acc[0][rt][r] + bhr);
              float zz = sigm(i0*wz0+i1*wz1+biz + acc[1][rt][r] + bhz);
              float nn = tanhf(i0*wn0+i1*wn1+bin + rr*(acc[2][rt][r]+bhn));
              float ho = hfOld[(size_t)row*HDP + d];
              float hv = (1.f-zz)*nn + zz*ho;
              hfNew[(size_t)row*HDP+d] = hv;
              hbNew[(size_t)row*HDP+d] = __float2bfloat16(hv);
            }
          }
        }
      }
    }
    __threadfence_block(); __syncthreads();
    { // ---- d1 ----
      const bf16* Ax = DH0Bp(ws,(k+1)&1);
      const bf16* Ah = DH1Bp(ws, k&1);
      const float* hfOld = DH1Fp(ws, k&1);
      float* hfNew = DH1Fp(ws,(k+1)&1);
      bf16* hbNew = DH1Bp(ws,(k+1)&1);
      for (int cc = w; cc < 9; cc += 4){
        v4f ax[3][2], ah[3][2];
        #pragma unroll
        for (int g=0;g<3;g++){ ax[g][0]=(v4f){0,0,0,0}; ax[g][1]=(v4f){0,0,0,0};
                               ah[g][0]=(v4f){0,0,0,0}; ah[g][1]=(v4f){0,0,0,0}; }
        #pragma unroll
        for (int kb=0;kb<5;kb++){
          v8s x0 = fragld(Ax, (size_t)(rowbase+lr)*HDP + kb*32 + q*8);
          v8s x1 = fragld(Ax, (size_t)(rowbase+16+lr)*HDP + kb*32 + q*8);
          v8s h0 = fragld(Ah, (size_t)(rowbase+lr)*HDP + kb*32 + q*8);
          v8s h1 = fragld(Ah, (size_t)(rowbase+16+lr)*HDP + kb*32 + q*8);
          #pragma unroll
          for (int g=0;g<3;g++){
            const size_t wr = (size_t)(g*GDP + cc*16 + lr)*HDP + kb*32 + q*8;
            v8s bx = fragld(WX1, wr);
            v8s bh = fragld(WH1, wr);
            ax[g][0] = mfma16(x0,bx,ax[g][0]);
            ax[g][1] = mfma16(x1,bx,ax[g][1]);
            ah[g][0] = mfma16(h0,bh,ah[g][0]);
            ah[g][1] = mfma16(h1,bh,ah[g][1]);
          }
        }
        const int d = cc*16 + lr;
        if (d < HD){
          const float bir=bi1[d]+bh1[d], biz=bi1[HD+d]+bh1[HD+d], bin=bi1[2*HD+d], bhn=bh1[2*HD+d];
          #pragma unroll
          for (int rt=0;rt<2;rt++){
            #pragma unroll
            for (int r=0;r<4;r++){
              const int row = rowbase + rt*16 + q*4 + r;
              float rr = sigm(ax[0][rt][r]+ah[0][rt][r]+bir);
              float zz = sigm(ax[1][rt][r]+ah[1][rt][r]+biz);
              float nn = tanhf(ax[2][rt][r]+bin + rr*(ah[2][rt][r]+bhn));
              float ho = hfOld[(size_t)row*HDP + d];
              float hv = (1.f-zz)*nn + zz*ho;
              hfNew[(size_t)row*HDP+d] = hv;
              hbNew[(size_t)row*HDP+d] = __float2bfloat16(hv);
            }
          }
        }
      }
    }
    __threadfence_block(); __syncthreads();
    if (w < 2){ // ---- mlp (waves 0,1 cover 32 rows) ----
      const bf16* A = DH1Bp(ws,(k+1)&1);
      const int rb2 = rowbase + w*16;
      const int rowA = rb2 + lr;
      v4f acc[4];
      #pragma unroll
      for (int c=0;c<4;c++) acc[c]=(v4f){0,0,0,0};
      #pragma unroll
      for (int kb=0;kb<4;kb++){
        v8s a = fragld(A, (size_t)rowA*HDP + kb*32 + q*8);
        #pragma unroll
        for (int c=0;c<4;c++){
          v8s b = fragld(W1g, (size_t)(c*16+lr)*NH + kb*32 + q*8);
          acc[c] = mfma16(a,b,acc[c]);
        }
      }
      #pragma unroll
      for (int r=0;r<4;r++){
        float p0 = 0.f, p1 = 0.f;
        #pragma unroll
        for (int c=0;c<4;c++){
          float hvv = acc[c][r] + b1v[c]; hvv = hvv > 0.f ? hvv : 0.f;
          p0 += hvv*w20[c]; p1 += hvv*w21[c];
        }
        #pragma unroll
        for (int m=1;m<16;m<<=1){ p0 += __shfl_xor(p0,m,64); p1 += __shfl_xor(p1,m,64); }
        if (lr == 0){
          const int row = rb2 + q*4 + r;
          float s0 = softplusf(p0+b20), s1 = softplusf(p1+b21);
          inp[(size_t)row*2]   = s0;
          inp[(size_t)row*2+1] = s1;
          size_t oo = N0v + ((size_t)row*64 + (k+1))*2;
          if (isbf){ ((bf16*)out)[oo] = __float2bfloat16(s0); ((bf16*)out)[oo+1] = __float2bfloat16(s1); }
          else     { ((float*)out)[oo] = s0; ((float*)out)[oo+1] = s1; }
        }
      }
    }
    __threadfence_block(); __syncthreads();
  }
}

// ---------- encoder-part output assembly ----------
__global__ void k_assemble_enc(char* ws, void* out){
  int isbf = *(const int*)(ws+wsoff::FLAG);
  const float* encp = f32p(ws,wsoff::ENCP);
  constexpr size_t N0v = (size_t)NS*NB*127*2;
  for (size_t i = (size_t)blockIdx.x*blockDim.x + threadIdx.x; i < N0v;
       i += (size_t)gridDim.x*blockDim.x){
    int c = (int)(i & 1); size_t qq = i >> 1;
    int tt = (int)(qq % 127); size_t q2 = qq / 127; int b = (int)(q2 & 1023);
    float v = encp[((size_t)tt*NB + b)*2 + c];
    if (isbf) ((bf16*)out)[i] = __float2bfloat16(v);
    else      ((float*)out)[i] = v;
  }
}

extern "C" void kernel_launch(void* const* d_in, const int* in_sizes, int n_in,
                              void* d_out, int out_size, void* d_ws, size_t ws_size,
                              hipStream_t stream) {
  char* ws = (char*)d_ws;
  const int* mask = (const int*)d_in[2];
  auto gb = [](size_t n){ return dim3((unsigned)((n + 255)/256)); };

  // zero initial state + barrier state (ws is re-poisoned before every call)
  hipMemsetAsync(ws+wsoff::BAR,  0, 8, stream);
  hipMemsetAsync(ws+wsoff::H0F0, 0, (size_t)NB*HE*4, stream);
  hipMemsetAsync(ws+wsoff::H0B0, 0, (size_t)NB*HE*2, stream);
  hipMemsetAsync(ws+wsoff::H1F0, 0, (size_t)NB*HE*4, stream);
  hipMemsetAsync(ws+wsoff::H1B0, 0, (size_t)NB*HE*2, stream);
  hipMemsetAsync(ws+wsoff::DH0B1, 0, (size_t)SB*HDP*2, stream);  // keep K-pad zero
  hipMemsetAsync(ws+wsoff::DH1B1, 0, (size_t)SB*HDP*2, stream);

  k_detect<<<1,64,0,stream>>>(ws, d_in[3]);

  k_stage_xs <<<gb((size_t)NT*NB*KX),256,0,stream>>>(ws, d_in[0], d_in[1]);
  k_stage_pad<<<gb(768*32) ,256,0,stream>>>(ws, d_in[7],  wsoff::WIH0, 768, 18, 32);
  k_stage_pad<<<gb(768*256),256,0,stream>>>(ws, d_in[8],  wsoff::WHH0, 768, 256, 256);
  k_stage_pad<<<gb(768*256),256,0,stream>>>(ws, d_in[11], wsoff::WIH1, 768, 256, 256);
  k_stage_pad<<<gb(768*256),256,0,stream>>>(ws, d_in[12], wsoff::WHH1, 768, 256, 256);
  k_stage_pad<<<gb(64*128) ,256,0,stream>>>(ws, d_in[23], wsoff::W1B,  64, 128, 128);
  k_stage_dec<<<gb(432*160),256,0,stream>>>(ws, d_in[16], wsoff::WDHH0);
  k_stage_dec<<<gb(432*160),256,0,stream>>>(ws, d_in[19], wsoff::WDIH1);
  k_stage_dec<<<gb(432*160),256,0,stream>>>(ws, d_in[20], wsoff::WDHH1);

  SmallSegs ss;
  const void* srcs[12] = {d_in[9],d_in[10],d_in[13],d_in[14],d_in[15],
                          d_in[17],d_in[18],d_in[21],d_in[22],
                          d_in[24],d_in[25],d_in[26]};
  const size_t offs[12] = {wsoff::BIH0,wsoff::BHH0,wsoff::BIH1,wsoff::BHH1,wsoff::WDIH0F,
                           wsoff::BDIH0,wsoff::BDHH0,wsoff::BDIH1,wsoff::BDHH1,
                           wsoff::B1F,wsoff::W2F,wsoff::B2F};
  const int ns[12] = {768,768,768,768,792,396,396,396,396,64,128,2};
  for (int i=0;i<12;i++){ ss.src[i]=srcs[i]; ss.dstoff[i]=(int)offs[i]; ss.n[i]=ns[i]; }
  k_stage_small<<<12,256,0,stream>>>(ws, ss);

  // persistent encoder: 208 blocks (<= 256 CUs, 54KB LDS, 4 waves) -> all co-resident
  k_encoder<<<EBLOCKS,256,0,stream>>>(ws, mask);

  // decoder: row-parallel, no grid sync needed
  k_decoder<<<256,256,0,stream>>>(ws, d_in[3], d_in[1], d_out);

  k_assemble_enc<<<2048,256,0,stream>>>(ws, d_out);
}

// Round 3
// 5597.811 us; speedup vs baseline: 1.3436x; 1.3436x over previous
//
#include <hip/hip_runtime.h>
#include <hip/hip_bf16.h>
#include <math.h>

typedef __hip_bfloat16 bf16;
typedef short v8s __attribute__((ext_vector_type(8)));
typedef float v4f __attribute__((ext_vector_type(4)));

#define NB   1024
#define NT   128
#define NH   128
#define HE   256
#define HD   132
#define HDP  160    // padded K for decoder weights (global)
#define HDS  164    // LDS row stride (elems) for decoder bf16 state
#define GDP  144
#define NS   8
#define SB   8192
#define KX   32
#define EBLOCKS 112

namespace wsoff {
constexpr size_t al(size_t x){ return (x + 255) & ~size_t(255); }
constexpr size_t FLAG  = 0;
constexpr size_t BAR   = 256;    // slots[112] ints; bcast at BAR+512
constexpr size_t XS    = 2048;
constexpr size_t WIH0  = al(XS    + (size_t)NT*NB*KX*2);
constexpr size_t WHH0  = al(WIH0  + 768*32*2);
constexpr size_t WIH1  = al(WHH0  + 768*256*2);
constexpr size_t WHH1  = al(WIH1  + 768*256*2);
constexpr size_t BIH0  = al(WHH1  + 768*256*2);
constexpr size_t BHH0  = al(BIH0  + 768*4);
constexpr size_t BIH1  = al(BHH0  + 768*4);
constexpr size_t BHH1  = al(BIH1  + 768*4);
constexpr size_t WDHH0 = al(BHH1  + 768*4);
constexpr size_t WDIH1 = al(WDHH0 + 432*HDP*2);
constexpr size_t WDHH1 = al(WDIH1 + 432*HDP*2);
constexpr size_t WDIH0F= al(WDHH1 + 432*HDP*2);
constexpr size_t BDIH0 = al(WDIH0F+ 792*4);
constexpr size_t BDHH0 = al(BDIH0 + 396*4);
constexpr size_t BDIH1 = al(BDHH0 + 396*4);
constexpr size_t BDHH1 = al(BDIH1 + 396*4);
constexpr size_t W1B   = al(BDHH1 + 396*4);
constexpr size_t B1F   = al(W1B   + 64*128*2);
constexpr size_t W2F   = al(B1F   + 64*4);
constexpr size_t B2F   = al(W2F   + 128*4);
constexpr size_t H0F0  = al(B2F   + 2*4);     // final h0 fp32 [NB][HE]
constexpr size_t H1F0  = al(H0F0  + (size_t)NB*HE*4);
constexpr size_t H0B0  = al(H1F0  + (size_t)NB*HE*4);
constexpr size_t H0B1  = al(H0B0  + (size_t)NB*HE*2);
constexpr size_t H1B0  = al(H0B1  + (size_t)NB*HE*2);
constexpr size_t H1B1  = al(H1B0  + (size_t)NB*HE*2);
constexpr size_t ENCP  = al(H1B1  + (size_t)NB*HE*2);   // fp32 [128][1024][2]
}

// ---------- helpers ----------
__device__ __forceinline__ float ld_any(const void* p, size_t i, int isbf){
  return isbf ? __bfloat162float(((const bf16*)p)[i]) : ((const float*)p)[i];
}
__device__ __forceinline__ void st_out(void* out, size_t i, float v, int isbf){
  if (isbf) ((bf16*)out)[i] = __float2bfloat16(v); else ((float*)out)[i] = v;
}
__device__ __forceinline__ float sigm(float x){ return 1.0f/(1.0f + __expf(-x)); }
__device__ __forceinline__ float tanh_f(float x){
  float t = __expf(2.0f*x); return 1.0f - 2.0f/(t+1.0f);
}
__device__ __forceinline__ float softplusf(float x){ return x>20.f ? x : log1pf(__expf(x)); }
__device__ __forceinline__ v4f mfma16(v8s a, v8s b, v4f c){
  return __builtin_amdgcn_mfma_f32_16x16x32_bf16(a,b,c,0,0,0);
}
__device__ __forceinline__ v8s fragld(const bf16* base, size_t elem_off){
  return *reinterpret_cast<const v8s*>(base + elem_off);
}
__device__ __forceinline__ v8s ldsfrag(const short* sm, int unit, int lane){
  return *reinterpret_cast<const v8s*>(sm + (unit<<9) + (lane<<3));
}
__device__ __forceinline__ v8s lds_frag8(const short* p){   // 8B-aligned LDS frag
  union { long long l[2]; v8s s; } r;
  r.l[0] = *(const long long*)(p);
  r.l[1] = *(const long long*)(p + 4);
  return r.s;
}
// coherent (agent-scope, relaxed) 16B load: 4x dword sc1
__device__ __forceinline__ v8s ldg_coh16(const bf16* p){
  union { unsigned u[4]; v8s s; } r;
  const unsigned* q = (const unsigned*)p;
  r.u[0] = __hip_atomic_load(q+0, __ATOMIC_RELAXED, __HIP_MEMORY_SCOPE_AGENT);
  r.u[1] = __hip_atomic_load(q+1, __ATOMIC_RELAXED, __HIP_MEMORY_SCOPE_AGENT);
  r.u[2] = __hip_atomic_load(q+2, __ATOMIC_RELAXED, __HIP_MEMORY_SCOPE_AGENT);
  r.u[3] = __hip_atomic_load(q+3, __ATOMIC_RELAXED, __HIP_MEMORY_SCOPE_AGENT);
  return r.s;
}
// coherent paired bf16 store: lanes (even,odd) in lr pair up to one dword
__device__ __forceinline__ void stg_coh_pair(bf16* base_even, int lr, float v){
  bf16 h = __float2bfloat16(v);
  unsigned vv; { unsigned short b; __builtin_memcpy(&b, &h, 2); vv = b; }
  unsigned ov = (unsigned)__shfl_xor((int)vv, 1, 64);
  if (!(lr & 1))
    __hip_atomic_store((unsigned*)base_even, vv | (ov<<16), __ATOMIC_RELAXED, __HIP_MEMORY_SCOPE_AGENT);
}
__device__ __forceinline__ float*  f32p(char* ws, size_t off){ return (float*)(ws+off); }
__device__ __forceinline__ bf16*   bfp (char* ws, size_t off){ return (bf16*)(ws+off); }
__device__ __forceinline__ bf16*   H0Bp(char* ws,int p){ return bfp (ws, p?wsoff::H0B1:wsoff::H0B0); }
__device__ __forceinline__ bf16*   H1Bp(char* ws,int p){ return bfp (ws, p?wsoff::H1B1:wsoff::H1B0); }

// ---------- grid barrier: slot stores + collector + broadcast, no cache fences ----
__device__ __forceinline__ void gbar(char* ws, int gen){
  __syncthreads();   // drains each wave's vmem (incl. sc1 state stores) before barrier
  int* slots = (int*)(ws + wsoff::BAR);
  int* bcast = (int*)(ws + wsoff::BAR + 512);
  if (blockIdx.x == 0){
    if (threadIdx.x > 0 && threadIdx.x < EBLOCKS){
      while (__hip_atomic_load(&slots[threadIdx.x], __ATOMIC_RELAXED, __HIP_MEMORY_SCOPE_AGENT) < gen)
        __builtin_amdgcn_s_sleep(1);
    }
    __syncthreads();
    if (threadIdx.x == 0)
      __hip_atomic_store(bcast, gen, __ATOMIC_RELAXED, __HIP_MEMORY_SCOPE_AGENT);
  } else {
    if (threadIdx.x == 0){
      __hip_atomic_store(&slots[blockIdx.x], gen, __ATOMIC_RELAXED, __HIP_MEMORY_SCOPE_AGENT);
      while (__hip_atomic_load(bcast, __ATOMIC_RELAXED, __HIP_MEMORY_SCOPE_AGENT) < gen)
        __builtin_amdgcn_s_sleep(1);
    }
    __syncthreads();
  }
}

// ---------- dtype detection ----------
__global__ void k_detect(char* ws, const void* eps){
  const unsigned short* p = (const unsigned short*)eps;
  int lane = threadIdx.x;
  unsigned short u = p[2*lane];
  int e = (u>>7)&0xFF;
  bool pl = (e>=118 && e<=130);
  unsigned long long m = __ballot(pl);
  if (lane==0) *(int*)(ws+wsoff::FLAG) = (__popcll(m) >= 32) ? 1 : 0;
}

// ---------- staging ----------
__global__ void k_stage_xs(char* ws, const void* x, const void* feat){
  int isbf = *(const int*)(ws+wsoff::FLAG);
  size_t i = (size_t)blockIdx.x*blockDim.x + threadIdx.x;
  if (i >= (size_t)NT*NB*KX) return;
  int c = i % KX; size_t q = i / KX; int b = q % NB; int t = q / NB;
  float v = 0.f;
  if (c < 2)        v = ld_any(x,    ((size_t)b*NT + t)*2 + c, isbf);
  else if (c < 18)  v = ld_any(feat, ((size_t)b*192 + t)*16 + (c-2), isbf);
  ((bf16*)(ws+wsoff::XS))[i] = __float2bfloat16(v);
}
__global__ void k_stage_pad(char* ws, const void* src, size_t dstoff, int R, int SC, int DC){
  int isbf = *(const int*)(ws+wsoff::FLAG);
  size_t i = (size_t)blockIdx.x*blockDim.x + threadIdx.x;
  if (i >= (size_t)R*DC) return;
  int r = i / DC, c = i % DC;
  float v = (c < SC) ? ld_any(src, (size_t)r*SC + c, isbf) : 0.f;
  ((bf16*)(ws+dstoff))[i] = __float2bfloat16(v);
}
__global__ void k_stage_dec(char* ws, const void* src, size_t dstoff){
  int isbf = *(const int*)(ws+wsoff::FLAG);
  size_t i = (size_t)blockIdx.x*blockDim.x + threadIdx.x;
  if (i >= (size_t)432*HDP) return;
  int R = i / HDP, c = i % HDP;
  int g = R / GDP, ii = R % GDP;
  float v = (ii < HD && c < HD) ? ld_any(src, ((size_t)(g*HD+ii))*HD + c, isbf) : 0.f;
  ((bf16*)(ws+dstoff))[i] = __float2bfloat16(v);
}
struct SmallSegs { const void* src[12]; int dstoff[12]; int n[12]; };
__global__ void k_stage_small(char* ws, SmallSegs segs){
  int isbf = *(const int*)(ws+wsoff::FLAG);
  int s = blockIdx.x;
  float* dst = (float*)(ws + (size_t)segs.dstoff[s]);
  for (int i = threadIdx.x; i < segs.n[s]; i += blockDim.x)
    dst[i] = ld_any(segs.src[s], i, isbf);
}

// ================= persistent encoder: 112 blocks =================
// 0..31  layer0: rb=bid>>2 rows rb*128, cb=bid&3 cols cb*64; LDS weights 110.6KB + hf 32KB
// 32..95 layer1: rb>>3 rows, cb&7 cols cb*32; LDS 98.3KB + hf 16KB
// 96..111 mlp: rows (bid-96)*64; LDS 16KB
__global__ __launch_bounds__(256,1) void k_encoder(char* ws, const int* mask){
  extern __shared__ __align__(16) char smem[];
  const int bid = blockIdx.x, tid = threadIdx.x;
  const int lane = tid & 63, w = tid >> 6, lr = lane & 15, q = lane >> 4;

  if (bid < 32){
    // ---- LAYER0 ----
    const int rb = bid >> 2, cb = bid & 3;
    short* wsm = (short*)smem;
    float* hf  = (float*)(smem + 110592);   // [128][64] local fp32 state
    const short* WH = (const short*)(ws + wsoff::WHH0);
    const short* WI = (const short*)(ws + wsoff::WIH0);
    for (int idx = tid; idx < 108*512; idx += 256){
      int u = idx >> 9, le = idx & 511, ln = le >> 3, j = le & 7, lrr = ln & 15, qq = ln >> 4;
      int g = u / 36, rem = u % 36, ct = rem / 9, kb = rem % 9;
      int row = g*HE + cb*64 + ct*16 + lrr;
      wsm[idx] = (kb < 8) ? WH[(size_t)row*256 + kb*32 + qq*8 + j]
                          : WI[(size_t)row*32  + qq*8 + j];
    }
    for (int idx = tid; idx < 128*64; idx += 256) hf[idx] = 0.f;
    const float* bih = f32p(ws,wsoff::BIH0);
    const float* bhh = f32p(ws,wsoff::BHH0);
    float birv[4], bizv[4], binv[4], bhnv[4];
    #pragma unroll
    for (int ct=0;ct<4;ct++){
      int d = cb*64 + ct*16 + lr;
      birv[ct]=bih[d]+bhh[d]; bizv[ct]=bih[HE+d]+bhh[HE+d];
      binv[ct]=bih[2*HE+d];   bhnv[ct]=bhh[2*HE+d];
    }
    __syncthreads();
    const int rowloc = w*32, rowg = rb*128 + rowloc;
    float* hTf = f32p(ws, wsoff::H0F0);
    for (int t = 0; t < 130; ++t){
      if (t < 128){
        const bf16* hbO = H0Bp(ws, t&1);
        bf16* hbN = H0Bp(ws, (t+1)&1);
        const bf16* Xs = bfp(ws,wsoff::XS) + (size_t)t*NB*KX;
        v4f accr[2][4], accz[2][4], acchn[2][4], accxn[2][4];
        #pragma unroll
        for (int mt=0;mt<2;mt++)
          #pragma unroll
          for (int ct=0;ct<4;ct++){
            accr[mt][ct]=(v4f){0,0,0,0}; accz[mt][ct]=(v4f){0,0,0,0};
            acchn[mt][ct]=(v4f){0,0,0,0}; accxn[mt][ct]=(v4f){0,0,0,0};
          }
        { // input K=32 (unit kb=8)
          v8s x0 = fragld(Xs, (size_t)(rowg+lr)*KX + q*8);
          v8s x1 = fragld(Xs, (size_t)(rowg+16+lr)*KX + q*8);
          #pragma unroll
          for (int g=0;g<3;g++)
            #pragma unroll
            for (int ct=0;ct<4;ct++){
              v8s b = ldsfrag(wsm, (g*4+ct)*9 + 8, lane);
              v4f* A0 = (g==0)?&accr[0][ct]:(g==1)?&accz[0][ct]:&accxn[0][ct];
              v4f* A1 = (g==0)?&accr[1][ct]:(g==1)?&accz[1][ct]:&accxn[1][ct];
              *A0 = mfma16(x0,b,*A0); *A1 = mfma16(x1,b,*A1);
            }
        }
        #pragma unroll
        for (int kb=0;kb<8;kb++){
          v8s a0 = ldg_coh16(hbO + (size_t)(rowg+lr)*HE + kb*32 + q*8);
          v8s a1 = ldg_coh16(hbO + (size_t)(rowg+16+lr)*HE + kb*32 + q*8);
          #pragma unroll
          for (int g=0;g<3;g++)
            #pragma unroll
            for (int ct=0;ct<4;ct++){
              v8s b = ldsfrag(wsm, (g*4+ct)*9 + kb, lane);
              v4f* A0 = (g==0)?&accr[0][ct]:(g==1)?&accz[0][ct]:&acchn[0][ct];
              v4f* A1 = (g==0)?&accr[1][ct]:(g==1)?&accz[1][ct]:&acchn[1][ct];
              *A0 = mfma16(a0,b,*A0); *A1 = mfma16(a1,b,*A1);
            }
        }
        int mk[2][4];
        #pragma unroll
        for (int mt=0;mt<2;mt++)
          #pragma unroll
          for (int r=0;r<4;r++)
            mk[mt][r] = mask[(size_t)(rowg + mt*16 + q*4 + r)*NT + t];
        #pragma unroll
        for (int ct=0;ct<4;ct++){
          const int d = cb*64 + ct*16 + lr;
          #pragma unroll
          for (int mt=0;mt<2;mt++)
            #pragma unroll
            for (int r=0;r<4;r++){
              const int rl = rowloc + mt*16 + q*4 + r;
              float rr = sigm(accr[mt][ct][r] + birv[ct]);
              float zz = sigm(accz[mt][ct][r] + bizv[ct]);
              float nn = tanh_f(accxn[mt][ct][r] + binv[ct] + rr*(acchn[mt][ct][r]+bhnv[ct]));
              float ho = hf[rl*64 + ct*16 + lr];
              float hv = (1.f-zz)*nn + zz*ho;
              float h2 = mk[mt][r] ? hv : ho;
              hf[rl*64 + ct*16 + lr] = h2;
              stg_coh_pair(hbN + ((size_t)(rb*128+rl)*HE + (d & ~1)), lr, h2);
              if (t == 127) hTf[(size_t)(rb*128+rl)*HE + d] = h2;
            }
        }
      }
      if (t < 129) gbar(ws, t+1);
    }
  } else if (bid < 96){
    // ---- LAYER1 ----
    const int id = bid - 32, rb = id >> 3, cb = id & 7;
    short* wsm = (short*)smem;
    float* hf  = (float*)(smem + 98304);    // [128][32]
    const short* WX = (const short*)(ws + wsoff::WIH1);
    const short* WHs= (const short*)(ws + wsoff::WHH1);
    for (int idx = tid; idx < 96*512; idx += 256){
      int u = idx >> 9, le = idx & 511, ln = le >> 3, j = le & 7, lrr = ln & 15, qq = ln >> 4;
      int g = u / 32, rem = u % 32, ct = rem >> 4, kb = rem & 15;
      int row = g*HE + cb*32 + ct*16 + lrr;
      wsm[idx] = (kb < 8) ? WX [(size_t)row*256 + kb*32 + qq*8 + j]
                          : WHs[(size_t)row*256 + (kb-8)*32 + qq*8 + j];
    }
    for (int idx = tid; idx < 128*32; idx += 256) hf[idx] = 0.f;
    const float* bih = f32p(ws,wsoff::BIH1);
    const float* bhh = f32p(ws,wsoff::BHH1);
    float birv[2], bizv[2], binv[2], bhnv[2];
    #pragma unroll
    for (int ct=0;ct<2;ct++){
      int d = cb*32 + ct*16 + lr;
      birv[ct]=bih[d]+bhh[d]; bizv[ct]=bih[HE+d]+bhh[HE+d];
      binv[ct]=bih[2*HE+d];   bhnv[ct]=bhh[2*HE+d];
    }
    __syncthreads();
    const int rowloc = w*32, rowg = rb*128 + rowloc;
    float* hTf = f32p(ws, wsoff::H1F0);
    for (int t = 0; t < 130; ++t){
      if (t >= 1 && t <= 128){
        const int s = t-1;
        const bf16* Ax = H0Bp(ws, t&1);
        const bf16* Ah = H1Bp(ws, s&1);
        bf16* hbN = H1Bp(ws, t&1);
        v4f accr[2][2], accz[2][2], accxn[2][2], acchn[2][2];
        #pragma unroll
        for (int mt=0;mt<2;mt++)
          #pragma unroll
          for (int ct=0;ct<2;ct++){
            accr[mt][ct]=(v4f){0,0,0,0}; accz[mt][ct]=(v4f){0,0,0,0};
            accxn[mt][ct]=(v4f){0,0,0,0}; acchn[mt][ct]=(v4f){0,0,0,0};
          }
        #pragma unroll
        for (int kb=0;kb<8;kb++){
          v8s a0 = ldg_coh16(Ax + (size_t)(rowg+lr)*HE + kb*32 + q*8);
          v8s a1 = ldg_coh16(Ax + (size_t)(rowg+16+lr)*HE + kb*32 + q*8);
          #pragma unroll
          for (int g=0;g<3;g++)
            #pragma unroll
            for (int ct=0;ct<2;ct++){
              v8s b = ldsfrag(wsm, (g*2+ct)*16 + kb, lane);
              v4f* A0 = (g==0)?&accr[0][ct]:(g==1)?&accz[0][ct]:&accxn[0][ct];
              v4f* A1 = (g==0)?&accr[1][ct]:(g==1)?&accz[1][ct]:&accxn[1][ct];
              *A0 = mfma16(a0,b,*A0); *A1 = mfma16(a1,b,*A1);
            }
        }
        #pragma unroll
        for (int kb=0;kb<8;kb++){
          v8s a0 = ldg_coh16(Ah + (size_t)(rowg+lr)*HE + kb*32 + q*8);
          v8s a1 = ldg_coh16(Ah + (size_t)(rowg+16+lr)*HE + kb*32 + q*8);
          #pragma unroll
          for (int g=0;g<3;g++)
            #pragma unroll
            for (int ct=0;ct<2;ct++){
              v8s b = ldsfrag(wsm, (g*2+ct)*16 + 8 + kb, lane);
              v4f* A0 = (g==0)?&accr[0][ct]:(g==1)?&accz[0][ct]:&acchn[0][ct];
              v4f* A1 = (g==0)?&accr[1][ct]:(g==1)?&accz[1][ct]:&acchn[1][ct];
              *A0 = mfma16(a0,b,*A0); *A1 = mfma16(a1,b,*A1);
            }
        }
        int mk[2][4];
        #pragma unroll
        for (int mt=0;mt<2;mt++)
          #pragma unroll
          for (int r=0;r<4;r++)
            mk[mt][r] = mask[(size_t)(rowg + mt*16 + q*4 + r)*NT + s];
        #pragma unroll
        for (int ct=0;ct<2;ct++){
          const int d = cb*32 + ct*16 + lr;
          #pragma unroll
          for (int mt=0;mt<2;mt++)
            #pragma unroll
            for (int r=0;r<4;r++){
              const int rl = rowloc + mt*16 + q*4 + r;
              float rr = sigm(accr[mt][ct][r] + birv[ct]);
              float zz = sigm(accz[mt][ct][r] + bizv[ct]);
              float nn = tanh_f(accxn[mt][ct][r] + binv[ct] + rr*(acchn[mt][ct][r]+bhnv[ct]));
              float ho = hf[rl*32 + ct*16 + lr];
              float hv = (1.f-zz)*nn + zz*ho;
              float h2 = mk[mt][r] ? hv : ho;
              hf[rl*32 + ct*16 + lr] = h2;
              stg_coh_pair(hbN + ((size_t)(rb*128+rl)*HE + (d & ~1)), lr, h2);
              if (s == 127) hTf[(size_t)(rb*128+rl)*HE + d] = h2;
            }
        }
      }
      if (t < 129) gbar(ws, t+1);
    }
  } else {
    // ---- MLP ----
    const int mb = bid - 96;
    short* wsm = (short*)smem;   // 16 units
    const short* W1s = (const short*)(ws + wsoff::W1B);
    for (int idx = tid; idx < 16*512; idx += 256){
      int u = idx >> 9, le = idx & 511, ln = le >> 3, j = le & 7, lrr = ln & 15, qq = ln >> 4;
      int ct = u >> 2, kb = u & 3;
      wsm[idx] = W1s[(size_t)(ct*16 + lrr)*NH + kb*32 + qq*8 + j];
    }
    float b1v[4], w20[4], w21[4];
    const float* B1 = f32p(ws,wsoff::B1F);
    const float* W2 = f32p(ws,wsoff::W2F);
    const float* B2 = f32p(ws,wsoff::B2F);
    #pragma unroll
    for (int c=0;c<4;c++){ int col=c*16+lr; b1v[c]=B1[col]; w20[c]=W2[col]; w21[c]=W2[64+col]; }
    const float b20 = B2[0], b21 = B2[1];
    __syncthreads();
    const int rowbase = mb*64 + w*16, rowA = rowbase + lr;
    for (int t = 0; t < 130; ++t){
      if (t >= 2){
        const int s = t-2;
        const bf16* A = H1Bp(ws, (t-1)&1);
        const bool valid = mask[(size_t)rowA*NT + s] != 0;
        v4f acc[4];
        #pragma unroll
        for (int c=0;c<4;c++) acc[c]=(v4f){0,0,0,0};
        #pragma unroll
        for (int kb=0;kb<4;kb++){
          v8s a = valid ? ldg_coh16(A + (size_t)rowA*HE + kb*32 + q*8) : (v8s){0,0,0,0,0,0,0,0};
          #pragma unroll
          for (int c=0;c<4;c++){
            v8s b = ldsfrag(wsm, c*4 + kb, lane);
            acc[c] = mfma16(a,b,acc[c]);
          }
        }
        float* outp = f32p(ws,wsoff::ENCP) + (size_t)s*NB*2;
        #pragma unroll
        for (int r=0;r<4;r++){
          float p0 = 0.f, p1 = 0.f;
          #pragma unroll
          for (int c=0;c<4;c++){
            float hv = acc[c][r] + b1v[c]; hv = hv>0.f ? hv : 0.f;
            p0 += hv*w20[c]; p1 += hv*w21[c];
          }
          #pragma unroll
          for (int m=1;m<16;m<<=1){ p0 += __shfl_xor(p0,m,64); p1 += __shfl_xor(p1,m,64); }
          if (lr == 0){
            const int grow = rowbase + q*4 + r;
            outp[(size_t)grow*2]   = softplusf(p0+b20);
            outp[(size_t)grow*2+1] = softplusf(p1+b21);
          }
        }
      }
      if (t < 129) gbar(ws, t+1);
    }
  }
}

// ================= decoder: state in LDS, weights streamed from L2 =================
__global__ __launch_bounds__(512,1) void k_decoder(char* ws, const void* eps, const void* feat, void* out){
  extern __shared__ __align__(16) char dsm[];
  float* s_h0f = (float*)dsm;                    // [32][160]
  float* s_h1f = (float*)(dsm + 20480);
  short* s_h0b = (short*)(dsm + 40960);          // [32][HDS]
  short* s_h1b = (short*)(dsm + 51456);
  short* s_w1  = (short*)(dsm + 61952);          // 16 frag units
  float* s_wih = (float*)(dsm + 78336);          // 792
  float* s_bia = (float*)(dsm + 81504);          // bi0,bh0,bi1,bh1 (4*396)
  float* s_inp = (float*)(dsm + 87840);          // [32][2]

  const int isbf = *(const int*)(ws+wsoff::FLAG);
  const int bid = blockIdx.x, tid = threadIdx.x;
  const int lane = tid & 63, w = tid >> 6, lr = lane & 15, q = lane >> 4;
  const int rowbase = bid*32;
  constexpr size_t N0v = (size_t)NS*NB*127*2;

  // ---- init ----
  {
    const float* h0T = f32p(ws,wsoff::H0F0);
    const float* h1T = f32p(ws,wsoff::H1F0);
    for (int idx = tid; idx < 2*32*HDS; idx += 512){
      int l = idx / (32*HDS), rem = idx % (32*HDS);
      int r0 = rem / HDS, d = rem % HDS;
      int sb = rowbase + r0, s = sb >> 10, b = sb & 1023;
      const float* hT = l ? h1T : h0T;
      float v = 0.f;
      if (d < NH){
        float mean = hT[(size_t)b*HE + d], lv = hT[(size_t)b*HE + NH + d];
        float e = ld_any(eps, ((size_t)(s*2+l)*NB + b)*NH + d, isbf);
        v = e*__expf(0.5f*lv) + mean;
      } else if (d < HD){
        v = ld_any(feat, (size_t)b*3072 + 2048 + (d-NH), isbf);
      }
      if (d < HDP) (l ? s_h1f : s_h0f)[r0*HDP + d] = v;
      (l ? s_h1b : s_h0b)[r0*HDS + d] = (short)0;
      { bf16 hb = __float2bfloat16(v); short sv; __builtin_memcpy(&sv,&hb,2);
        (l ? s_h1b : s_h0b)[r0*HDS + d] = sv; }
    }
    for (int i = tid; i < 792; i += 512) s_wih[i] = f32p(ws,wsoff::WDIH0F)[i];
    for (int i = tid; i < 396; i += 512){
      s_bia[i]        = f32p(ws,wsoff::BDIH0)[i];
      s_bia[396+i]    = f32p(ws,wsoff::BDHH0)[i];
      s_bia[792+i]    = f32p(ws,wsoff::BDIH1)[i];
      s_bia[1188+i]   = f32p(ws,wsoff::BDHH1)[i];
    }
    const short* W1s = (const short*)(ws + wsoff::W1B);
    for (int idx = tid; idx < 16*512; idx += 512){
      int u = idx >> 9, le = idx & 511, ln = le >> 3, j = le & 7, lrr = ln & 15, qq = ln >> 4;
      int ct = u >> 2, kb = u & 3;
      s_w1[idx] = W1s[(size_t)(ct*16 + lrr)*NH + kb*32 + qq*8 + j];
    }
    for (int idx = tid; idx < 64; idx += 512){
      int r0 = idx >> 1, c = idx & 1;
      int b = (rowbase + r0) & 1023;
      float v = f32p(ws,wsoff::ENCP)[((size_t)127*NB + b)*2 + c];
      s_inp[idx] = v;
      st_out(out, N0v + ((size_t)(rowbase+r0)*64)*2 + c, v, isbf);
    }
  }
  float b1v[4], w20[4], w21[4];
  { const float* B1 = f32p(ws,wsoff::B1F); const float* W2 = f32p(ws,wsoff::W2F);
    #pragma unroll
    for (int c=0;c<4;c++){ int col=c*16+lr; b1v[c]=B1[col]; w20[c]=W2[col]; w21[c]=W2[64+col]; } }
  const float b20 = f32p(ws,wsoff::B2F)[0], b21 = f32p(ws,wsoff::B2F)[1];
  const bf16* W0  = bfp(ws,wsoff::WDHH0);
  const bf16* WX1 = bfp(ws,wsoff::WDIH1);
  const bf16* WH1 = bfp(ws,wsoff::WDHH1);
  __syncthreads();

  for (int k = 0; k < 63; ++k){
    // ---- P1: d0 matmul (reads s_h0b) ----
    v4f Ar[3], Az[3], Ahn[3];
    #pragma unroll
    for (int ui=0; ui<3; ++ui){
      Ar[ui]=(v4f){0,0,0,0}; Az[ui]=(v4f){0,0,0,0}; Ahn[ui]=(v4f){0,0,0,0};
      int u = w + ui*8;
      if (u < 18){
        int m = u & 1, cc = u >> 1;
        #pragma unroll
        for (int kb=0;kb<5;kb++){
          v8s a = lds_frag8(s_h0b + (m*16+lr)*HDS + kb*32 + q*8);
          v8s br = fragld(W0, (size_t)(0*GDP + cc*16 + lr)*HDP + kb*32 + q*8);
          v8s bz = fragld(W0, (size_t)(1*GDP + cc*16 + lr)*HDP + kb*32 + q*8);
          v8s bn = fragld(W0, (size_t)(2*GDP + cc*16 + lr)*HDP + kb*32 + q*8);
          Ar[ui]=mfma16(a,br,Ar[ui]); Az[ui]=mfma16(a,bz,Az[ui]); Ahn[ui]=mfma16(a,bn,Ahn[ui]);
        }
      }
    }
    __syncthreads();
    // ---- P1 epilogue (writes s_h0f/s_h0b) ----
    #pragma unroll
    for (int ui=0; ui<3; ++ui){
      int u = w + ui*8;
      if (u < 18){
        int m = u & 1, cc = u >> 1, d = cc*16 + lr;
        if (d < HD){
          float wr0=s_wih[(0*HD+d)*2], wr1=s_wih[(0*HD+d)*2+1];
          float wz0=s_wih[(1*HD+d)*2], wz1=s_wih[(1*HD+d)*2+1];
          float wn0=s_wih[(2*HD+d)*2], wn1=s_wih[(2*HD+d)*2+1];
          float bir=s_bia[d], bhr=s_bia[396+d], biz=s_bia[HD+d], bhz=s_bia[396+HD+d];
          float bin=s_bia[2*HD+d], bhn=s_bia[396+2*HD+d];
          #pragma unroll
          for (int r=0;r<4;r++){
            int row = m*16 + q*4 + r;
            float i0 = s_inp[row*2], i1 = s_inp[row*2+1];
            float rr = sigm(i0*wr0+i1*wr1+bir + Ar[ui][r] + bhr);
            float zz = sigm(i0*wz0+i1*wz1+biz + Az[ui][r] + bhz);
            float nn = tanh_f(i0*wn0+i1*wn1+bin + rr*(Ahn[ui][r]+bhn));
            float ho = s_h0f[row*HDP + d];
            float hv = (1.f-zz)*nn + zz*ho;
            s_h0f[row*HDP + d] = hv;
            bf16 hb = __float2bfloat16(hv); short sv; __builtin_memcpy(&sv,&hb,2);
            s_h0b[row*HDS + d] = sv;
          }
        }
      }
    }
    __syncthreads();
    // ---- P2: d1 matmul (reads s_h0b new + s_h1b old) ----
    v4f Br[3], Bz[3], Bxn[3], Bhn[3];
    #pragma unroll
    for (int ui=0; ui<3; ++ui){
      Br[ui]=(v4f){0,0,0,0}; Bz[ui]=(v4f){0,0,0,0}; Bxn[ui]=(v4f){0,0,0,0}; Bhn[ui]=(v4f){0,0,0,0};
      int u = w + ui*8;
      if (u < 18){
        int m = u & 1, cc = u >> 1;
        #pragma unroll
        for (int kb=0;kb<5;kb++){
          v8s ax = lds_frag8(s_h0b + (m*16+lr)*HDS + kb*32 + q*8);
          v8s ah = lds_frag8(s_h1b + (m*16+lr)*HDS + kb*32 + q*8);
          size_t wr = (size_t)(0*GDP + cc*16 + lr)*HDP + kb*32 + q*8;
          size_t wz = (size_t)(1*GDP + cc*16 + lr)*HDP + kb*32 + q*8;
          size_t wn = (size_t)(2*GDP + cc*16 + lr)*HDP + kb*32 + q*8;
          Br[ui]=mfma16(ax,fragld(WX1,wr),Br[ui]); Br[ui]=mfma16(ah,fragld(WH1,wr),Br[ui]);
          Bz[ui]=mfma16(ax,fragld(WX1,wz),Bz[ui]); Bz[ui]=mfma16(ah,fragld(WH1,wz),Bz[ui]);
          Bxn[ui]=mfma16(ax,fragld(WX1,wn),Bxn[ui]); Bhn[ui]=mfma16(ah,fragld(WH1,wn),Bhn[ui]);
        }
      }
    }
    __syncthreads();
    // ---- P2 epilogue (writes s_h1f/s_h1b) ----
    #pragma unroll
    for (int ui=0; ui<3; ++ui){
      int u = w + ui*8;
      if (u < 18){
        int m = u & 1, cc = u >> 1, d = cc*16 + lr;
        if (d < HD){
          float bir=s_bia[792+d]+s_bia[1188+d], biz=s_bia[792+HD+d]+s_bia[1188+HD+d];
          float bin=s_bia[792+2*HD+d], bhn=s_bia[1188+2*HD+d];
          #pragma unroll
          for (int r=0;r<4;r++){
            int row = m*16 + q*4 + r;
            float rr = sigm(Br[ui][r] + bir);
            float zz = sigm(Bz[ui][r] + biz);
            float nn = tanh_f(Bxn[ui][r] + bin + rr*(Bhn[ui][r]+bhn));
            float ho = s_h1f[row*HDP + d];
            float hv = (1.f-zz)*nn + zz*ho;
            s_h1f[row*HDP + d] = hv;
            bf16 hb = __float2bfloat16(hv); short sv; __builtin_memcpy(&sv,&hb,2);
            s_h1b[row*HDS + d] = sv;
          }
        }
      }
    }
    __syncthreads();
    // ---- P3: mlp (waves 0,1) ----
    if (w < 2){
      const int m = w;
      v4f acc[4];
      #pragma unroll
      for (int c=0;c<4;c++) acc[c]=(v4f){0,0,0,0};
      #pragma unroll
      for (int kb=0;kb<4;kb++){
        v8s a = lds_frag8(s_h1b + (m*16+lr)*HDS + kb*32 + q*8);
        #pragma unroll
        for (int c=0;c<4;c++){
          v8s b = ldsfrag(s_w1, c*4 + kb, lane);
          acc[c] = mfma16(a,b,acc[c]);
        }
      }
      #pragma unroll
      for (int r=0;r<4;r++){
        float p0 = 0.f, p1 = 0.f;
        #pragma unroll
        for (int c=0;c<4;c++){
          float hv = acc[c][r] + b1v[c]; hv = hv>0.f ? hv : 0.f;
          p0 += hv*w20[c]; p1 += hv*w21[c];
        }
        #pragma unroll
        for (int mm=1;mm<16;mm<<=1){ p0 += __shfl_xor(p0,mm,64); p1 += __shfl_xor(p1,mm,64); }
        if (lr == 0){
          int row = m*16 + q*4 + r;
          float s0 = softplusf(p0+b20), s1 = softplusf(p1+b21);
          s_inp[row*2] = s0; s_inp[row*2+1] = s1;
          size_t oo = N0v + ((size_t)(rowbase+row)*64 + (k+1))*2;
          st_out(out, oo,   s0, isbf);
          st_out(out, oo+1, s1, isbf);
        }
      }
    }
    __syncthreads();
  }
}

// ---------- encoder-part output assembly ----------
__global__ void k_assemble_enc(char* ws, void* out){
  int isbf = *(const int*)(ws+wsoff::FLAG);
  const float* encp = f32p(ws,wsoff::ENCP);
  constexpr size_t N0v = (size_t)NS*NB*127*2;
  for (size_t i = (size_t)blockIdx.x*blockDim.x + threadIdx.x; i < N0v;
       i += (size_t)gridDim.x*blockDim.x){
    int c = (int)(i & 1); size_t qq = i >> 1;
    int tt = (int)(qq % 127); size_t q2 = qq / 127; int b = (int)(q2 & 1023);
    st_out(out, i, encp[((size_t)tt*NB + b)*2 + c], isbf);
  }
}

extern "C" void kernel_launch(void* const* d_in, const int* in_sizes, int n_in,
                              void* d_out, int out_size, void* d_ws, size_t ws_size,
                              hipStream_t stream) {
  char* ws = (char*)d_ws;
  const int* mask = (const int*)d_in[2];
  auto gb = [](size_t n){ return dim3((unsigned)((n + 255)/256)); };

  hipMemsetAsync(ws+wsoff::BAR,  0, 1024, stream);
  hipMemsetAsync(ws+wsoff::H0B0, 0, (size_t)NB*HE*2, stream);
  hipMemsetAsync(ws+wsoff::H1B0, 0, (size_t)NB*HE*2, stream);

  k_detect<<<1,64,0,stream>>>(ws, d_in[3]);

  k_stage_xs <<<gb((size_t)NT*NB*KX),256,0,stream>>>(ws, d_in[0], d_in[1]);
  k_stage_pad<<<gb(768*32) ,256,0,stream>>>(ws, d_in[7],  wsoff::WIH0, 768, 18, 32);
  k_stage_pad<<<gb(768*256),256,0,stream>>>(ws, d_in[8],  wsoff::WHH0, 768, 256, 256);
  k_stage_pad<<<gb(768*256),256,0,stream>>>(ws, d_in[11], wsoff::WIH1, 768, 256, 256);
  k_stage_pad<<<gb(768*256),256,0,stream>>>(ws, d_in[12], wsoff::WHH1, 768, 256, 256);
  k_stage_pad<<<gb(64*128) ,256,0,stream>>>(ws, d_in[23], wsoff::W1B,  64, 128, 128);
  k_stage_dec<<<gb(432*HDP),256,0,stream>>>(ws, d_in[16], wsoff::WDHH0);
  k_stage_dec<<<gb(432*HDP),256,0,stream>>>(ws, d_in[19], wsoff::WDIH1);
  k_stage_dec<<<gb(432*HDP),256,0,stream>>>(ws, d_in[20], wsoff::WDHH1);

  SmallSegs ss;
  const void* srcs[12] = {d_in[9],d_in[10],d_in[13],d_in[14],d_in[15],
                          d_in[17],d_in[18],d_in[21],d_in[22],
                          d_in[24],d_in[25],d_in[26]};
  const size_t offs[12] = {wsoff::BIH0,wsoff::BHH0,wsoff::BIH1,wsoff::BHH1,wsoff::WDIH0F,
                           wsoff::BDIH0,wsoff::BDHH0,wsoff::BDIH1,wsoff::BDHH1,
                           wsoff::B1F,wsoff::W2F,wsoff::B2F};
  const int ns[12] = {768,768,768,768,792,396,396,396,396,64,128,2};
  for (int i=0;i<12;i++){ ss.src[i]=srcs[i]; ss.dstoff[i]=(int)offs[i]; ss.n[i]=ns[i]; }
  k_stage_small<<<12,256,0,stream>>>(ws, ss);

  hipFuncSetAttribute(reinterpret_cast<const void*>(k_encoder),
                      hipFuncAttributeMaxDynamicSharedMemorySize, 143360);
  hipFuncSetAttribute(reinterpret_cast<const void*>(k_decoder),
                      hipFuncAttributeMaxDynamicSharedMemorySize, 88096);

  // persistent encoder: 112 blocks, all co-resident (<=256 CUs, 1 block/CU by LDS)
  k_encoder<<<EBLOCKS,256,143360,stream>>>(ws, mask);

  // decoder: batch-stationary, state in LDS, no grid sync
  k_decoder<<<256,512,88096,stream>>>(ws, d_in[3], d_in[1], d_out);

  k_assemble_enc<<<2048,256,0,stream>>>(ws, d_out);
}

// Round 4
// 4829.544 us; speedup vs baseline: 1.5573x; 1.1591x over previous
//
#include <hip/hip_runtime.h>
#include <hip/hip_bf16.h>
#include <math.h>

typedef __hip_bfloat16 bf16;
typedef short v8s __attribute__((ext_vector_type(8)));
typedef float v4f __attribute__((ext_vector_type(4)));

#define NB   1024
#define NT   128
#define NH   128
#define HE   256
#define HD   132
#define HDP  160    // padded K for decoder weights (global)
#define HDS  164    // LDS row stride (elems) for decoder bf16 state
#define GDP  144
#define NS   8
#define SB   8192
#define KX   32
#define EBLOCKS 112

namespace wsoff {
constexpr size_t al(size_t x){ return (x + 255) & ~size_t(255); }
constexpr size_t FLAG  = 0;
constexpr size_t BAR   = 256;    // slots[112] ints; bcast at BAR+512
constexpr size_t XS    = 2048;
constexpr size_t WIH0  = al(XS    + (size_t)NT*NB*KX*2);
constexpr size_t WHH0  = al(WIH0  + 768*32*2);
constexpr size_t WIH1  = al(WHH0  + 768*256*2);
constexpr size_t WHH1  = al(WIH1  + 768*256*2);
constexpr size_t BIH0  = al(WHH1  + 768*256*2);
constexpr size_t BHH0  = al(BIH0  + 768*4);
constexpr size_t BIH1  = al(BHH0  + 768*4);
constexpr size_t BHH1  = al(BIH1  + 768*4);
constexpr size_t WDHH0 = al(BHH1  + 768*4);
constexpr size_t WDIH1 = al(WDHH0 + 432*HDP*2);
constexpr size_t WDHH1 = al(WDIH1 + 432*HDP*2);
constexpr size_t WDIH0F= al(WDHH1 + 432*HDP*2);
constexpr size_t BDIH0 = al(WDIH0F+ 792*4);
constexpr size_t BDHH0 = al(BDIH0 + 396*4);
constexpr size_t BDIH1 = al(BDHH0 + 396*4);
constexpr size_t BDHH1 = al(BDIH1 + 396*4);
constexpr size_t W1B   = al(BDHH1 + 396*4);
constexpr size_t B1F   = al(W1B   + 64*128*2);
constexpr size_t W2F   = al(B1F   + 64*4);
constexpr size_t B2F   = al(W2F   + 128*4);
constexpr size_t H0F0  = al(B2F   + 2*4);     // final h0 fp32 [NB][HE]
constexpr size_t H1F0  = al(H0F0  + (size_t)NB*HE*4);
constexpr size_t H0B0  = al(H1F0  + (size_t)NB*HE*4);
constexpr size_t H0B1  = al(H0B0  + (size_t)NB*HE*2);
constexpr size_t H1B0  = al(H0B1  + (size_t)NB*HE*2);
constexpr size_t H1B1  = al(H1B0  + (size_t)NB*HE*2);
constexpr size_t ENCP  = al(H1B1  + (size_t)NB*HE*2);   // fp32 [128][1024][2]
}

// ---------- helpers ----------
__device__ __forceinline__ float ld_any(const void* p, size_t i, int isbf){
  return isbf ? __bfloat162float(((const bf16*)p)[i]) : ((const float*)p)[i];
}
__device__ __forceinline__ void st_out(void* out, size_t i, float v, int isbf){
  if (isbf) ((bf16*)out)[i] = __float2bfloat16(v); else ((float*)out)[i] = v;
}
__device__ __forceinline__ float sigm(float x){ return 1.0f/(1.0f + __expf(-x)); }
__device__ __forceinline__ float tanh_f(float x){
  float t = __expf(2.0f*x); return 1.0f - 2.0f/(t+1.0f);
}
__device__ __forceinline__ float softplusf(float x){ return x>20.f ? x : log1pf(__expf(x)); }
__device__ __forceinline__ v4f mfma16(v8s a, v8s b, v4f c){
  return __builtin_amdgcn_mfma_f32_16x16x32_bf16(a,b,c,0,0,0);
}
__device__ __forceinline__ v8s fragld(const bf16* base, size_t elem_off){
  return *reinterpret_cast<const v8s*>(base + elem_off);
}
__device__ __forceinline__ v8s ldsfrag(const short* sm, int unit, int lane){
  return *reinterpret_cast<const v8s*>(sm + (unit<<9) + (lane<<3));
}
__device__ __forceinline__ v8s lds_frag8(const short* p){   // 8B-aligned LDS frag
  union { long long l[2]; v8s s; } r;
  r.l[0] = *(const long long*)(p);
  r.l[1] = *(const long long*)(p + 4);
  return r.s;
}
__device__ __forceinline__ short bf16bits(float v){
  bf16 h = __float2bfloat16(v); short s; __builtin_memcpy(&s,&h,2); return s;
}
// coherent (agent-scope, relaxed) 16B load: 4x dword sc1
__device__ __forceinline__ v8s ldg_coh16(const bf16* p){
  union { unsigned u[4]; v8s s; } r;
  const unsigned* q = (const unsigned*)p;
  r.u[0] = __hip_atomic_load(q+0, __ATOMIC_RELAXED, __HIP_MEMORY_SCOPE_AGENT);
  r.u[1] = __hip_atomic_load(q+1, __ATOMIC_RELAXED, __HIP_MEMORY_SCOPE_AGENT);
  r.u[2] = __hip_atomic_load(q+2, __ATOMIC_RELAXED, __HIP_MEMORY_SCOPE_AGENT);
  r.u[3] = __hip_atomic_load(q+3, __ATOMIC_RELAXED, __HIP_MEMORY_SCOPE_AGENT);
  return r.s;
}
// coherent paired bf16 store: lanes (even,odd) in lr pair up to one dword
__device__ __forceinline__ void stg_coh_pair(bf16* base_even, int lr, float v){
  bf16 h = __float2bfloat16(v);
  unsigned vv; { unsigned short b; __builtin_memcpy(&b, &h, 2); vv = b; }
  unsigned ov = (unsigned)__shfl_xor((int)vv, 1, 64);
  if (!(lr & 1))
    __hip_atomic_store((unsigned*)base_even, vv | (ov<<16), __ATOMIC_RELAXED, __HIP_MEMORY_SCOPE_AGENT);
}
__device__ __forceinline__ float*  f32p(char* ws, size_t off){ return (float*)(ws+off); }
__device__ __forceinline__ bf16*   bfp (char* ws, size_t off){ return (bf16*)(ws+off); }
__device__ __forceinline__ bf16*   H0Bp(char* ws,int p){ return bfp (ws, p?wsoff::H0B1:wsoff::H0B0); }
__device__ __forceinline__ bf16*   H1Bp(char* ws,int p){ return bfp (ws, p?wsoff::H1B1:wsoff::H1B0); }

// ---------- grid barrier: slot stores + collector + broadcast, no cache fences ----
__device__ __forceinline__ void gbar(char* ws, int gen){
  __syncthreads();
  int* slots = (int*)(ws + wsoff::BAR);
  int* bcast = (int*)(ws + wsoff::BAR + 512);
  if (blockIdx.x == 0){
    if (threadIdx.x > 0 && threadIdx.x < EBLOCKS){
      while (__hip_atomic_load(&slots[threadIdx.x], __ATOMIC_RELAXED, __HIP_MEMORY_SCOPE_AGENT) < gen)
        __builtin_amdgcn_s_sleep(1);
    }
    __syncthreads();
    if (threadIdx.x == 0)
      __hip_atomic_store(bcast, gen, __ATOMIC_RELAXED, __HIP_MEMORY_SCOPE_AGENT);
  } else {
    if (threadIdx.x == 0){
      __hip_atomic_store(&slots[blockIdx.x], gen, __ATOMIC_RELAXED, __HIP_MEMORY_SCOPE_AGENT);
      while (__hip_atomic_load(bcast, __ATOMIC_RELAXED, __HIP_MEMORY_SCOPE_AGENT) < gen)
        __builtin_amdgcn_s_sleep(1);
    }
    __syncthreads();
  }
}

// ---------- dtype detection ----------
__global__ void k_detect(char* ws, const void* eps){
  const unsigned short* p = (const unsigned short*)eps;
  int lane = threadIdx.x;
  unsigned short u = p[2*lane];
  int e = (u>>7)&0xFF;
  bool pl = (e>=118 && e<=130);
  unsigned long long m = __ballot(pl);
  if (lane==0) *(int*)(ws+wsoff::FLAG) = (__popcll(m) >= 32) ? 1 : 0;
}

// ---------- staging ----------
__global__ void k_stage_xs(char* ws, const void* x, const void* feat){
  int isbf = *(const int*)(ws+wsoff::FLAG);
  size_t i = (size_t)blockIdx.x*blockDim.x + threadIdx.x;
  if (i >= (size_t)NT*NB*KX) return;
  int c = i % KX; size_t q = i / KX; int b = q % NB; int t = q / NB;
  float v = 0.f;
  if (c < 2)        v = ld_any(x,    ((size_t)b*NT + t)*2 + c, isbf);
  else if (c < 18)  v = ld_any(feat, ((size_t)b*192 + t)*16 + (c-2), isbf);
  ((bf16*)(ws+wsoff::XS))[i] = __float2bfloat16(v);
}
__global__ void k_stage_pad(char* ws, const void* src, size_t dstoff, int R, int SC, int DC){
  int isbf = *(const int*)(ws+wsoff::FLAG);
  size_t i = (size_t)blockIdx.x*blockDim.x + threadIdx.x;
  if (i >= (size_t)R*DC) return;
  int r = i / DC, c = i % DC;
  float v = (c < SC) ? ld_any(src, (size_t)r*SC + c, isbf) : 0.f;
  ((bf16*)(ws+dstoff))[i] = __float2bfloat16(v);
}
__global__ void k_stage_dec(char* ws, const void* src, size_t dstoff){
  int isbf = *(const int*)(ws+wsoff::FLAG);
  size_t i = (size_t)blockIdx.x*blockDim.x + threadIdx.x;
  if (i >= (size_t)432*HDP) return;
  int R = i / HDP, c = i % HDP;
  int g = R / GDP, ii = R % GDP;
  float v = (ii < HD && c < HD) ? ld_any(src, ((size_t)(g*HD+ii))*HD + c, isbf) : 0.f;
  ((bf16*)(ws+dstoff))[i] = __float2bfloat16(v);
}
struct SmallSegs { const void* src[12]; int dstoff[12]; int n[12]; };
__global__ void k_stage_small(char* ws, SmallSegs segs){
  int isbf = *(const int*)(ws+wsoff::FLAG);
  int s = blockIdx.x;
  float* dst = (float*)(ws + (size_t)segs.dstoff[s]);
  for (int i = threadIdx.x; i < segs.n[s]; i += blockDim.x)
    dst[i] = ld_any(segs.src[s], i, isbf);
}

// ================= persistent encoder: 112 blocks (unchanged from R3) =================
__global__ __launch_bounds__(256,1) void k_encoder(char* ws, const int* mask){
  extern __shared__ __align__(16) char smem[];
  const int bid = blockIdx.x, tid = threadIdx.x;
  const int lane = tid & 63, w = tid >> 6, lr = lane & 15, q = lane >> 4;

  if (bid < 32){
    const int rb = bid >> 2, cb = bid & 3;
    short* wsm = (short*)smem;
    float* hf  = (float*)(smem + 110592);
    const short* WH = (const short*)(ws + wsoff::WHH0);
    const short* WI = (const short*)(ws + wsoff::WIH0);
    for (int idx = tid; idx < 108*512; idx += 256){
      int u = idx >> 9, le = idx & 511, ln = le >> 3, j = le & 7, lrr = ln & 15, qq = ln >> 4;
      int g = u / 36, rem = u % 36, ct = rem / 9, kb = rem % 9;
      int row = g*HE + cb*64 + ct*16 + lrr;
      wsm[idx] = (kb < 8) ? WH[(size_t)row*256 + kb*32 + qq*8 + j]
                          : WI[(size_t)row*32  + qq*8 + j];
    }
    for (int idx = tid; idx < 128*64; idx += 256) hf[idx] = 0.f;
    const float* bih = f32p(ws,wsoff::BIH0);
    const float* bhh = f32p(ws,wsoff::BHH0);
    float birv[4], bizv[4], binv[4], bhnv[4];
    #pragma unroll
    for (int ct=0;ct<4;ct++){
      int d = cb*64 + ct*16 + lr;
      birv[ct]=bih[d]+bhh[d]; bizv[ct]=bih[HE+d]+bhh[HE+d];
      binv[ct]=bih[2*HE+d];   bhnv[ct]=bhh[2*HE+d];
    }
    __syncthreads();
    const int rowloc = w*32, rowg = rb*128 + rowloc;
    float* hTf = f32p(ws, wsoff::H0F0);
    for (int t = 0; t < 130; ++t){
      if (t < 128){
        const bf16* hbO = H0Bp(ws, t&1);
        bf16* hbN = H0Bp(ws, (t+1)&1);
        const bf16* Xs = bfp(ws,wsoff::XS) + (size_t)t*NB*KX;
        v4f accr[2][4], accz[2][4], acchn[2][4], accxn[2][4];
        #pragma unroll
        for (int mt=0;mt<2;mt++)
          #pragma unroll
          for (int ct=0;ct<4;ct++){
            accr[mt][ct]=(v4f){0,0,0,0}; accz[mt][ct]=(v4f){0,0,0,0};
            acchn[mt][ct]=(v4f){0,0,0,0}; accxn[mt][ct]=(v4f){0,0,0,0};
          }
        {
          v8s x0 = fragld(Xs, (size_t)(rowg+lr)*KX + q*8);
          v8s x1 = fragld(Xs, (size_t)(rowg+16+lr)*KX + q*8);
          #pragma unroll
          for (int g=0;g<3;g++)
            #pragma unroll
            for (int ct=0;ct<4;ct++){
              v8s b = ldsfrag(wsm, (g*4+ct)*9 + 8, lane);
              v4f* A0 = (g==0)?&accr[0][ct]:(g==1)?&accz[0][ct]:&accxn[0][ct];
              v4f* A1 = (g==0)?&accr[1][ct]:(g==1)?&accz[1][ct]:&accxn[1][ct];
              *A0 = mfma16(x0,b,*A0); *A1 = mfma16(x1,b,*A1);
            }
        }
        #pragma unroll
        for (int kb=0;kb<8;kb++){
          v8s a0 = ldg_coh16(hbO + (size_t)(rowg+lr)*HE + kb*32 + q*8);
          v8s a1 = ldg_coh16(hbO + (size_t)(rowg+16+lr)*HE + kb*32 + q*8);
          #pragma unroll
          for (int g=0;g<3;g++)
            #pragma unroll
            for (int ct=0;ct<4;ct++){
              v8s b = ldsfrag(wsm, (g*4+ct)*9 + kb, lane);
              v4f* A0 = (g==0)?&accr[0][ct]:(g==1)?&accz[0][ct]:&acchn[0][ct];
              v4f* A1 = (g==0)?&accr[1][ct]:(g==1)?&accz[1][ct]:&acchn[1][ct];
              *A0 = mfma16(a0,b,*A0); *A1 = mfma16(a1,b,*A1);
            }
        }
        int mk[2][4];
        #pragma unroll
        for (int mt=0;mt<2;mt++)
          #pragma unroll
          for (int r=0;r<4;r++)
            mk[mt][r] = mask[(size_t)(rowg + mt*16 + q*4 + r)*NT + t];
        #pragma unroll
        for (int ct=0;ct<4;ct++){
          const int d = cb*64 + ct*16 + lr;
          #pragma unroll
          for (int mt=0;mt<2;mt++)
            #pragma unroll
            for (int r=0;r<4;r++){
              const int rl = rowloc + mt*16 + q*4 + r;
              float rr = sigm(accr[mt][ct][r] + birv[ct]);
              float zz = sigm(accz[mt][ct][r] + bizv[ct]);
              float nn = tanh_f(accxn[mt][ct][r] + binv[ct] + rr*(acchn[mt][ct][r]+bhnv[ct]));
              float ho = hf[rl*64 + ct*16 + lr];
              float hv = (1.f-zz)*nn + zz*ho;
              float h2 = mk[mt][r] ? hv : ho;
              hf[rl*64 + ct*16 + lr] = h2;
              stg_coh_pair(hbN + ((size_t)(rb*128+rl)*HE + (d & ~1)), lr, h2);
              if (t == 127) hTf[(size_t)(rb*128+rl)*HE + d] = h2;
            }
        }
      }
      if (t < 129) gbar(ws, t+1);
    }
  } else if (bid < 96){
    const int id = bid - 32, rb = id >> 3, cb = id & 7;
    short* wsm = (short*)smem;
    float* hf  = (float*)(smem + 98304);
    const short* WX = (const short*)(ws + wsoff::WIH1);
    const short* WHs= (const short*)(ws + wsoff::WHH1);
    for (int idx = tid; idx < 96*512; idx += 256){
      int u = idx >> 9, le = idx & 511, ln = le >> 3, j = le & 7, lrr = ln & 15, qq = ln >> 4;
      int g = u / 32, rem = u % 32, ct = rem >> 4, kb = rem & 15;
      int row = g*HE + cb*32 + ct*16 + lrr;
      wsm[idx] = (kb < 8) ? WX [(size_t)row*256 + kb*32 + qq*8 + j]
                          : WHs[(size_t)row*256 + (kb-8)*32 + qq*8 + j];
    }
    for (int idx = tid; idx < 128*32; idx += 256) hf[idx] = 0.f;
    const float* bih = f32p(ws,wsoff::BIH1);
    const float* bhh = f32p(ws,wsoff::BHH1);
    float birv[2], bizv[2], binv[2], bhnv[2];
    #pragma unroll
    for (int ct=0;ct<2;ct++){
      int d = cb*32 + ct*16 + lr;
      birv[ct]=bih[d]+bhh[d]; bizv[ct]=bih[HE+d]+bhh[HE+d];
      binv[ct]=bih[2*HE+d];   bhnv[ct]=bhh[2*HE+d];
    }
    __syncthreads();
    const int rowloc = w*32, rowg = rb*128 + rowloc;
    float* hTf = f32p(ws, wsoff::H1F0);
    for (int t = 0; t < 130; ++t){
      if (t >= 1 && t <= 128){
        const int s = t-1;
        const bf16* Ax = H0Bp(ws, t&1);
        const bf16* Ah = H1Bp(ws, s&1);
        bf16* hbN = H1Bp(ws, t&1);
        v4f accr[2][2], accz[2][2], accxn[2][2], acchn[2][2];
        #pragma unroll
        for (int mt=0;mt<2;mt++)
          #pragma unroll
          for (int ct=0;ct<2;ct++){
            accr[mt][ct]=(v4f){0,0,0,0}; accz[mt][ct]=(v4f){0,0,0,0};
            accxn[mt][ct]=(v4f){0,0,0,0}; acchn[mt][ct]=(v4f){0,0,0,0};
          }
        #pragma unroll
        for (int kb=0;kb<8;kb++){
          v8s a0 = ldg_coh16(Ax + (size_t)(rowg+lr)*HE + kb*32 + q*8);
          v8s a1 = ldg_coh16(Ax + (size_t)(rowg+16+lr)*HE + kb*32 + q*8);
          #pragma unroll
          for (int g=0;g<3;g++)
            #pragma unroll
            for (int ct=0;ct<2;ct++){
              v8s b = ldsfrag(wsm, (g*2+ct)*16 + kb, lane);
              v4f* A0 = (g==0)?&accr[0][ct]:(g==1)?&accz[0][ct]:&accxn[0][ct];
              v4f* A1 = (g==0)?&accr[1][ct]:(g==1)?&accz[1][ct]:&accxn[1][ct];
              *A0 = mfma16(a0,b,*A0); *A1 = mfma16(a1,b,*A1);
            }
        }
        #pragma unroll
        for (int kb=0;kb<8;kb++){
          v8s a0 = ldg_coh16(Ah + (size_t)(rowg+lr)*HE + kb*32 + q*8);
          v8s a1 = ldg_coh16(Ah + (size_t)(rowg+16+lr)*HE + kb*32 + q*8);
          #pragma unroll
          for (int g=0;g<3;g++)
            #pragma unroll
            for (int ct=0;ct<2;ct++){
              v8s b = ldsfrag(wsm, (g*2+ct)*16 + 8 + kb, lane);
              v4f* A0 = (g==0)?&accr[0][ct]:(g==1)?&accz[0][ct]:&acchn[0][ct];
              v4f* A1 = (g==0)?&accr[1][ct]:(g==1)?&accz[1][ct]:&acchn[1][ct];
              *A0 = mfma16(a0,b,*A0); *A1 = mfma16(a1,b,*A1);
            }
        }
        int mk[2][4];
        #pragma unroll
        for (int mt=0;mt<2;mt++)
          #pragma unroll
          for (int r=0;r<4;r++)
            mk[mt][r] = mask[(size_t)(rowg + mt*16 + q*4 + r)*NT + s];
        #pragma unroll
        for (int ct=0;ct<2;ct++){
          const int d = cb*32 + ct*16 + lr;
          #pragma unroll
          for (int mt=0;mt<2;mt++)
            #pragma unroll
            for (int r=0;r<4;r++){
              const int rl = rowloc + mt*16 + q*4 + r;
              float rr = sigm(accr[mt][ct][r] + birv[ct]);
              float zz = sigm(accz[mt][ct][r] + bizv[ct]);
              float nn = tanh_f(accxn[mt][ct][r] + binv[ct] + rr*(acchn[mt][ct][r]+bhnv[ct]));
              float ho = hf[rl*32 + ct*16 + lr];
              float hv = (1.f-zz)*nn + zz*ho;
              float h2 = mk[mt][r] ? hv : ho;
              hf[rl*32 + ct*16 + lr] = h2;
              stg_coh_pair(hbN + ((size_t)(rb*128+rl)*HE + (d & ~1)), lr, h2);
              if (s == 127) hTf[(size_t)(rb*128+rl)*HE + d] = h2;
            }
        }
      }
      if (t < 129) gbar(ws, t+1);
    }
  } else {
    const int mb = bid - 96;
    short* wsm = (short*)smem;
    const short* W1s = (const short*)(ws + wsoff::W1B);
    for (int idx = tid; idx < 16*512; idx += 256){
      int u = idx >> 9, le = idx & 511, ln = le >> 3, j = le & 7, lrr = ln & 15, qq = ln >> 4;
      int c = u >> 2, kb = u & 3;
      wsm[idx] = W1s[(size_t)(c*16 + lrr)*NH + kb*32 + qq*8 + j];
    }
    float b1v[4], w20[4], w21[4];
    const float* B1 = f32p(ws,wsoff::B1F);
    const float* W2 = f32p(ws,wsoff::W2F);
    const float* B2 = f32p(ws,wsoff::B2F);
    #pragma unroll
    for (int c=0;c<4;c++){ int col=c*16+lr; b1v[c]=B1[col]; w20[c]=W2[col]; w21[c]=W2[64+col]; }
    const float b20 = B2[0], b21 = B2[1];
    __syncthreads();
    const int rowbase = mb*64 + w*16, rowA = rowbase + lr;
    for (int t = 0; t < 130; ++t){
      if (t >= 2){
        const int s = t-2;
        const bf16* A = H1Bp(ws, (t-1)&1);
        const bool valid = mask[(size_t)rowA*NT + s] != 0;
        v4f acc[4];
        #pragma unroll
        for (int c=0;c<4;c++) acc[c]=(v4f){0,0,0,0};
        #pragma unroll
        for (int kb=0;kb<4;kb++){
          v8s a = valid ? ldg_coh16(A + (size_t)rowA*HE + kb*32 + q*8) : (v8s){0,0,0,0,0,0,0,0};
          #pragma unroll
          for (int c=0;c<4;c++){
            v8s b = ldsfrag(wsm, c*4 + kb, lane);
            acc[c] = mfma16(a,b,acc[c]);
          }
        }
        float* outp = f32p(ws,wsoff::ENCP) + (size_t)s*NB*2;
        #pragma unroll
        for (int r=0;r<4;r++){
          float p0 = 0.f, p1 = 0.f;
          #pragma unroll
          for (int c=0;c<4;c++){
            float hv = acc[c][r] + b1v[c]; hv = hv>0.f ? hv : 0.f;
            p0 += hv*w20[c]; p1 += hv*w21[c];
          }
          #pragma unroll
          for (int m=1;m<16;m<<=1){ p0 += __shfl_xor(p0,m,64); p1 += __shfl_xor(p1,m,64); }
          if (lr == 0){
            const int grow = rowbase + q*4 + r;
            outp[(size_t)grow*2]   = softplusf(p0+b20);
            outp[(size_t)grow*2+1] = softplusf(p1+b21);
          }
        }
      }
      if (t < 129) gbar(ws, t+1);
    }
  }
}

// ================= decoder: weight-resident (RF + LDS), zero steady-state streaming =================
// 256 blocks x 512 thr, 32 rows/block. waves 0..6: cc=w, W0+WX1 in RF, WH1 in LDS.
// wave 7: cc7 (W0/WX1 streamed L2-hot, WH1 LDS) + cc8 ragged tile (all streamed).
// waves 5,6: MLP halves (W1 frags in RF), LDS partial-combine.
__global__ __launch_bounds__(512,2) void k_decoder(char* ws, const void* eps, const void* feat, void* out){
  extern __shared__ __align__(16) char dsm[];
  short* s_h0b = (short*)dsm;                       // [32][HDS]
  short* s_h1b = s_h0b + 32*HDS;
  float* s_ep0 = (float*)(s_h1b + 32*HDS);          // [144][10]
  float* s_ep1 = s_ep0 + 144*10;                    // [144][4]
  float* s_inp = s_ep1 + 144*4;                     // [64]
  float* s_red = s_inp + 64;                        // [2][32][2]
  short* s_wh  = (short*)(s_red + 128);             // WH1 cc0..7: unit = g*40 + cc*5 + kb

  const int isbf = *(const int*)(ws+wsoff::FLAG);
  const int tid = threadIdx.x;
  const int lane = tid & 63, w = tid >> 6, lr = lane & 15, q = lane >> 4;
  const int rowbase = blockIdx.x*32;
  constexpr size_t N0v = (size_t)NS*NB*127*2;

  const bf16* W0g  = bfp(ws,wsoff::WDHH0);
  const bf16* WX1g = bfp(ws,wsoff::WDIH1);
  const bf16* WH1g = bfp(ws,wsoff::WDHH1);

  // zero both state arrays (contiguous)
  for (int i = tid; i < 2*32*HDS; i += 512) s_h0b[i] = 0;
  // stage WH1 cc0..7 into LDS fragment units
  {
    const short* src = (const short*)(ws + wsoff::WDHH1);
    for (int idx = tid; idx < 120*512; idx += 512){
      int u = idx >> 9, le = idx & 511, ln = le >> 3, e = le & 7, lrr = ln & 15, qq = ln >> 4;
      int g = u / 40, rem = u % 40, cc = rem / 5, kb = rem % 5;
      s_wh[idx] = src[(size_t)(g*GDP + cc*16 + lrr)*HDP + kb*32 + qq*8 + e];
    }
  }
  // stage epilogue scalar tables
  {
    const float* wih = f32p(ws,wsoff::WDIH0F);
    const float* bi0 = f32p(ws,wsoff::BDIH0); const float* bh0 = f32p(ws,wsoff::BDHH0);
    const float* bi1 = f32p(ws,wsoff::BDIH1); const float* bh1 = f32p(ws,wsoff::BDHH1);
    for (int d = tid; d < 144; d += 512){
      float* e0 = s_ep0 + d*10; float* e1 = s_ep1 + d*4;
      if (d < HD){
        e0[0]=wih[(0*HD+d)*2]; e0[1]=wih[(0*HD+d)*2+1];
        e0[2]=wih[(1*HD+d)*2]; e0[3]=wih[(1*HD+d)*2+1];
        e0[4]=wih[(2*HD+d)*2]; e0[5]=wih[(2*HD+d)*2+1];
        e0[6]=bi0[d]+bh0[d]; e0[7]=bi0[HD+d]+bh0[HD+d]; e0[8]=bi0[2*HD+d]; e0[9]=bh0[2*HD+d];
        e1[0]=bi1[d]+bh1[d]; e1[1]=bi1[HD+d]+bh1[HD+d]; e1[2]=bi1[2*HD+d]; e1[3]=bh1[2*HD+d];
      } else {
        #pragma unroll
        for (int j=0;j<10;j++) e0[j]=0.f;
        #pragma unroll
        for (int j=0;j<4;j++) e1[j]=0.f;
      }
    }
  }
  if (tid < 64){
    int r0 = tid >> 1, c = tid & 1;
    int b = (rowbase + r0) & 1023;
    float v = f32p(ws,wsoff::ENCP)[((size_t)127*NB + b)*2 + c];
    s_inp[tid] = v;
    st_out(out, N0v + ((size_t)(rowbase+r0)*64)*2 + c, v, isbf);
  }
  __syncthreads();

  // per-thread fp32 master state for owned (row,d) cells + bf16 shadow writes
  float h0f[2][2][4], h1f[2][2][4];   // [pass][m][r]; pass1 used only by wave7 (cc8)
  const int npass = (w==7) ? 2 : 1;
  {
    const float* h0T = f32p(ws,wsoff::H0F0);
    const float* h1T = f32p(ws,wsoff::H1F0);
    for (int p = 0; p < npass; ++p){
      const int cc = p ? 8 : w;
      const int d = cc*16 + lr;
      #pragma unroll
      for (int m=0;m<2;m++)
        #pragma unroll
        for (int r=0;r<4;r++){
          int row = m*16 + q*4 + r, grow = rowbase + row;
          int s = grow >> 10, b = grow & 1023;
          float v0=0.f, v1=0.f;
          if (d < NH){
            float e0 = ld_any(eps, ((size_t)(s*2+0)*NB + b)*NH + d, isbf);
            float e1 = ld_any(eps, ((size_t)(s*2+1)*NB + b)*NH + d, isbf);
            v0 = e0*__expf(0.5f*h0T[(size_t)b*HE + NH + d]) + h0T[(size_t)b*HE + d];
            v1 = e1*__expf(0.5f*h1T[(size_t)b*HE + NH + d]) + h1T[(size_t)b*HE + d];
          } else if (d < HD){
            float fc = ld_any(feat, (size_t)b*3072 + 2048 + (d-NH), isbf);
            v0 = fc; v1 = fc;
          }
          h0f[p][m][r] = v0; h1f[p][m][r] = v1;
          if (d < 144){
            s_h0b[row*HDS + d] = (d < HD) ? bf16bits(v0) : (short)0;
            s_h1b[row*HDS + d] = (d < HD) ? bf16bits(v1) : (short)0;
          }
        }
    }
  }

  // RF-resident weights
  v8s w0f[3][5], wxf[3][5];
  if (w < 7){
    #pragma unroll
    for (int g=0;g<3;g++)
      #pragma unroll
      for (int kb=0;kb<5;kb++){
        size_t off = (size_t)(g*GDP + w*16 + lr)*HDP + kb*32 + q*8;
        w0f[g][kb] = fragld(W0g, off);
        wxf[g][kb] = fragld(WX1g, off);
      }
  }
  v8s w1f[2][4]; float b1v[2], w20v[2], w21v[2];
  if (w == 5 || w == 6){
    const int tb = (w-5)*2;
    const bf16* W1g = bfp(ws,wsoff::W1B);
    #pragma unroll
    for (int ct=0;ct<2;ct++){
      #pragma unroll
      for (int kb=0;kb<4;kb++)
        w1f[ct][kb] = fragld(W1g, (size_t)((tb+ct)*16+lr)*NH + kb*32 + q*8);
      b1v[ct]  = f32p(ws,wsoff::B1F)[(tb+ct)*16+lr];
      w20v[ct] = f32p(ws,wsoff::W2F)[(tb+ct)*16+lr];
      w21v[ct] = f32p(ws,wsoff::W2F)[64+(tb+ct)*16+lr];
    }
  }
  __syncthreads();

  for (int k = 0; k < 63; ++k){
    // ---- P1 matmul (d0): reads s_h0b(old) ----
    v4f p1a[3][2], p1b[3][2];
    #pragma unroll
    for (int g=0;g<3;g++){ p1a[g][0]=(v4f){0,0,0,0}; p1a[g][1]=(v4f){0,0,0,0};
                           p1b[g][0]=(v4f){0,0,0,0}; p1b[g][1]=(v4f){0,0,0,0}; }
    if (w < 7){
      #pragma unroll
      for (int m=0;m<2;m++)
        #pragma unroll
        for (int kb=0;kb<5;kb++){
          v8s A = lds_frag8(s_h0b + (m*16+lr)*HDS + kb*32 + q*8);
          #pragma unroll
          for (int g=0;g<3;g++) p1a[g][m] = mfma16(A, w0f[g][kb], p1a[g][m]);
        }
    } else {
      #pragma unroll
      for (int m=0;m<2;m++)
        #pragma unroll
        for (int kb=0;kb<5;kb++){
          v8s A = lds_frag8(s_h0b + (m*16+lr)*HDS + kb*32 + q*8);
          #pragma unroll
          for (int g=0;g<3;g++){
            p1a[g][m] = mfma16(A, fragld(W0g, (size_t)(g*GDP + 7*16 + lr)*HDP + kb*32 + q*8), p1a[g][m]);
            p1b[g][m] = mfma16(A, fragld(W0g, (size_t)(g*GDP + 8*16 + lr)*HDP + kb*32 + q*8), p1b[g][m]);
          }
        }
    }
    __syncthreads();
    // ---- P1 epilogue: writes s_h0b(new) ----
    for (int p = 0; p < npass; ++p){
      const int cc = p ? 8 : w;
      const int d = cc*16 + lr;
      const float* e0 = s_ep0 + d*10;
      float wr0=e0[0],wr1=e0[1],wz0=e0[2],wz1=e0[3],wn0=e0[4],wn1=e0[5];
      float birc=e0[6],bizc=e0[7],binb=e0[8],bhnb=e0[9];
      #pragma unroll
      for (int m=0;m<2;m++)
        #pragma unroll
        for (int r=0;r<4;r++){
          int row = m*16 + q*4 + r;
          float i0 = s_inp[row*2], i1 = s_inp[row*2+1];
          float ar = p ? p1b[0][m][r] : p1a[0][m][r];
          float az = p ? p1b[1][m][r] : p1a[1][m][r];
          float an = p ? p1b[2][m][r] : p1a[2][m][r];
          float rr = sigm(i0*wr0+i1*wr1 + ar + birc);
          float zz = sigm(i0*wz0+i1*wz1 + az + bizc);
          float nn = tanh_f(i0*wn0+i1*wn1 + binb + rr*(an + bhnb));
          float h = (1.f-zz)*nn + zz*h0f[p][m][r];
          h0f[p][m][r] = h;
          s_h0b[row*HDS + d] = (d < HD) ? bf16bits(h) : (short)0;
        }
    }
    __syncthreads();
    // ---- P2 matmul (d1): reads s_h0b(new) + s_h1b(old) ----
    v4f p2a[4][2], p2b[4][2];
    #pragma unroll
    for (int g=0;g<4;g++){ p2a[g][0]=(v4f){0,0,0,0}; p2a[g][1]=(v4f){0,0,0,0};
                           p2b[g][0]=(v4f){0,0,0,0}; p2b[g][1]=(v4f){0,0,0,0}; }
    if (w < 7){
      #pragma unroll
      for (int m=0;m<2;m++)
        #pragma unroll
        for (int kb=0;kb<5;kb++){
          v8s ax = lds_frag8(s_h0b + (m*16+lr)*HDS + kb*32 + q*8);
          v8s ah = lds_frag8(s_h1b + (m*16+lr)*HDS + kb*32 + q*8);
          #pragma unroll
          for (int g=0;g<3;g++){
            int aix = (g==2) ? 2 : g, aih = (g==2) ? 3 : g;
            p2a[aix][m] = mfma16(ax, wxf[g][kb], p2a[aix][m]);
            p2a[aih][m] = mfma16(ah, ldsfrag(s_wh, g*40 + w*5 + kb, lane), p2a[aih][m]);
          }
        }
    } else {
      #pragma unroll
      for (int m=0;m<2;m++)
        #pragma unroll
        for (int kb=0;kb<5;kb++){
          v8s ax = lds_frag8(s_h0b + (m*16+lr)*HDS + kb*32 + q*8);
          v8s ah = lds_frag8(s_h1b + (m*16+lr)*HDS + kb*32 + q*8);
          #pragma unroll
          for (int g=0;g<3;g++){
            int aix = (g==2) ? 2 : g, aih = (g==2) ? 3 : g;
            size_t o7 = (size_t)(g*GDP + 7*16 + lr)*HDP + kb*32 + q*8;
            size_t o8 = (size_t)(g*GDP + 8*16 + lr)*HDP + kb*32 + q*8;
            p2a[aix][m] = mfma16(ax, fragld(WX1g, o7), p2a[aix][m]);
            p2a[aih][m] = mfma16(ah, ldsfrag(s_wh, g*40 + 7*5 + kb, lane), p2a[aih][m]);
            p2b[aix][m] = mfma16(ax, fragld(WX1g, o8), p2b[aix][m]);
            p2b[aih][m] = mfma16(ah, fragld(WH1g, o8), p2b[aih][m]);
          }
        }
    }
    __syncthreads();
    // ---- P2 epilogue: writes s_h1b(new) ----
    for (int p = 0; p < npass; ++p){
      const int cc = p ? 8 : w;
      const int d = cc*16 + lr;
      const float* e1 = s_ep1 + d*4;
      float birc=e1[0], bizc=e1[1], binb=e1[2], bhnb=e1[3];
      #pragma unroll
      for (int m=0;m<2;m++)
        #pragma unroll
        for (int r=0;r<4;r++){
          int row = m*16 + q*4 + r;
          float ar = p ? p2b[0][m][r] : p2a[0][m][r];
          float az = p ? p2b[1][m][r] : p2a[1][m][r];
          float axn= p ? p2b[2][m][r] : p2a[2][m][r];
          float ahn= p ? p2b[3][m][r] : p2a[3][m][r];
          float rr = sigm(ar + birc);
          float zz = sigm(az + bizc);
          float nn = tanh_f(axn + binb + rr*(ahn + bhnb));
          float h = (1.f-zz)*nn + zz*h1f[p][m][r];
          h1f[p][m][r] = h;
          s_h1b[row*HDS + d] = (d < HD) ? bf16bits(h) : (short)0;
        }
    }
    __syncthreads();
    // ---- P3: MLP halves on waves 5,6 ----
    if (w == 5 || w == 6){
      v4f a3[2][2];
      #pragma unroll
      for (int ct=0;ct<2;ct++){ a3[ct][0]=(v4f){0,0,0,0}; a3[ct][1]=(v4f){0,0,0,0}; }
      #pragma unroll
      for (int m=0;m<2;m++)
        #pragma unroll
        for (int kb=0;kb<4;kb++){
          v8s A = lds_frag8(s_h1b + (m*16+lr)*HDS + kb*32 + q*8);
          #pragma unroll
          for (int ct=0;ct<2;ct++) a3[ct][m] = mfma16(A, w1f[ct][kb], a3[ct][m]);
        }
      #pragma unroll
      for (int m=0;m<2;m++)
        #pragma unroll
        for (int r=0;r<4;r++){
          float p0 = 0.f, p1 = 0.f;
          #pragma unroll
          for (int ct=0;ct<2;ct++){
            float hv = a3[ct][m][r] + b1v[ct]; hv = hv > 0.f ? hv : 0.f;
            p0 += hv*w20v[ct]; p1 += hv*w21v[ct];
          }
          #pragma unroll
          for (int mm=1;mm<16;mm<<=1){ p0 += __shfl_xor(p0,mm,64); p1 += __shfl_xor(p1,mm,64); }
          if (lr == 0){
            int row = m*16 + q*4 + r;
            s_red[(w-5)*64 + row*2]   = p0;
            s_red[(w-5)*64 + row*2+1] = p1;
          }
        }
    }
    __syncthreads();
    // ---- P4: combine + softplus + feedback + out ----
    if (tid < 64){
      int row = tid >> 1, c = tid & 1;
      float p = s_red[row*2 + c] + s_red[64 + row*2 + c];
      float v = softplusf(p + f32p(ws,wsoff::B2F)[c]);
      s_inp[tid] = v;
      st_out(out, N0v + ((size_t)(rowbase+row)*64 + (k+1))*2 + c, v, isbf);
    }
    __syncthreads();
  }
}

// ---------- encoder-part output assembly ----------
__global__ void k_assemble_enc(char* ws, void* out){
  int isbf = *(const int*)(ws+wsoff::FLAG);
  const float* encp = f32p(ws,wsoff::ENCP);
  constexpr size_t N0v = (size_t)NS*NB*127*2;
  for (size_t i = (size_t)blockIdx.x*blockDim.x + threadIdx.x; i < N0v;
       i += (size_t)gridDim.x*blockDim.x){
    int c = (int)(i & 1); size_t qq = i >> 1;
    int tt = (int)(qq % 127); size_t q2 = qq / 127; int b = (int)(q2 & 1023);
    st_out(out, i, encp[((size_t)tt*NB + b)*2 + c], isbf);
  }
}

extern "C" void kernel_launch(void* const* d_in, const int* in_sizes, int n_in,
                              void* d_out, int out_size, void* d_ws, size_t ws_size,
                              hipStream_t stream) {
  char* ws = (char*)d_ws;
  const int* mask = (const int*)d_in[2];
  auto gb = [](size_t n){ return dim3((unsigned)((n + 255)/256)); };

  hipMemsetAsync(ws+wsoff::BAR,  0, 1024, stream);
  hipMemsetAsync(ws+wsoff::H0B0, 0, (size_t)NB*HE*2, stream);
  hipMemsetAsync(ws+wsoff::H1B0, 0, (size_t)NB*HE*2, stream);

  k_detect<<<1,64,0,stream>>>(ws, d_in[3]);

  k_stage_xs <<<gb((size_t)NT*NB*KX),256,0,stream>>>(ws, d_in[0], d_in[1]);
  k_stage_pad<<<gb(768*32) ,256,0,stream>>>(ws, d_in[7],  wsoff::WIH0, 768, 18, 32);
  k_stage_pad<<<gb(768*256),256,0,stream>>>(ws, d_in[8],  wsoff::WHH0, 768, 256, 256);
  k_stage_pad<<<gb(768*256),256,0,stream>>>(ws, d_in[11], wsoff::WIH1, 768, 256, 256);
  k_stage_pad<<<gb(768*256),256,0,stream>>>(ws, d_in[12], wsoff::WHH1, 768, 256, 256);
  k_stage_pad<<<gb(64*128) ,256,0,stream>>>(ws, d_in[23], wsoff::W1B,  64, 128, 128);
  k_stage_dec<<<gb(432*HDP),256,0,stream>>>(ws, d_in[16], wsoff::WDHH0);
  k_stage_dec<<<gb(432*HDP),256,0,stream>>>(ws, d_in[19], wsoff::WDIH1);
  k_stage_dec<<<gb(432*HDP),256,0,stream>>>(ws, d_in[20], wsoff::WDHH1);

  SmallSegs ss;
  const void* srcs[12] = {d_in[9],d_in[10],d_in[13],d_in[14],d_in[15],
                          d_in[17],d_in[18],d_in[21],d_in[22],
                          d_in[24],d_in[25],d_in[26]};
  const size_t offs[12] = {wsoff::BIH0,wsoff::BHH0,wsoff::BIH1,wsoff::BHH1,wsoff::WDIH0F,
                           wsoff::BDIH0,wsoff::BDHH0,wsoff::BDIH1,wsoff::BDHH1,
                           wsoff::B1F,wsoff::W2F,wsoff::B2F};
  const int ns[12] = {768,768,768,768,792,396,396,396,396,64,128,2};
  for (int i=0;i<12;i++){ ss.src[i]=srcs[i]; ss.dstoff[i]=(int)offs[i]; ss.n[i]=ns[i]; }
  k_stage_small<<<12,256,0,stream>>>(ws, ss);

  hipFuncSetAttribute(reinterpret_cast<const void*>(k_encoder),
                      hipFuncAttributeMaxDynamicSharedMemorySize, 143360);
  // decoder LDS: state 2*32*164*2=20992 + ep0 5760 + ep1 2304 + inp 256 + red 512 + wh 122880 = 152704
  hipFuncSetAttribute(reinterpret_cast<const void*>(k_decoder),
                      hipFuncAttributeMaxDynamicSharedMemorySize, 152704);

  // persistent encoder: 112 blocks, all co-resident
  k_encoder<<<EBLOCKS,256,143360,stream>>>(ws, mask);

  // decoder: batch-stationary, weights resident in RF+LDS
  k_decoder<<<256,512,152704,stream>>>(ws, d_in[3], d_in[1], d_out);

  k_assemble_enc<<<2048,256,0,stream>>>(ws, d_out);
}

// Round 5
// 4286.676 us; speedup vs baseline: 1.7546x; 1.1266x over previous
//
#include <hip/hip_runtime.h>
#include <hip/hip_bf16.h>
#include <math.h>

typedef __hip_bfloat16 bf16;
typedef short v8s __attribute__((ext_vector_type(8)));
typedef float v4f __attribute__((ext_vector_type(4)));

#define NB   1024
#define NT   128
#define NH   128
#define HE   256
#define HD   132
#define HDP  160    // padded K for decoder weights (global)
#define HDS  164    // LDS row stride (elems) for decoder bf16 state
#define GDP  144
#define NS   8
#define SB   8192
#define KX   32
#define EBLOCKS 112

namespace wsoff {
constexpr size_t al(size_t x){ return (x + 255) & ~size_t(255); }
constexpr size_t FLAG  = 0;
constexpr size_t BARF  = 256;                 // 112 flags, 64B stride = 7168B
constexpr size_t XS    = al(BARF + 112*64);
constexpr size_t WIH0  = al(XS    + (size_t)NT*NB*KX*2);
constexpr size_t WHH0  = al(WIH0  + 768*32*2);
constexpr size_t WIH1  = al(WHH0  + 768*256*2);
constexpr size_t WHH1  = al(WIH1  + 768*256*2);
constexpr size_t BIH0  = al(WHH1  + 768*256*2);
constexpr size_t BHH0  = al(BIH0  + 768*4);
constexpr size_t BIH1  = al(BHH0  + 768*4);
constexpr size_t BHH1  = al(BIH1  + 768*4);
constexpr size_t WDHH0 = al(BHH1  + 768*4);
constexpr size_t WDIH1 = al(WDHH0 + 432*HDP*2);
constexpr size_t WDHH1 = al(WDIH1 + 432*HDP*2);
constexpr size_t WDIH0F= al(WDHH1 + 432*HDP*2);
constexpr size_t BDIH0 = al(WDIH0F+ 792*4);
constexpr size_t BDHH0 = al(BDIH0 + 396*4);
constexpr size_t BDIH1 = al(BDHH0 + 396*4);
constexpr size_t BDHH1 = al(BDIH1 + 396*4);
constexpr size_t W1B   = al(BDHH1 + 396*4);
constexpr size_t B1F   = al(W1B   + 64*128*2);
constexpr size_t W2F   = al(B1F   + 64*4);
constexpr size_t B2F   = al(W2F   + 128*4);
constexpr size_t H0F0  = al(B2F   + 2*4);     // final h0 fp32 [NB][HE]
constexpr size_t H1F0  = al(H0F0  + (size_t)NB*HE*4);
constexpr size_t H0B0  = al(H1F0  + (size_t)NB*HE*4);
constexpr size_t H0B1  = al(H0B0  + (size_t)NB*HE*2);
constexpr size_t H1B0  = al(H0B1  + (size_t)NB*HE*2);
constexpr size_t H1B1  = al(H1B0  + (size_t)NB*HE*2);
constexpr size_t ENCP  = al(H1B1  + (size_t)NB*HE*2);   // fp32 [128][1024][2]
}

// ---------- helpers ----------
__device__ __forceinline__ float ld_any(const void* p, size_t i, int isbf){
  return isbf ? __bfloat162float(((const bf16*)p)[i]) : ((const float*)p)[i];
}
__device__ __forceinline__ void st_out(void* out, size_t i, float v, int isbf){
  if (isbf) ((bf16*)out)[i] = __float2bfloat16(v); else ((float*)out)[i] = v;
}
__device__ __forceinline__ float sigm(float x){ return 1.0f/(1.0f + __expf(-x)); }
__device__ __forceinline__ float tanh_f(float x){
  float t = __expf(2.0f*x); return 1.0f - 2.0f/(t+1.0f);
}
__device__ __forceinline__ float softplusf(float x){ return x>20.f ? x : log1pf(__expf(x)); }
__device__ __forceinline__ v4f mfma16(v8s a, v8s b, v4f c){
  return __builtin_amdgcn_mfma_f32_16x16x32_bf16(a,b,c,0,0,0);
}
__device__ __forceinline__ v8s fragld(const bf16* base, size_t elem_off){
  return *reinterpret_cast<const v8s*>(base + elem_off);
}
__device__ __forceinline__ v8s ldsfrag(const short* sm, int unit, int lane){
  return *reinterpret_cast<const v8s*>(sm + (unit<<9) + (lane<<3));
}
__device__ __forceinline__ v8s lds_frag8(const short* p){
  union { long long l[2]; v8s s; } r;
  r.l[0] = *(const long long*)(p);
  r.l[1] = *(const long long*)(p + 4);
  return r.s;
}
__device__ __forceinline__ short bf16bits(float v){
  bf16 h = __float2bfloat16(v); short s; __builtin_memcpy(&s,&h,2); return s;
}
// coherent (agent-scope, relaxed) 16B load as 2x qword
__device__ __forceinline__ v8s ldg_coh16(const bf16* p){
  union { unsigned long long u[2]; v8s s; } r;
  const unsigned long long* q = (const unsigned long long*)p;
  r.u[0] = __hip_atomic_load(q+0, __ATOMIC_RELAXED, __HIP_MEMORY_SCOPE_AGENT);
  r.u[1] = __hip_atomic_load(q+1, __ATOMIC_RELAXED, __HIP_MEMORY_SCOPE_AGENT);
  return r.s;
}
__device__ __forceinline__ void stg_coh_pair(bf16* base_even, int lr, float v){
  bf16 h = __float2bfloat16(v);
  unsigned vv; { unsigned short b; __builtin_memcpy(&b, &h, 2); vv = b; }
  unsigned ov = (unsigned)__shfl_xor((int)vv, 1, 64);
  if (!(lr & 1))
    __hip_atomic_store((unsigned*)base_even, vv | (ov<<16), __ATOMIC_RELAXED, __HIP_MEMORY_SCOPE_AGENT);
}
__device__ __forceinline__ float*  f32p(char* ws, size_t off){ return (float*)(ws+off); }
__device__ __forceinline__ bf16*   bfp (char* ws, size_t off){ return (bf16*)(ws+off); }
__device__ __forceinline__ bf16*   H0Bp(char* ws,int p){ return bfp (ws, p?wsoff::H0B1:wsoff::H0B0); }
__device__ __forceinline__ bf16*   H1Bp(char* ws,int p){ return bfp (ws, p?wsoff::H1B1:wsoff::H1B0); }

// ---------- dataflow flags ----------
__device__ __forceinline__ int* flagp(char* ws, int idx){
  return (int*)(ws + wsoff::BARF + (size_t)idx*64);
}
__device__ __forceinline__ void pollge(int* f, int v){
  while (__hip_atomic_load(f, __ATOMIC_RELAXED, __HIP_MEMORY_SCOPE_AGENT) < v)
    __builtin_amdgcn_s_sleep(2);
}
__device__ __forceinline__ void flagst(int* f, int v){
  __hip_atomic_store(f, v, __ATOMIC_RELAXED, __HIP_MEMORY_SCOPE_AGENT);
}

// ---------- dtype detection ----------
__global__ void k_detect(char* ws, const void* eps){
  const unsigned short* p = (const unsigned short*)eps;
  int lane = threadIdx.x;
  unsigned short u = p[2*lane];
  int e = (u>>7)&0xFF;
  bool pl = (e>=118 && e<=130);
  unsigned long long m = __ballot(pl);
  if (lane==0) *(int*)(ws+wsoff::FLAG) = (__popcll(m) >= 32) ? 1 : 0;
}

// ---------- staging ----------
__global__ void k_stage_xs(char* ws, const void* x, const void* feat){
  int isbf = *(const int*)(ws+wsoff::FLAG);
  size_t i = (size_t)blockIdx.x*blockDim.x + threadIdx.x;
  if (i >= (size_t)NT*NB*KX) return;
  int c = i % KX; size_t q = i / KX; int b = q % NB; int t = q / NB;
  float v = 0.f;
  if (c < 2)        v = ld_any(x,    ((size_t)b*NT + t)*2 + c, isbf);
  else if (c < 18)  v = ld_any(feat, ((size_t)b*192 + t)*16 + (c-2), isbf);
  ((bf16*)(ws+wsoff::XS))[i] = __float2bfloat16(v);
}
__global__ void k_stage_pad(char* ws, const void* src, size_t dstoff, int R, int SC, int DC){
  int isbf = *(const int*)(ws+wsoff::FLAG);
  size_t i = (size_t)blockIdx.x*blockDim.x + threadIdx.x;
  if (i >= (size_t)R*DC) return;
  int r = i / DC, c = i % DC;
  float v = (c < SC) ? ld_any(src, (size_t)r*SC + c, isbf) : 0.f;
  ((bf16*)(ws+dstoff))[i] = __float2bfloat16(v);
}
__global__ void k_stage_dec(char* ws, const void* src, size_t dstoff){
  int isbf = *(const int*)(ws+wsoff::FLAG);
  size_t i = (size_t)blockIdx.x*blockDim.x + threadIdx.x;
  if (i >= (size_t)432*HDP) return;
  int R = i / HDP, c = i % HDP;
  int g = R / GDP, ii = R % GDP;
  float v = (ii < HD && c < HD) ? ld_any(src, ((size_t)(g*HD+ii))*HD + c, isbf) : 0.f;
  ((bf16*)(ws+dstoff))[i] = __float2bfloat16(v);
}
struct SmallSegs { const void* src[12]; int dstoff[12]; int n[12]; };
__global__ void k_stage_small(char* ws, SmallSegs segs){
  int isbf = *(const int*)(ws+wsoff::FLAG);
  int s = blockIdx.x;
  float* dst = (float*)(ws + (size_t)segs.dstoff[s]);
  for (int i = threadIdx.x; i < segs.n[s]; i += blockDim.x)
    dst[i] = ld_any(segs.src[s], i, isbf);
}

// ================= persistent encoder: dataflow, no global barrier =================
// blocks 0..31  L0: rb=bid>>2 (128 rows), cb=bid&3 (64 cols). flag idx = bid.
// blocks 32..95 L1: rb=(bid-32)>>3, cb=(bid-32)&7 (32 cols). flag idx = bid.
// blocks 96..111 MLP: mb=bid-96 (64 rows), rb=mb>>1. flag idx = bid.
__global__ __launch_bounds__(256,1) void k_encoder(char* ws, const int* mask){
  extern __shared__ __align__(16) char smem[];
  const int bid = blockIdx.x, tid = threadIdx.x;
  const int lane = tid & 63, w = tid >> 6, lr = lane & 15, q = lane >> 4;

  if (bid < 32){
    // ---- LAYER0 ----
    const int rb = bid >> 2, cb = bid & 3;
    short* wsm = (short*)smem;
    float* hf  = (float*)(smem + 110592);
    const short* WH = (const short*)(ws + wsoff::WHH0);
    const short* WI = (const short*)(ws + wsoff::WIH0);
    for (int idx = tid; idx < 108*512; idx += 256){
      int u = idx >> 9, le = idx & 511, ln = le >> 3, j = le & 7, lrr = ln & 15, qq = ln >> 4;
      int g = u / 36, rem = u % 36, ct = rem / 9, kb = rem % 9;
      int row = g*HE + cb*64 + ct*16 + lrr;
      wsm[idx] = (kb < 8) ? WH[(size_t)row*256 + kb*32 + qq*8 + j]
                          : WI[(size_t)row*32  + qq*8 + j];
    }
    for (int idx = tid; idx < 128*64; idx += 256) hf[idx] = 0.f;
    const float* bih = f32p(ws,wsoff::BIH0);
    const float* bhh = f32p(ws,wsoff::BHH0);
    float birv[4], bizv[4], binv[4], bhnv[4];
    #pragma unroll
    for (int ct=0;ct<4;ct++){
      int d = cb*64 + ct*16 + lr;
      birv[ct]=bih[d]+bhh[d]; bizv[ct]=bih[HE+d]+bhh[HE+d];
      binv[ct]=bih[2*HE+d];   bhnv[ct]=bhh[2*HE+d];
    }
    __syncthreads();
    const int rowloc = w*32, rowg = rb*128 + rowloc;
    float* hTf = f32p(ws, wsoff::H0F0);
    for (int t = 0; t < 128; ++t){
      // waits: L0 siblings >= t (h0(t-1) ready); L1 of rb >= t-1 (buffer reuse)
      if (tid < 12){
        if (tid < 4){ if (tid != cb) pollge(flagp(ws, rb*4+tid), t); }
        else pollge(flagp(ws, 32 + rb*8 + (tid-4)), t-1);
      }
      __syncthreads();
      const bf16* hbO = H0Bp(ws, t&1);
      bf16* hbN = H0Bp(ws, (t+1)&1);
      const bf16* Xs = bfp(ws,wsoff::XS) + (size_t)t*NB*KX;
      // prefetch A-state (all loads issued before MFMA)
      v8s hA0[8], hA1[8];
      v8s x0 = fragld(Xs, (size_t)(rowg+lr)*KX + q*8);
      v8s x1 = fragld(Xs, (size_t)(rowg+16+lr)*KX + q*8);
      #pragma unroll
      for (int kb=0;kb<8;kb++){
        hA0[kb] = ldg_coh16(hbO + (size_t)(rowg+lr)*HE + kb*32 + q*8);
        hA1[kb] = ldg_coh16(hbO + (size_t)(rowg+16+lr)*HE + kb*32 + q*8);
      }
      v4f accr[2][4], accz[2][4], acchn[2][4], accxn[2][4];
      #pragma unroll
      for (int mt=0;mt<2;mt++)
        #pragma unroll
        for (int ct=0;ct<4;ct++){
          accr[mt][ct]=(v4f){0,0,0,0}; accz[mt][ct]=(v4f){0,0,0,0};
          acchn[mt][ct]=(v4f){0,0,0,0}; accxn[mt][ct]=(v4f){0,0,0,0};
        }
      #pragma unroll
      for (int g=0;g<3;g++)
        #pragma unroll
        for (int ct=0;ct<4;ct++){
          v8s b = ldsfrag(wsm, (g*4+ct)*9 + 8, lane);
          v4f* A0 = (g==0)?&accr[0][ct]:(g==1)?&accz[0][ct]:&accxn[0][ct];
          v4f* A1 = (g==0)?&accr[1][ct]:(g==1)?&accz[1][ct]:&accxn[1][ct];
          *A0 = mfma16(x0,b,*A0); *A1 = mfma16(x1,b,*A1);
        }
      #pragma unroll
      for (int kb=0;kb<8;kb++){
        #pragma unroll
        for (int g=0;g<3;g++)
          #pragma unroll
          for (int ct=0;ct<4;ct++){
            v8s b = ldsfrag(wsm, (g*4+ct)*9 + kb, lane);
            v4f* A0 = (g==0)?&accr[0][ct]:(g==1)?&accz[0][ct]:&acchn[0][ct];
            v4f* A1 = (g==0)?&accr[1][ct]:(g==1)?&accz[1][ct]:&acchn[1][ct];
            *A0 = mfma16(hA0[kb],b,*A0); *A1 = mfma16(hA1[kb],b,*A1);
          }
      }
      int mk[2][4];
      #pragma unroll
      for (int mt=0;mt<2;mt++)
        #pragma unroll
        for (int r=0;r<4;r++)
          mk[mt][r] = mask[(size_t)(rowg + mt*16 + q*4 + r)*NT + t];
      #pragma unroll
      for (int ct=0;ct<4;ct++){
        const int d = cb*64 + ct*16 + lr;
        #pragma unroll
        for (int mt=0;mt<2;mt++)
          #pragma unroll
          for (int r=0;r<4;r++){
            const int rl = rowloc + mt*16 + q*4 + r;
            float rr = sigm(accr[mt][ct][r] + birv[ct]);
            float zz = sigm(accz[mt][ct][r] + bizv[ct]);
            float nn = tanh_f(accxn[mt][ct][r] + binv[ct] + rr*(acchn[mt][ct][r]+bhnv[ct]));
            float ho = hf[rl*64 + ct*16 + lr];
            float hv = (1.f-zz)*nn + zz*ho;
            float h2 = mk[mt][r] ? hv : ho;
            hf[rl*64 + ct*16 + lr] = h2;
            stg_coh_pair(hbN + ((size_t)(rb*128+rl)*HE + (d & ~1)), lr, h2);
            if (t == 127) hTf[(size_t)(rb*128+rl)*HE + d] = h2;
          }
      }
      __syncthreads();   // drains state stores (vmcnt) before flag bump
      if (tid == 0) flagst(flagp(ws, bid), t+1);
    }
  } else if (bid < 96){
    // ---- LAYER1 ----
    const int id = bid - 32, rb = id >> 3, cb = id & 7;
    short* wsm = (short*)smem;
    float* hf  = (float*)(smem + 98304);
    const short* WX = (const short*)(ws + wsoff::WIH1);
    const short* WHs= (const short*)(ws + wsoff::WHH1);
    for (int idx = tid; idx < 96*512; idx += 256){
      int u = idx >> 9, le = idx & 511, ln = le >> 3, j = le & 7, lrr = ln & 15, qq = ln >> 4;
      int g = u / 32, rem = u % 32, ct = rem >> 4, kb = rem & 15;
      int row = g*HE + cb*32 + ct*16 + lrr;
      wsm[idx] = (kb < 8) ? WX [(size_t)row*256 + kb*32 + qq*8 + j]
                          : WHs[(size_t)row*256 + (kb-8)*32 + qq*8 + j];
    }
    for (int idx = tid; idx < 128*32; idx += 256) hf[idx] = 0.f;
    const float* bih = f32p(ws,wsoff::BIH1);
    const float* bhh = f32p(ws,wsoff::BHH1);
    float birv[2], bizv[2], binv[2], bhnv[2];
    #pragma unroll
    for (int ct=0;ct<2;ct++){
      int d = cb*32 + ct*16 + lr;
      birv[ct]=bih[d]+bhh[d]; bizv[ct]=bih[HE+d]+bhh[HE+d];
      binv[ct]=bih[2*HE+d];   bhnv[ct]=bhh[2*HE+d];
    }
    __syncthreads();
    const int rowloc = w*32, rowg = rb*128 + rowloc;
    float* hTf = f32p(ws, wsoff::H1F0);
    for (int s = 0; s < 128; ++s){
      // waits: L0 of rb >= s+1 (h0(s)); L1 siblings >= s (h1(s-1)); MLP of rb >= s-1 (buffer reuse)
      if (tid < 14){
        if (tid < 4) pollge(flagp(ws, rb*4+tid), s+1);
        else if (tid < 12){ if (tid-4 != cb) pollge(flagp(ws, 32 + rb*8 + (tid-4)), s); }
        else pollge(flagp(ws, 96 + rb*2 + (tid-12)), s-1);
      }
      __syncthreads();
      const bf16* Ax = H0Bp(ws, (s+1)&1);
      const bf16* Ah = H1Bp(ws, s&1);
      bf16* hbN = H1Bp(ws, (s+1)&1);
      // prefetch all 32 A-frags
      v8s Ax0[8], Ax1[8], Ah0[8], Ah1[8];
      #pragma unroll
      for (int kb=0;kb<8;kb++){
        Ax0[kb] = ldg_coh16(Ax + (size_t)(rowg+lr)*HE + kb*32 + q*8);
        Ax1[kb] = ldg_coh16(Ax + (size_t)(rowg+16+lr)*HE + kb*32 + q*8);
        Ah0[kb] = ldg_coh16(Ah + (size_t)(rowg+lr)*HE + kb*32 + q*8);
        Ah1[kb] = ldg_coh16(Ah + (size_t)(rowg+16+lr)*HE + kb*32 + q*8);
      }
      v4f accr[2][2], accz[2][2], accxn[2][2], acchn[2][2];
      #pragma unroll
      for (int mt=0;mt<2;mt++)
        #pragma unroll
        for (int ct=0;ct<2;ct++){
          accr[mt][ct]=(v4f){0,0,0,0}; accz[mt][ct]=(v4f){0,0,0,0};
          accxn[mt][ct]=(v4f){0,0,0,0}; acchn[mt][ct]=(v4f){0,0,0,0};
        }
      #pragma unroll
      for (int kb=0;kb<8;kb++){
        #pragma unroll
        for (int g=0;g<3;g++)
          #pragma unroll
          for (int ct=0;ct<2;ct++){
            v8s bx = ldsfrag(wsm, (g*2+ct)*16 + kb, lane);
            v8s bh = ldsfrag(wsm, (g*2+ct)*16 + 8 + kb, lane);
            v4f* X0 = (g==0)?&accr[0][ct]:(g==1)?&accz[0][ct]:&accxn[0][ct];
            v4f* X1 = (g==0)?&accr[1][ct]:(g==1)?&accz[1][ct]:&accxn[1][ct];
            v4f* H0v= (g==0)?&accr[0][ct]:(g==1)?&accz[0][ct]:&acchn[0][ct];
            v4f* H1v= (g==0)?&accr[1][ct]:(g==1)?&accz[1][ct]:&acchn[1][ct];
            *X0 = mfma16(Ax0[kb],bx,*X0); *X1 = mfma16(Ax1[kb],bx,*X1);
            *H0v= mfma16(Ah0[kb],bh,*H0v); *H1v= mfma16(Ah1[kb],bh,*H1v);
          }
      }
      int mk[2][4];
      #pragma unroll
      for (int mt=0;mt<2;mt++)
        #pragma unroll
        for (int r=0;r<4;r++)
          mk[mt][r] = mask[(size_t)(rowg + mt*16 + q*4 + r)*NT + s];
      #pragma unroll
      for (int ct=0;ct<2;ct++){
        const int d = cb*32 + ct*16 + lr;
        #pragma unroll
        for (int mt=0;mt<2;mt++)
          #pragma unroll
          for (int r=0;r<4;r++){
            const int rl = rowloc + mt*16 + q*4 + r;
            float rr = sigm(accr[mt][ct][r] + birv[ct]);
            float zz = sigm(accz[mt][ct][r] + bizv[ct]);
            float nn = tanh_f(accxn[mt][ct][r] + binv[ct] + rr*(acchn[mt][ct][r]+bhnv[ct]));
            float ho = hf[rl*32 + ct*16 + lr];
            float hv = (1.f-zz)*nn + zz*ho;
            float h2 = mk[mt][r] ? hv : ho;
            hf[rl*32 + ct*16 + lr] = h2;
            stg_coh_pair(hbN + ((size_t)(rb*128+rl)*HE + (d & ~1)), lr, h2);
            if (s == 127) hTf[(size_t)(rb*128+rl)*HE + d] = h2;
          }
      }
      __syncthreads();
      if (tid == 0) flagst(flagp(ws, bid), s+1);
    }
  } else {
    // ---- MLP ----
    const int mb = bid - 96, rb = mb >> 1;
    short* wsm = (short*)smem;
    const short* W1s = (const short*)(ws + wsoff::W1B);
    for (int idx = tid; idx < 16*512; idx += 256){
      int u = idx >> 9, le = idx & 511, ln = le >> 3, j = le & 7, lrr = ln & 15, qq = ln >> 4;
      int c = u >> 2, kb = u & 3;
      wsm[idx] = W1s[(size_t)(c*16 + lrr)*NH + kb*32 + qq*8 + j];
    }
    float b1v[4], w20[4], w21[4];
    const float* B1 = f32p(ws,wsoff::B1F);
    const float* W2 = f32p(ws,wsoff::W2F);
    const float* B2 = f32p(ws,wsoff::B2F);
    #pragma unroll
    for (int c=0;c<4;c++){ int col=c*16+lr; b1v[c]=B1[col]; w20[c]=W2[col]; w21[c]=W2[64+col]; }
    const float b20 = B2[0], b21 = B2[1];
    __syncthreads();
    const int rowbase = mb*64 + w*16, rowA = rowbase + lr;
    for (int s = 0; s < 128; ++s){
      if (tid < 8) pollge(flagp(ws, 32 + rb*8 + tid), s+1);
      __syncthreads();
      const bf16* A = H1Bp(ws, (s+1)&1);
      const bool valid = mask[(size_t)rowA*NT + s] != 0;
      v8s af[4];
      #pragma unroll
      for (int kb=0;kb<4;kb++)
        af[kb] = valid ? ldg_coh16(A + (size_t)rowA*HE + kb*32 + q*8) : (v8s){0,0,0,0,0,0,0,0};
      v4f acc[4];
      #pragma unroll
      for (int c=0;c<4;c++) acc[c]=(v4f){0,0,0,0};
      #pragma unroll
      for (int kb=0;kb<4;kb++)
        #pragma unroll
        for (int c=0;c<4;c++)
          acc[c] = mfma16(af[kb], ldsfrag(wsm, c*4 + kb, lane), acc[c]);
      float* outp = f32p(ws,wsoff::ENCP) + (size_t)s*NB*2;
      #pragma unroll
      for (int r=0;r<4;r++){
        float p0 = 0.f, p1 = 0.f;
        #pragma unroll
        for (int c=0;c<4;c++){
          float hv = acc[c][r] + b1v[c]; hv = hv>0.f ? hv : 0.f;
          p0 += hv*w20[c]; p1 += hv*w21[c];
        }
        #pragma unroll
        for (int m=1;m<16;m<<=1){ p0 += __shfl_xor(p0,m,64); p1 += __shfl_xor(p1,m,64); }
        if (lr == 0){
          const int grow = rowbase + q*4 + r;
          outp[(size_t)grow*2]   = softplusf(p0+b20);
          outp[(size_t)grow*2+1] = softplusf(p1+b21);
        }
      }
      __syncthreads();
      if (tid == 0) flagst(flagp(ws, bid), s+1);
    }
  }
}

// ================= decoder: fully weight-resident, no dynamic-index spills =================
// 256 blocks x 512 thr, 32 rows/block. wave w: cc=w resident in RF (W0,WX1);
// wave 7 additionally cc8 in RF. WH1 (cc0..8) in LDS. waves 5,6: MLP halves.
__global__ __launch_bounds__(512,1) void k_decoder(char* ws, const void* eps, const void* feat, void* out){
  extern __shared__ __align__(16) char dsm[];
  short* s_h0b = (short*)dsm;                       // [32][HDS]
  short* s_h1b = s_h0b + 32*HDS;                    // +10496B
  float* s_inp = (float*)(dsm + 20992);             // [64]
  float* s_red = s_inp + 64;                        // [128]
  short* s_wh  = (short*)(dsm + 21760);             // 135 units (cc0..7: g*40+cc*5+kb; cc8: 120+g*5+kb)

  const int isbf = *(const int*)(ws+wsoff::FLAG);
  const int tid = threadIdx.x;
  const int lane = tid & 63, w = tid >> 6, lr = lane & 15, q = lane >> 4;
  const int rowbase = blockIdx.x*32;
  constexpr size_t N0v = (size_t)NS*NB*127*2;

  const bf16* W0g  = bfp(ws,wsoff::WDHH0);
  const bf16* WX1g = bfp(ws,wsoff::WDIH1);

  for (int i = tid; i < 2*32*HDS; i += 512) s_h0b[i] = 0;
  {
    const short* src = (const short*)(ws + wsoff::WDHH1);
    for (int idx = tid; idx < 135*512; idx += 512){
      int u = idx >> 9, le = idx & 511, ln = le >> 3, e = le & 7, lrr = ln & 15, qq = ln >> 4;
      int g, cc, kb;
      if (u < 120){ g = u / 40; cc = (u % 40) / 5; kb = u % 5; }
      else        { int u2 = u - 120; g = u2 / 5; cc = 8; kb = u2 % 5; }
      s_wh[idx] = src[(size_t)(g*GDP + cc*16 + lrr)*HDP + kb*32 + qq*8 + e];
    }
  }
  if (tid < 64){
    int r0 = tid >> 1, c = tid & 1;
    int b = (rowbase + r0) & 1023;
    float v = f32p(ws,wsoff::ENCP)[((size_t)127*NB + b)*2 + c];
    s_inp[tid] = v;
    st_out(out, N0v + ((size_t)(rowbase+r0)*64)*2 + c, v, isbf);
  }
  __syncthreads();

  // epilogue scalar tables in registers (pass a: d = w*16+lr < 132 always; pass b: d = 128+lr)
  float e0a[10], e1a[4], e0b[10], e1b[4];
  {
    const float* wih = f32p(ws,wsoff::WDIH0F);
    const float* bi0 = f32p(ws,wsoff::BDIH0); const float* bh0 = f32p(ws,wsoff::BDHH0);
    const float* bi1 = f32p(ws,wsoff::BDIH1); const float* bh1 = f32p(ws,wsoff::BDHH1);
    int da = w*16 + lr;
    e0a[0]=wih[(0*HD+da)*2]; e0a[1]=wih[(0*HD+da)*2+1];
    e0a[2]=wih[(1*HD+da)*2]; e0a[3]=wih[(1*HD+da)*2+1];
    e0a[4]=wih[(2*HD+da)*2]; e0a[5]=wih[(2*HD+da)*2+1];
    e0a[6]=bi0[da]+bh0[da]; e0a[7]=bi0[HD+da]+bh0[HD+da]; e0a[8]=bi0[2*HD+da]; e0a[9]=bh0[2*HD+da];
    e1a[0]=bi1[da]+bh1[da]; e1a[1]=bi1[HD+da]+bh1[HD+da]; e1a[2]=bi1[2*HD+da]; e1a[3]=bh1[2*HD+da];
    int db = 128 + lr;
    bool vb = (w == 7) && (db < HD);
    #pragma unroll
    for (int j=0;j<10;j++) e0b[j]=0.f;
    #pragma unroll
    for (int j=0;j<4;j++) e1b[j]=0.f;
    if (vb){
      e0b[0]=wih[(0*HD+db)*2]; e0b[1]=wih[(0*HD+db)*2+1];
      e0b[2]=wih[(1*HD+db)*2]; e0b[3]=wih[(1*HD+db)*2+1];
      e0b[4]=wih[(2*HD+db)*2]; e0b[5]=wih[(2*HD+db)*2+1];
      e0b[6]=bi0[db]+bh0[db]; e0b[7]=bi0[HD+db]+bh0[HD+db]; e0b[8]=bi0[2*HD+db]; e0b[9]=bh0[2*HD+db];
      e1b[0]=bi1[db]+bh1[db]; e1b[1]=bi1[HD+db]+bh1[HD+db]; e1b[2]=bi1[2*HD+db]; e1b[3]=bh1[2*HD+db];
    }
  }

  // fp32 master state (explicit pass a/b, no dynamic indexing)
  float h0a[2][4], h1a[2][4], h0b2[2][4], h1b2[2][4];
  {
    const float* h0T = f32p(ws,wsoff::H0F0);
    const float* h1T = f32p(ws,wsoff::H1F0);
    const int da = w*16 + lr;
    #pragma unroll
    for (int m=0;m<2;m++)
      #pragma unroll
      for (int r=0;r<4;r++){
        int row = m*16 + q*4 + r, grow = rowbase + row;
        int s = grow >> 10, b = grow & 1023;
        float v0=0.f, v1=0.f;
        if (da < NH){
          float e0 = ld_any(eps, ((size_t)(s*2+0)*NB + b)*NH + da, isbf);
          float e1 = ld_any(eps, ((size_t)(s*2+1)*NB + b)*NH + da, isbf);
          v0 = e0*__expf(0.5f*h0T[(size_t)b*HE + NH + da]) + h0T[(size_t)b*HE + da];
          v1 = e1*__expf(0.5f*h1T[(size_t)b*HE + NH + da]) + h1T[(size_t)b*HE + da];
        } else if (da < HD){
          float fc = ld_any(feat, (size_t)b*3072 + 2048 + (da-NH), isbf);
          v0 = fc; v1 = fc;
        }
        h0a[m][r] = v0; h1a[m][r] = v1;
        s_h0b[row*HDS + da] = (da < HD) ? bf16bits(v0) : (short)0;
        s_h1b[row*HDS + da] = (da < HD) ? bf16bits(v1) : (short)0;
        if (w == 7){
          const int db = 128 + lr;
          float w0=0.f, w1=0.f;
          if (db < HD){
            float fc = ld_any(feat, (size_t)b*3072 + 2048 + (db-NH), isbf);
            w0 = fc; w1 = fc;
          }
          h0b2[m][r] = w0; h1b2[m][r] = w1;
          s_h0b[row*HDS + db] = (db < HD) ? bf16bits(w0) : (short)0;
          s_h1b[row*HDS + db] = (db < HD) ? bf16bits(w1) : (short)0;
        }
      }
    if (w != 7){
      #pragma unroll
      for (int m=0;m<2;m++)
        #pragma unroll
        for (int r=0;r<4;r++){ h0b2[m][r]=0.f; h1b2[m][r]=0.f; }
    }
  }

  // RF-resident weights: every wave holds cc=w; wave7 additionally cc8
  v8s w0f[3][5], wxf[3][5], w0fb[3][5], wxfb[3][5];
  #pragma unroll
  for (int g=0;g<3;g++)
    #pragma unroll
    for (int kb=0;kb<5;kb++){
      size_t off = (size_t)(g*GDP + w*16 + lr)*HDP + kb*32 + q*8;
      w0f[g][kb] = fragld(W0g, off);
      wxf[g][kb] = fragld(WX1g, off);
      if (w == 7){
        size_t o8 = (size_t)(g*GDP + 8*16 + lr)*HDP + kb*32 + q*8;
        w0fb[g][kb] = fragld(W0g, o8);
        wxfb[g][kb] = fragld(WX1g, o8);
      } else { w0fb[g][kb] = (v8s){0,0,0,0,0,0,0,0}; wxfb[g][kb] = (v8s){0,0,0,0,0,0,0,0}; }
    }
  v8s w1f[2][4]; float b1v[2], w20v[2], w21v[2];
  if (w == 5 || w == 6){
    const int tb = (w-5)*2;
    const bf16* W1g = bfp(ws,wsoff::W1B);
    #pragma unroll
    for (int ct=0;ct<2;ct++){
      #pragma unroll
      for (int kb=0;kb<4;kb++)
        w1f[ct][kb] = fragld(W1g, (size_t)((tb+ct)*16+lr)*NH + kb*32 + q*8);
      b1v[ct]  = f32p(ws,wsoff::B1F)[(tb+ct)*16+lr];
      w20v[ct] = f32p(ws,wsoff::W2F)[(tb+ct)*16+lr];
      w21v[ct] = f32p(ws,wsoff::W2F)[64+(tb+ct)*16+lr];
    }
  }
  const float b20 = f32p(ws,wsoff::B2F)[0], b21 = f32p(ws,wsoff::B2F)[1];
  __syncthreads();

  const int da = w*16 + lr, db = 128 + lr;
  for (int k = 0; k < 63; ++k){
    // ---- P1 matmul ----
    v4f p1a[3][2], p1b[3][2];
    #pragma unroll
    for (int g=0;g<3;g++){ p1a[g][0]=(v4f){0,0,0,0}; p1a[g][1]=(v4f){0,0,0,0};
                           p1b[g][0]=(v4f){0,0,0,0}; p1b[g][1]=(v4f){0,0,0,0}; }
    #pragma unroll
    for (int m=0;m<2;m++)
      #pragma unroll
      for (int kb=0;kb<5;kb++){
        v8s A = lds_frag8(s_h0b + (m*16+lr)*HDS + kb*32 + q*8);
        #pragma unroll
        for (int g=0;g<3;g++) p1a[g][m] = mfma16(A, w0f[g][kb], p1a[g][m]);
        if (w == 7){
          #pragma unroll
          for (int g=0;g<3;g++) p1b[g][m] = mfma16(A, w0fb[g][kb], p1b[g][m]);
        }
      }
    __syncthreads();
    // ---- P1 epilogue ----
    #pragma unroll
    for (int m=0;m<2;m++)
      #pragma unroll
      for (int r=0;r<4;r++){
        int row = m*16 + q*4 + r;
        float i0 = s_inp[row*2], i1 = s_inp[row*2+1];
        float rr = sigm(i0*e0a[0]+i1*e0a[1] + p1a[0][m][r] + e0a[6]);
        float zz = sigm(i0*e0a[2]+i1*e0a[3] + p1a[1][m][r] + e0a[7]);
        float nn = tanh_f(i0*e0a[4]+i1*e0a[5] + e0a[8] + rr*(p1a[2][m][r] + e0a[9]));
        float h = (1.f-zz)*nn + zz*h0a[m][r];
        h0a[m][r] = h;
        s_h0b[row*HDS + da] = bf16bits(h);
      }
    if (w == 7){
      #pragma unroll
      for (int m=0;m<2;m++)
        #pragma unroll
        for (int r=0;r<4;r++){
          int row = m*16 + q*4 + r;
          float i0 = s_inp[row*2], i1 = s_inp[row*2+1];
          float rr = sigm(i0*e0b[0]+i1*e0b[1] + p1b[0][m][r] + e0b[6]);
          float zz = sigm(i0*e0b[2]+i1*e0b[3] + p1b[1][m][r] + e0b[7]);
          float nn = tanh_f(i0*e0b[4]+i1*e0b[5] + e0b[8] + rr*(p1b[2][m][r] + e0b[9]));
          float h = (1.f-zz)*nn + zz*h0b2[m][r];
          h0b2[m][r] = h;
          s_h0b[row*HDS + db] = (db < HD) ? bf16bits(h) : (short)0;
        }
    }
    __syncthreads();
    // ---- P2 matmul ----
    v4f p2a[4][2], p2b[4][2];
    #pragma unroll
    for (int g=0;g<4;g++){ p2a[g][0]=(v4f){0,0,0,0}; p2a[g][1]=(v4f){0,0,0,0};
                           p2b[g][0]=(v4f){0,0,0,0}; p2b[g][1]=(v4f){0,0,0,0}; }
    #pragma unroll
    for (int m=0;m<2;m++)
      #pragma unroll
      for (int kb=0;kb<5;kb++){
        v8s ax = lds_frag8(s_h0b + (m*16+lr)*HDS + kb*32 + q*8);
        v8s ah = lds_frag8(s_h1b + (m*16+lr)*HDS + kb*32 + q*8);
        #pragma unroll
        for (int g=0;g<3;g++){
          int aix = (g==2) ? 2 : g, aih = (g==2) ? 3 : g;
          p2a[aix][m] = mfma16(ax, wxf[g][kb], p2a[aix][m]);
          p2a[aih][m] = mfma16(ah, ldsfrag(s_wh, g*40 + w*5 + kb, lane), p2a[aih][m]);
        }
        if (w == 7){
          #pragma unroll
          for (int g=0;g<3;g++){
            int aix = (g==2) ? 2 : g, aih = (g==2) ? 3 : g;
            p2b[aix][m] = mfma16(ax, wxfb[g][kb], p2b[aix][m]);
            p2b[aih][m] = mfma16(ah, ldsfrag(s_wh, 120 + g*5 + kb, lane), p2b[aih][m]);
          }
        }
      }
    __syncthreads();
    // ---- P2 epilogue ----
    #pragma unroll
    for (int m=0;m<2;m++)
      #pragma unroll
      for (int r=0;r<4;r++){
        int row = m*16 + q*4 + r;
        float rr = sigm(p2a[0][m][r] + e1a[0]);
        float zz = sigm(p2a[1][m][r] + e1a[1]);
        float nn = tanh_f(p2a[2][m][r] + e1a[2] + rr*(p2a[3][m][r] + e1a[3]));
        float h = (1.f-zz)*nn + zz*h1a[m][r];
        h1a[m][r] = h;
        s_h1b[row*HDS + da] = bf16bits(h);
      }
    if (w == 7){
      #pragma unroll
      for (int m=0;m<2;m++)
        #pragma unroll
        for (int r=0;r<4;r++){
          int row = m*16 + q*4 + r;
          float rr = sigm(p2b[0][m][r] + e1b[0]);
          float zz = sigm(p2b[1][m][r] + e1b[1]);
          float nn = tanh_f(p2b[2][m][r] + e1b[2] + rr*(p2b[3][m][r] + e1b[3]));
          float h = (1.f-zz)*nn + zz*h1b2[m][r];
          h1b2[m][r] = h;
          s_h1b[row*HDS + db] = (db < HD) ? bf16bits(h) : (short)0;
        }
    }
    __syncthreads();
    // ---- P3: MLP halves on waves 5,6 ----
    if (w == 5 || w == 6){
      v4f a3[2][2];
      #pragma unroll
      for (int ct=0;ct<2;ct++){ a3[ct][0]=(v4f){0,0,0,0}; a3[ct][1]=(v4f){0,0,0,0}; }
      #pragma unroll
      for (int m=0;m<2;m++)
        #pragma unroll
        for (int kb=0;kb<4;kb++){
          v8s A = lds_frag8(s_h1b + (m*16+lr)*HDS + kb*32 + q*8);
          #pragma unroll
          for (int ct=0;ct<2;ct++) a3[ct][m] = mfma16(A, w1f[ct][kb], a3[ct][m]);
        }
      #pragma unroll
      for (int m=0;m<2;m++)
        #pragma unroll
        for (int r=0;r<4;r++){
          float p0 = 0.f, p1 = 0.f;
          #pragma unroll
          for (int ct=0;ct<2;ct++){
            float hv = a3[ct][m][r] + b1v[ct]; hv = hv > 0.f ? hv : 0.f;
            p0 += hv*w20v[ct]; p1 += hv*w21v[ct];
          }
          #pragma unroll
          for (int mm=1;mm<16;mm<<=1){ p0 += __shfl_xor(p0,mm,64); p1 += __shfl_xor(p1,mm,64); }
          if (lr == 0){
            int row = m*16 + q*4 + r;
            s_red[(w-5)*64 + row*2]   = p0;
            s_red[(w-5)*64 + row*2+1] = p1;
          }
        }
    }
    __syncthreads();
    // ---- P4: combine + softplus + feedback + out ----
    if (tid < 64){
      int row = tid >> 1, c = tid & 1;
      float p = s_red[row*2 + c] + s_red[64 + row*2 + c];
      float v = softplusf(p + (c ? b21 : b20));
      s_inp[tid] = v;
      st_out(out, N0v + ((size_t)(rowbase+row)*64 + (k+1))*2 + c, v, isbf);
    }
    __syncthreads();
  }
}

// ---------- encoder-part output assembly ----------
__global__ void k_assemble_enc(char* ws, void* out){
  int isbf = *(const int*)(ws+wsoff::FLAG);
  const float* encp = f32p(ws,wsoff::ENCP);
  constexpr size_t N0v = (size_t)NS*NB*127*2;
  for (size_t i = (size_t)blockIdx.x*blockDim.x + threadIdx.x; i < N0v;
       i += (size_t)gridDim.x*blockDim.x){
    int c = (int)(i & 1); size_t qq = i >> 1;
    int tt = (int)(qq % 127); size_t q2 = qq / 127; int b = (int)(q2 & 1023);
    st_out(out, i, encp[((size_t)tt*NB + b)*2 + c], isbf);
  }
}

extern "C" void kernel_launch(void* const* d_in, const int* in_sizes, int n_in,
                              void* d_out, int out_size, void* d_ws, size_t ws_size,
                              hipStream_t stream) {
  char* ws = (char*)d_ws;
  const int* mask = (const int*)d_in[2];
  auto gb = [](size_t n){ return dim3((unsigned)((n + 255)/256)); };

  hipMemsetAsync(ws+wsoff::BARF, 0, 112*64, stream);
  hipMemsetAsync(ws+wsoff::H0B0, 0, (size_t)NB*HE*2, stream);
  hipMemsetAsync(ws+wsoff::H1B0, 0, (size_t)NB*HE*2, stream);

  k_detect<<<1,64,0,stream>>>(ws, d_in[3]);

  k_stage_xs <<<gb((size_t)NT*NB*KX),256,0,stream>>>(ws, d_in[0], d_in[1]);
  k_stage_pad<<<gb(768*32) ,256,0,stream>>>(ws, d_in[7],  wsoff::WIH0, 768, 18, 32);
  k_stage_pad<<<gb(768*256),256,0,stream>>>(ws, d_in[8],  wsoff::WHH0, 768, 256, 256);
  k_stage_pad<<<gb(768*256),256,0,stream>>>(ws, d_in[11], wsoff::WIH1, 768, 256, 256);
  k_stage_pad<<<gb(768*256),256,0,stream>>>(ws, d_in[12], wsoff::WHH1, 768, 256, 256);
  k_stage_pad<<<gb(64*128) ,256,0,stream>>>(ws, d_in[23], wsoff::W1B,  64, 128, 128);
  k_stage_dec<<<gb(432*HDP),256,0,stream>>>(ws, d_in[16], wsoff::WDHH0);
  k_stage_dec<<<gb(432*HDP),256,0,stream>>>(ws, d_in[19], wsoff::WDIH1);
  k_stage_dec<<<gb(432*HDP),256,0,stream>>>(ws, d_in[20], wsoff::WDHH1);

  SmallSegs ss;
  const void* srcs[12] = {d_in[9],d_in[10],d_in[13],d_in[14],d_in[15],
                          d_in[17],d_in[18],d_in[21],d_in[22],
                          d_in[24],d_in[25],d_in[26]};
  const size_t offs[12] = {wsoff::BIH0,wsoff::BHH0,wsoff::BIH1,wsoff::BHH1,wsoff::WDIH0F,
                           wsoff::BDIH0,wsoff::BDHH0,wsoff::BDIH1,wsoff::BDHH1,
                           wsoff::B1F,wsoff::W2F,wsoff::B2F};
  const int ns[12] = {768,768,768,768,792,396,396,396,396,64,128,2};
  for (int i=0;i<12;i++){ ss.src[i]=srcs[i]; ss.dstoff[i]=(int)offs[i]; ss.n[i]=ns[i]; }
  k_stage_small<<<12,256,0,stream>>>(ws, ss);

  hipFuncSetAttribute(reinterpret_cast<const void*>(k_encoder),
                      hipFuncAttributeMaxDynamicSharedMemorySize, 143360);
  hipFuncSetAttribute(reinterpret_cast<const void*>(k_decoder),
                      hipFuncAttributeMaxDynamicSharedMemorySize, 160000);

  // persistent encoder: 112 blocks, all co-resident (1 block/CU by LDS)
  k_encoder<<<EBLOCKS,256,143360,stream>>>(ws, mask);

  // decoder: batch-stationary, fully weight-resident
  k_decoder<<<256,512,160000,stream>>>(ws, d_in[3], d_in[1], d_out);

  k_assemble_enc<<<2048,256,0,stream>>>(ws, d_out);
}

// Round 6
// 3928.235 us; speedup vs baseline: 1.9147x; 1.0912x over previous
//
#include <hip/hip_runtime.h>
#include <hip/hip_bf16.h>
#include <math.h>

typedef __hip_bfloat16 bf16;
typedef short v8s __attribute__((ext_vector_type(8)));
typedef float v4f __attribute__((ext_vector_type(4)));

#define NB   1024
#define NT   128
#define NH   128
#define HE   256
#define HD   132
#define HDP  160    // padded K for decoder weights (global)
#define HDS  164    // LDS row stride (elems) for decoder bf16 state
#define GDP  144
#define NS   8
#define SB   8192
#define KX   32
#define EBLOCKS 112

namespace wsoff {
constexpr size_t al(size_t x){ return (x + 255) & ~size_t(255); }
constexpr size_t FLAG  = 0;
constexpr size_t BARF  = 256;                 // 112 flags, 64B stride = 7168B
constexpr size_t XS    = al(BARF + 112*64);
constexpr size_t WIH0  = al(XS    + (size_t)NT*NB*KX*2);
constexpr size_t WHH0  = al(WIH0  + 768*32*2);
constexpr size_t WIH1  = al(WHH0  + 768*256*2);
constexpr size_t WHH1  = al(WIH1  + 768*256*2);
constexpr size_t BIH0  = al(WHH1  + 768*256*2);
constexpr size_t BHH0  = al(BIH0  + 768*4);
constexpr size_t BIH1  = al(BHH0  + 768*4);
constexpr size_t BHH1  = al(BIH1  + 768*4);
constexpr size_t WDHH0 = al(BHH1  + 768*4);
constexpr size_t WDIH1 = al(WDHH0 + 432*HDP*2);
constexpr size_t WDHH1 = al(WDIH1 + 432*HDP*2);
constexpr size_t WDIH0F= al(WDHH1 + 432*HDP*2);
constexpr size_t BDIH0 = al(WDIH0F+ 792*4);
constexpr size_t BDHH0 = al(BDIH0 + 396*4);
constexpr size_t BDIH1 = al(BDHH0 + 396*4);
constexpr size_t BDHH1 = al(BDIH1 + 396*4);
constexpr size_t W1B   = al(BDHH1 + 396*4);
constexpr size_t B1F   = al(W1B   + 64*128*2);
constexpr size_t W2F   = al(B1F   + 64*4);
constexpr size_t B2F   = al(W2F   + 128*4);
constexpr size_t H0F0  = al(B2F   + 2*4);     // final h0 fp32 [NB][HE]
constexpr size_t H1F0  = al(H0F0  + (size_t)NB*HE*4);
constexpr size_t H0B0  = al(H1F0  + (size_t)NB*HE*4);
constexpr size_t H0B1  = al(H0B0  + (size_t)NB*HE*2);
constexpr size_t H1B0  = al(H0B1  + (size_t)NB*HE*2);
constexpr size_t H1B1  = al(H1B0  + (size_t)NB*HE*2);
constexpr size_t ENCP  = al(H1B1  + (size_t)NB*HE*2);   // fp32 [128][1024][2]
}

// ---------- helpers ----------
__device__ __forceinline__ float ld_any(const void* p, size_t i, int isbf){
  return isbf ? __bfloat162float(((const bf16*)p)[i]) : ((const float*)p)[i];
}
__device__ __forceinline__ void st_out(void* out, size_t i, float v, int isbf){
  if (isbf) ((bf16*)out)[i] = __float2bfloat16(v); else ((float*)out)[i] = v;
}
__device__ __forceinline__ float sigm(float x){ return 1.0f/(1.0f + __expf(-x)); }
__device__ __forceinline__ float tanh_f(float x){
  float t = __expf(2.0f*x); return 1.0f - 2.0f/(t+1.0f);
}
__device__ __forceinline__ float softplusf(float x){ return x>20.f ? x : log1pf(__expf(x)); }
__device__ __forceinline__ v4f mfma16(v8s a, v8s b, v4f c){
  return __builtin_amdgcn_mfma_f32_16x16x32_bf16(a,b,c,0,0,0);
}
__device__ __forceinline__ v8s fragld(const bf16* base, size_t elem_off){
  return *reinterpret_cast<const v8s*>(base + elem_off);
}
__device__ __forceinline__ v8s ldsfrag(const short* sm, int unit, int lane){
  return *reinterpret_cast<const v8s*>(sm + (unit<<9) + (lane<<3));
}
__device__ __forceinline__ v8s lds_frag8(const short* p){
  union { long long l[2]; v8s s; } r;
  r.l[0] = *(const long long*)(p);
  r.l[1] = *(const long long*)(p + 4);
  return r.s;
}
__device__ __forceinline__ short bf16bits(float v){
  bf16 h = __float2bfloat16(v); short s; __builtin_memcpy(&s,&h,2); return s;
}
// coherent (agent-scope, relaxed) 16B load as 2x qword
__device__ __forceinline__ v8s ldg_coh16(const bf16* p){
  union { unsigned long long u[2]; v8s s; } r;
  const unsigned long long* q = (const unsigned long long*)p;
  r.u[0] = __hip_atomic_load(q+0, __ATOMIC_RELAXED, __HIP_MEMORY_SCOPE_AGENT);
  r.u[1] = __hip_atomic_load(q+1, __ATOMIC_RELAXED, __HIP_MEMORY_SCOPE_AGENT);
  return r.s;
}
__device__ __forceinline__ void stg_coh_pair(bf16* base_even, int lr, float v){
  bf16 h = __float2bfloat16(v);
  unsigned vv; { unsigned short b; __builtin_memcpy(&b, &h, 2); vv = b; }
  unsigned ov = (unsigned)__shfl_xor((int)vv, 1, 64);
  if (!(lr & 1))
    __hip_atomic_store((unsigned*)base_even, vv | (ov<<16), __ATOMIC_RELAXED, __HIP_MEMORY_SCOPE_AGENT);
}
__device__ __forceinline__ float*  f32p(char* ws, size_t off){ return (float*)(ws+off); }
__device__ __forceinline__ bf16*   bfp (char* ws, size_t off){ return (bf16*)(ws+off); }
__device__ __forceinline__ bf16*   H0Bp(char* ws,int p){ return bfp (ws, p?wsoff::H0B1:wsoff::H0B0); }
__device__ __forceinline__ bf16*   H1Bp(char* ws,int p){ return bfp (ws, p?wsoff::H1B1:wsoff::H1B0); }

// ---------- dataflow flags ----------
__device__ __forceinline__ int* flagp(char* ws, int idx){
  return (int*)(ws + wsoff::BARF + (size_t)idx*64);
}
__device__ __forceinline__ void pollge(int* f, int v){
  while (__hip_atomic_load(f, __ATOMIC_RELAXED, __HIP_MEMORY_SCOPE_AGENT) < v)
    __builtin_amdgcn_s_sleep(2);
}
__device__ __forceinline__ void flagst(int* f, int v){
  __hip_atomic_store(f, v, __ATOMIC_RELAXED, __HIP_MEMORY_SCOPE_AGENT);
}

// ---------- dtype detection ----------
__global__ void k_detect(char* ws, const void* eps){
  const unsigned short* p = (const unsigned short*)eps;
  int lane = threadIdx.x;
  unsigned short u = p[2*lane];
  int e = (u>>7)&0xFF;
  bool pl = (e>=118 && e<=130);
  unsigned long long m = __ballot(pl);
  if (lane==0) *(int*)(ws+wsoff::FLAG) = (__popcll(m) >= 32) ? 1 : 0;
}

// ---------- staging ----------
__global__ void k_stage_xs(char* ws, const void* x, const void* feat){
  int isbf = *(const int*)(ws+wsoff::FLAG);
  size_t i = (size_t)blockIdx.x*blockDim.x + threadIdx.x;
  if (i >= (size_t)NT*NB*KX) return;
  int c = i % KX; size_t q = i / KX; int b = q % NB; int t = q / NB;
  float v = 0.f;
  if (c < 2)        v = ld_any(x,    ((size_t)b*NT + t)*2 + c, isbf);
  else if (c < 18)  v = ld_any(feat, ((size_t)b*192 + t)*16 + (c-2), isbf);
  ((bf16*)(ws+wsoff::XS))[i] = __float2bfloat16(v);
}
__global__ void k_stage_pad(char* ws, const void* src, size_t dstoff, int R, int SC, int DC){
  int isbf = *(const int*)(ws+wsoff::FLAG);
  size_t i = (size_t)blockIdx.x*blockDim.x + threadIdx.x;
  if (i >= (size_t)R*DC) return;
  int r = i / DC, c = i % DC;
  float v = (c < SC) ? ld_any(src, (size_t)r*SC + c, isbf) : 0.f;
  ((bf16*)(ws+dstoff))[i] = __float2bfloat16(v);
}
__global__ void k_stage_dec(char* ws, const void* src, size_t dstoff){
  int isbf = *(const int*)(ws+wsoff::FLAG);
  size_t i = (size_t)blockIdx.x*blockDim.x + threadIdx.x;
  if (i >= (size_t)432*HDP) return;
  int R = i / HDP, c = i % HDP;
  int g = R / GDP, ii = R % GDP;
  float v = (ii < HD && c < HD) ? ld_any(src, ((size_t)(g*HD+ii))*HD + c, isbf) : 0.f;
  ((bf16*)(ws+dstoff))[i] = __float2bfloat16(v);
}
struct SmallSegs { const void* src[12]; int dstoff[12]; int n[12]; };
__global__ void k_stage_small(char* ws, SmallSegs segs){
  int isbf = *(const int*)(ws+wsoff::FLAG);
  int s = blockIdx.x;
  float* dst = (float*)(ws + (size_t)segs.dstoff[s]);
  for (int i = threadIdx.x; i < segs.n[s]; i += blockDim.x)
    dst[i] = ld_any(segs.src[s], i, isbf);
}

// ================= persistent encoder: dataflow, no global barrier (unchanged R5) =====
__global__ __launch_bounds__(256,1) void k_encoder(char* ws, const int* mask){
  extern __shared__ __align__(16) char smem[];
  const int bid = blockIdx.x, tid = threadIdx.x;
  const int lane = tid & 63, w = tid >> 6, lr = lane & 15, q = lane >> 4;

  if (bid < 32){
    // ---- LAYER0 ----
    const int rb = bid >> 2, cb = bid & 3;
    short* wsm = (short*)smem;
    float* hf  = (float*)(smem + 110592);
    const short* WH = (const short*)(ws + wsoff::WHH0);
    const short* WI = (const short*)(ws + wsoff::WIH0);
    for (int idx = tid; idx < 108*512; idx += 256){
      int u = idx >> 9, le = idx & 511, ln = le >> 3, j = le & 7, lrr = ln & 15, qq = ln >> 4;
      int g = u / 36, rem = u % 36, ct = rem / 9, kb = rem % 9;
      int row = g*HE + cb*64 + ct*16 + lrr;
      wsm[idx] = (kb < 8) ? WH[(size_t)row*256 + kb*32 + qq*8 + j]
                          : WI[(size_t)row*32  + qq*8 + j];
    }
    for (int idx = tid; idx < 128*64; idx += 256) hf[idx] = 0.f;
    const float* bih = f32p(ws,wsoff::BIH0);
    const float* bhh = f32p(ws,wsoff::BHH0);
    float birv[4], bizv[4], binv[4], bhnv[4];
    #pragma unroll
    for (int ct=0;ct<4;ct++){
      int d = cb*64 + ct*16 + lr;
      birv[ct]=bih[d]+bhh[d]; bizv[ct]=bih[HE+d]+bhh[HE+d];
      binv[ct]=bih[2*HE+d];   bhnv[ct]=bhh[2*HE+d];
    }
    __syncthreads();
    const int rowloc = w*32, rowg = rb*128 + rowloc;
    float* hTf = f32p(ws, wsoff::H0F0);
    for (int t = 0; t < 128; ++t){
      if (tid < 12){
        if (tid < 4){ if (tid != cb) pollge(flagp(ws, rb*4+tid), t); }
        else pollge(flagp(ws, 32 + rb*8 + (tid-4)), t-1);
      }
      __syncthreads();
      const bf16* hbO = H0Bp(ws, t&1);
      bf16* hbN = H0Bp(ws, (t+1)&1);
      const bf16* Xs = bfp(ws,wsoff::XS) + (size_t)t*NB*KX;
      v8s hA0[8], hA1[8];
      v8s x0 = fragld(Xs, (size_t)(rowg+lr)*KX + q*8);
      v8s x1 = fragld(Xs, (size_t)(rowg+16+lr)*KX + q*8);
      #pragma unroll
      for (int kb=0;kb<8;kb++){
        hA0[kb] = ldg_coh16(hbO + (size_t)(rowg+lr)*HE + kb*32 + q*8);
        hA1[kb] = ldg_coh16(hbO + (size_t)(rowg+16+lr)*HE + kb*32 + q*8);
      }
      v4f accr[2][4], accz[2][4], acchn[2][4], accxn[2][4];
      #pragma unroll
      for (int mt=0;mt<2;mt++)
        #pragma unroll
        for (int ct=0;ct<4;ct++){
          accr[mt][ct]=(v4f){0,0,0,0}; accz[mt][ct]=(v4f){0,0,0,0};
          acchn[mt][ct]=(v4f){0,0,0,0}; accxn[mt][ct]=(v4f){0,0,0,0};
        }
      #pragma unroll
      for (int g=0;g<3;g++)
        #pragma unroll
        for (int ct=0;ct<4;ct++){
          v8s b = ldsfrag(wsm, (g*4+ct)*9 + 8, lane);
          v4f* A0 = (g==0)?&accr[0][ct]:(g==1)?&accz[0][ct]:&accxn[0][ct];
          v4f* A1 = (g==0)?&accr[1][ct]:(g==1)?&accz[1][ct]:&accxn[1][ct];
          *A0 = mfma16(x0,b,*A0); *A1 = mfma16(x1,b,*A1);
        }
      #pragma unroll
      for (int kb=0;kb<8;kb++){
        #pragma unroll
        for (int g=0;g<3;g++)
          #pragma unroll
          for (int ct=0;ct<4;ct++){
            v8s b = ldsfrag(wsm, (g*4+ct)*9 + kb, lane);
            v4f* A0 = (g==0)?&accr[0][ct]:(g==1)?&accz[0][ct]:&acchn[0][ct];
            v4f* A1 = (g==0)?&accr[1][ct]:(g==1)?&accz[1][ct]:&acchn[1][ct];
            *A0 = mfma16(hA0[kb],b,*A0); *A1 = mfma16(hA1[kb],b,*A1);
          }
      }
      int mk[2][4];
      #pragma unroll
      for (int mt=0;mt<2;mt++)
        #pragma unroll
        for (int r=0;r<4;r++)
          mk[mt][r] = mask[(size_t)(rowg + mt*16 + q*4 + r)*NT + t];
      #pragma unroll
      for (int ct=0;ct<4;ct++){
        const int d = cb*64 + ct*16 + lr;
        #pragma unroll
        for (int mt=0;mt<2;mt++)
          #pragma unroll
          for (int r=0;r<4;r++){
            const int rl = rowloc + mt*16 + q*4 + r;
            float rr = sigm(accr[mt][ct][r] + birv[ct]);
            float zz = sigm(accz[mt][ct][r] + bizv[ct]);
            float nn = tanh_f(accxn[mt][ct][r] + binv[ct] + rr*(acchn[mt][ct][r]+bhnv[ct]));
            float ho = hf[rl*64 + ct*16 + lr];
            float hv = (1.f-zz)*nn + zz*ho;
            float h2 = mk[mt][r] ? hv : ho;
            hf[rl*64 + ct*16 + lr] = h2;
            stg_coh_pair(hbN + ((size_t)(rb*128+rl)*HE + (d & ~1)), lr, h2);
            if (t == 127) hTf[(size_t)(rb*128+rl)*HE + d] = h2;
          }
      }
      __syncthreads();
      if (tid == 0) flagst(flagp(ws, bid), t+1);
    }
  } else if (bid < 96){
    // ---- LAYER1 ----
    const int id = bid - 32, rb = id >> 3, cb = id & 7;
    short* wsm = (short*)smem;
    float* hf  = (float*)(smem + 98304);
    const short* WX = (const short*)(ws + wsoff::WIH1);
    const short* WHs= (const short*)(ws + wsoff::WHH1);
    for (int idx = tid; idx < 96*512; idx += 256){
      int u = idx >> 9, le = idx & 511, ln = le >> 3, j = le & 7, lrr = ln & 15, qq = ln >> 4;
      int g = u / 32, rem = u % 32, ct = rem >> 4, kb = rem & 15;
      int row = g*HE + cb*32 + ct*16 + lrr;
      wsm[idx] = (kb < 8) ? WX [(size_t)row*256 + kb*32 + qq*8 + j]
                          : WHs[(size_t)row*256 + (kb-8)*32 + qq*8 + j];
    }
    for (int idx = tid; idx < 128*32; idx += 256) hf[idx] = 0.f;
    const float* bih = f32p(ws,wsoff::BIH1);
    const float* bhh = f32p(ws,wsoff::BHH1);
    float birv[2], bizv[2], binv[2], bhnv[2];
    #pragma unroll
    for (int ct=0;ct<2;ct++){
      int d = cb*32 + ct*16 + lr;
      birv[ct]=bih[d]+bhh[d]; bizv[ct]=bih[HE+d]+bhh[HE+d];
      binv[ct]=bih[2*HE+d];   bhnv[ct]=bhh[2*HE+d];
    }
    __syncthreads();
    const int rowloc = w*32, rowg = rb*128 + rowloc;
    float* hTf = f32p(ws, wsoff::H1F0);
    for (int s = 0; s < 128; ++s){
      if (tid < 14){
        if (tid < 4) pollge(flagp(ws, rb*4+tid), s+1);
        else if (tid < 12){ if (tid-4 != cb) pollge(flagp(ws, 32 + rb*8 + (tid-4)), s); }
        else pollge(flagp(ws, 96 + rb*2 + (tid-12)), s-1);
      }
      __syncthreads();
      const bf16* Ax = H0Bp(ws, (s+1)&1);
      const bf16* Ah = H1Bp(ws, s&1);
      bf16* hbN = H1Bp(ws, (s+1)&1);
      v8s Ax0[8], Ax1[8], Ah0[8], Ah1[8];
      #pragma unroll
      for (int kb=0;kb<8;kb++){
        Ax0[kb] = ldg_coh16(Ax + (size_t)(rowg+lr)*HE + kb*32 + q*8);
        Ax1[kb] = ldg_coh16(Ax + (size_t)(rowg+16+lr)*HE + kb*32 + q*8);
        Ah0[kb] = ldg_coh16(Ah + (size_t)(rowg+lr)*HE + kb*32 + q*8);
        Ah1[kb] = ldg_coh16(Ah + (size_t)(rowg+16+lr)*HE + kb*32 + q*8);
      }
      v4f accr[2][2], accz[2][2], accxn[2][2], acchn[2][2];
      #pragma unroll
      for (int mt=0;mt<2;mt++)
        #pragma unroll
        for (int ct=0;ct<2;ct++){
          accr[mt][ct]=(v4f){0,0,0,0}; accz[mt][ct]=(v4f){0,0,0,0};
          accxn[mt][ct]=(v4f){0,0,0,0}; acchn[mt][ct]=(v4f){0,0,0,0};
        }
      #pragma unroll
      for (int kb=0;kb<8;kb++){
        #pragma unroll
        for (int g=0;g<3;g++)
          #pragma unroll
          for (int ct=0;ct<2;ct++){
            v8s bx = ldsfrag(wsm, (g*2+ct)*16 + kb, lane);
            v8s bh = ldsfrag(wsm, (g*2+ct)*16 + 8 + kb, lane);
            v4f* X0 = (g==0)?&accr[0][ct]:(g==1)?&accz[0][ct]:&accxn[0][ct];
            v4f* X1 = (g==0)?&accr[1][ct]:(g==1)?&accz[1][ct]:&accxn[1][ct];
            v4f* H0v= (g==0)?&accr[0][ct]:(g==1)?&accz[0][ct]:&acchn[0][ct];
            v4f* H1v= (g==0)?&accr[1][ct]:(g==1)?&accz[1][ct]:&acchn[1][ct];
            *X0 = mfma16(Ax0[kb],bx,*X0); *X1 = mfma16(Ax1[kb],bx,*X1);
            *H0v= mfma16(Ah0[kb],bh,*H0v); *H1v= mfma16(Ah1[kb],bh,*H1v);
          }
      }
      int mk[2][4];
      #pragma unroll
      for (int mt=0;mt<2;mt++)
        #pragma unroll
        for (int r=0;r<4;r++)
          mk[mt][r] = mask[(size_t)(rowg + mt*16 + q*4 + r)*NT + s];
      #pragma unroll
      for (int ct=0;ct<2;ct++){
        const int d = cb*32 + ct*16 + lr;
        #pragma unroll
        for (int mt=0;mt<2;mt++)
          #pragma unroll
          for (int r=0;r<4;r++){
            const int rl = rowloc + mt*16 + q*4 + r;
            float rr = sigm(accr[mt][ct][r] + birv[ct]);
            float zz = sigm(accz[mt][ct][r] + bizv[ct]);
            float nn = tanh_f(accxn[mt][ct][r] + binv[ct] + rr*(acchn[mt][ct][r]+bhnv[ct]));
            float ho = hf[rl*32 + ct*16 + lr];
            float hv = (1.f-zz)*nn + zz*ho;
            float h2 = mk[mt][r] ? hv : ho;
            hf[rl*32 + ct*16 + lr] = h2;
            stg_coh_pair(hbN + ((size_t)(rb*128+rl)*HE + (d & ~1)), lr, h2);
            if (s == 127) hTf[(size_t)(rb*128+rl)*HE + d] = h2;
          }
      }
      __syncthreads();
      if (tid == 0) flagst(flagp(ws, bid), s+1);
    }
  } else {
    // ---- MLP ----
    const int mb = bid - 96, rb = mb >> 1;
    short* wsm = (short*)smem;
    const short* W1s = (const short*)(ws + wsoff::W1B);
    for (int idx = tid; idx < 16*512; idx += 256){
      int u = idx >> 9, le = idx & 511, ln = le >> 3, j = le & 7, lrr = ln & 15, qq = ln >> 4;
      int c = u >> 2, kb = u & 3;
      wsm[idx] = W1s[(size_t)(c*16 + lrr)*NH + kb*32 + qq*8 + j];
    }
    float b1v[4], w20[4], w21[4];
    const float* B1 = f32p(ws,wsoff::B1F);
    const float* W2 = f32p(ws,wsoff::W2F);
    const float* B2 = f32p(ws,wsoff::B2F);
    #pragma unroll
    for (int c=0;c<4;c++){ int col=c*16+lr; b1v[c]=B1[col]; w20[c]=W2[col]; w21[c]=W2[64+col]; }
    const float b20 = B2[0], b21 = B2[1];
    __syncthreads();
    const int rowbase = mb*64 + w*16, rowA = rowbase + lr;
    for (int s = 0; s < 128; ++s){
      if (tid < 8) pollge(flagp(ws, 32 + rb*8 + tid), s+1);
      __syncthreads();
      const bf16* A = H1Bp(ws, (s+1)&1);
      const bool valid = mask[(size_t)rowA*NT + s] != 0;
      v8s af[4];
      #pragma unroll
      for (int kb=0;kb<4;kb++)
        af[kb] = valid ? ldg_coh16(A + (size_t)rowA*HE + kb*32 + q*8) : (v8s){0,0,0,0,0,0,0,0};
      v4f acc[4];
      #pragma unroll
      for (int c=0;c<4;c++) acc[c]=(v4f){0,0,0,0};
      #pragma unroll
      for (int kb=0;kb<4;kb++)
        #pragma unroll
        for (int c=0;c<4;c++)
          acc[c] = mfma16(af[kb], ldsfrag(wsm, c*4 + kb, lane), acc[c]);
      float* outp = f32p(ws,wsoff::ENCP) + (size_t)s*NB*2;
      #pragma unroll
      for (int r=0;r<4;r++){
        float p0 = 0.f, p1 = 0.f;
        #pragma unroll
        for (int c=0;c<4;c++){
          float hv = acc[c][r] + b1v[c]; hv = hv>0.f ? hv : 0.f;
          p0 += hv*w20[c]; p1 += hv*w21[c];
        }
        #pragma unroll
        for (int m=1;m<16;m<<=1){ p0 += __shfl_xor(p0,m,64); p1 += __shfl_xor(p1,m,64); }
        if (lr == 0){
          const int grow = rowbase + q*4 + r;
          outp[(size_t)grow*2]   = softplusf(p0+b20);
          outp[(size_t)grow*2+1] = softplusf(p1+b21);
        }
      }
      __syncthreads();
      if (tid == 0) flagst(flagp(ws, bid), s+1);
    }
  }
}

// ================= decoder: 9 waves, uniform tile ownership, RF+LDS weight residency ====
// 256 blocks x 576 thr, 32 rows/block. wave w in [0,9): owns cc=w (cols w*16..w*16+15).
// RF: W0[cc=w], WX1[cc=w] fragments (120 VGPR). LDS: WH1 all 9 tiles + bf16 state.
// waves 5,6: MLP halves in RF.
__global__ __launch_bounds__(576,1) void k_decoder(char* ws, const void* eps, const void* feat, void* out){
  extern __shared__ __align__(16) char dsm[];
  short* s_h0b = (short*)dsm;                       // [32][HDS]
  short* s_h1b = s_h0b + 32*HDS;                    // +10496B each
  float* s_inp = (float*)(dsm + 20992);             // [64]
  float* s_red = s_inp + 64;                        // [128]
  short* s_wh  = (short*)(dsm + 21760);             // WH1: unit = (g*9+cc)*5+kb, 135 units

  const int isbf = *(const int*)(ws+wsoff::FLAG);
  const int tid = threadIdx.x;
  const int lane = tid & 63, w = tid >> 6, lr = lane & 15, q = lane >> 4;
  const int rowbase = blockIdx.x*32;
  constexpr size_t N0v = (size_t)NS*NB*127*2;

  const bf16* W0g  = bfp(ws,wsoff::WDHH0);
  const bf16* WX1g = bfp(ws,wsoff::WDIH1);

  for (int i = tid; i < 2*32*HDS; i += 576) s_h0b[i] = 0;
  {
    const short* src = (const short*)(ws + wsoff::WDHH1);
    for (int idx = tid; idx < 135*512; idx += 576){
      int u = idx >> 9, le = idx & 511, ln = le >> 3, e = le & 7, lrr = ln & 15, qq = ln >> 4;
      int kb = u % 5, t2 = u / 5, cc = t2 % 9, g = t2 / 9;
      s_wh[idx] = src[(size_t)(g*GDP + cc*16 + lrr)*HDP + kb*32 + qq*8 + e];
    }
  }
  if (tid < 64){
    int r0 = tid >> 1, c = tid & 1;
    int b = (rowbase + r0) & 1023;
    float v = f32p(ws,wsoff::ENCP)[((size_t)127*NB + b)*2 + c];
    s_inp[tid] = v;
    st_out(out, N0v + ((size_t)(rowbase+r0)*64)*2 + c, v, isbf);
  }
  __syncthreads();

  // epilogue scalar tables in registers; d = w*16+lr (clamped for OOB lanes of wave 8)
  const int d = w*16 + lr;
  const bool dval = (d < HD);
  float e0a[10], e1a[4];
  {
    const float* wih = f32p(ws,wsoff::WDIH0F);
    const float* bi0 = f32p(ws,wsoff::BDIH0); const float* bh0 = f32p(ws,wsoff::BDHH0);
    const float* bi1 = f32p(ws,wsoff::BDIH1); const float* bh1 = f32p(ws,wsoff::BDHH1);
    int dd = dval ? d : (HD-1);
    e0a[0]=wih[(0*HD+dd)*2]; e0a[1]=wih[(0*HD+dd)*2+1];
    e0a[2]=wih[(1*HD+dd)*2]; e0a[3]=wih[(1*HD+dd)*2+1];
    e0a[4]=wih[(2*HD+dd)*2]; e0a[5]=wih[(2*HD+dd)*2+1];
    e0a[6]=bi0[dd]+bh0[dd]; e0a[7]=bi0[HD+dd]+bh0[HD+dd]; e0a[8]=bi0[2*HD+dd]; e0a[9]=bh0[2*HD+dd];
    e1a[0]=bi1[dd]+bh1[dd]; e1a[1]=bi1[HD+dd]+bh1[HD+dd]; e1a[2]=bi1[2*HD+dd]; e1a[3]=bh1[2*HD+dd];
  }

  // fp32 master state
  float h0a[2][4], h1a[2][4];
  {
    const float* h0T = f32p(ws,wsoff::H0F0);
    const float* h1T = f32p(ws,wsoff::H1F0);
    #pragma unroll
    for (int m=0;m<2;m++)
      #pragma unroll
      for (int r=0;r<4;r++){
        int row = m*16 + q*4 + r, grow = rowbase + row;
        int s = grow >> 10, b = grow & 1023;
        float v0=0.f, v1=0.f;
        if (d < NH){
          float e0 = ld_any(eps, ((size_t)(s*2+0)*NB + b)*NH + d, isbf);
          float e1 = ld_any(eps, ((size_t)(s*2+1)*NB + b)*NH + d, isbf);
          v0 = e0*__expf(0.5f*h0T[(size_t)b*HE + NH + d]) + h0T[(size_t)b*HE + d];
          v1 = e1*__expf(0.5f*h1T[(size_t)b*HE + NH + d]) + h1T[(size_t)b*HE + d];
        } else if (d < HD){
          float fc = ld_any(feat, (size_t)b*3072 + 2048 + (d-NH), isbf);
          v0 = fc; v1 = fc;
        }
        h0a[m][r] = v0; h1a[m][r] = v1;
        if (dval){
          s_h0b[row*HDS + d] = bf16bits(v0);
          s_h1b[row*HDS + d] = bf16bits(v1);
        }
      }
  }

  // RF-resident weights: tile cc=w of W0 and WX1 (zero-padded rows for w=8)
  v8s w0f[3][5], wxf[3][5];
  #pragma unroll
  for (int g=0;g<3;g++)
    #pragma unroll
    for (int kb=0;kb<5;kb++){
      size_t off = (size_t)(g*GDP + w*16 + lr)*HDP + kb*32 + q*8;
      w0f[g][kb] = fragld(W0g, off);
      wxf[g][kb] = fragld(WX1g, off);
    }
  v8s w1f[2][4]; float b1v[2], w20v[2], w21v[2];
  if (w == 5 || w == 6){
    const int tb = (w-5)*2;
    const bf16* W1g = bfp(ws,wsoff::W1B);
    #pragma unroll
    for (int ct=0;ct<2;ct++){
      #pragma unroll
      for (int kb=0;kb<4;kb++)
        w1f[ct][kb] = fragld(W1g, (size_t)((tb+ct)*16+lr)*NH + kb*32 + q*8);
      b1v[ct]  = f32p(ws,wsoff::B1F)[(tb+ct)*16+lr];
      w20v[ct] = f32p(ws,wsoff::W2F)[(tb+ct)*16+lr];
      w21v[ct] = f32p(ws,wsoff::W2F)[64+(tb+ct)*16+lr];
    }
  }
  const float b20 = f32p(ws,wsoff::B2F)[0], b21 = f32p(ws,wsoff::B2F)[1];
  __syncthreads();

  for (int k = 0; k < 63; ++k){
    // ---- P1 matmul (d0): reads s_h0b(old) ----
    v4f p1[3][2];
    #pragma unroll
    for (int g=0;g<3;g++){ p1[g][0]=(v4f){0,0,0,0}; p1[g][1]=(v4f){0,0,0,0}; }
    #pragma unroll
    for (int m=0;m<2;m++)
      #pragma unroll
      for (int kb=0;kb<5;kb++){
        v8s A = lds_frag8(s_h0b + (m*16+lr)*HDS + kb*32 + q*8);
        #pragma unroll
        for (int g=0;g<3;g++) p1[g][m] = mfma16(A, w0f[g][kb], p1[g][m]);
      }
    __syncthreads();
    // ---- P1 epilogue: writes s_h0b(new) ----
    #pragma unroll
    for (int m=0;m<2;m++)
      #pragma unroll
      for (int r=0;r<4;r++){
        int row = m*16 + q*4 + r;
        float i0 = s_inp[row*2], i1 = s_inp[row*2+1];
        float rr = sigm(i0*e0a[0]+i1*e0a[1] + p1[0][m][r] + e0a[6]);
        float zz = sigm(i0*e0a[2]+i1*e0a[3] + p1[1][m][r] + e0a[7]);
        float nn = tanh_f(i0*e0a[4]+i1*e0a[5] + e0a[8] + rr*(p1[2][m][r] + e0a[9]));
        float h = (1.f-zz)*nn + zz*h0a[m][r];
        h0a[m][r] = h;
        if (dval) s_h0b[row*HDS + d] = bf16bits(h);
      }
    __syncthreads();
    // ---- P2 matmul (d1): reads s_h0b(new) + s_h1b(old) ----
    v4f p2[4][2];
    #pragma unroll
    for (int g=0;g<4;g++){ p2[g][0]=(v4f){0,0,0,0}; p2[g][1]=(v4f){0,0,0,0}; }
    #pragma unroll
    for (int m=0;m<2;m++)
      #pragma unroll
      for (int kb=0;kb<5;kb++){
        v8s ax = lds_frag8(s_h0b + (m*16+lr)*HDS + kb*32 + q*8);
        v8s ah = lds_frag8(s_h1b + (m*16+lr)*HDS + kb*32 + q*8);
        #pragma unroll
        for (int g=0;g<3;g++){
          int aix = (g==2) ? 2 : g, aih = (g==2) ? 3 : g;
          p2[aix][m] = mfma16(ax, wxf[g][kb], p2[aix][m]);
          p2[aih][m] = mfma16(ah, ldsfrag(s_wh, (g*9+w)*5 + kb, lane), p2[aih][m]);
        }
      }
    __syncthreads();
    // ---- P2 epilogue: writes s_h1b(new) ----
    #pragma unroll
    for (int m=0;m<2;m++)
      #pragma unroll
      for (int r=0;r<4;r++){
        int row = m*16 + q*4 + r;
        float rr = sigm(p2[0][m][r] + e1a[0]);
        float zz = sigm(p2[1][m][r] + e1a[1]);
        float nn = tanh_f(p2[2][m][r] + e1a[2] + rr*(p2[3][m][r] + e1a[3]));
        float h = (1.f-zz)*nn + zz*h1a[m][r];
        h1a[m][r] = h;
        if (dval) s_h1b[row*HDS + d] = bf16bits(h);
      }
    __syncthreads();
    // ---- P3: MLP halves on waves 5,6 ----
    if (w == 5 || w == 6){
      v4f a3[2][2];
      #pragma unroll
      for (int ct=0;ct<2;ct++){ a3[ct][0]=(v4f){0,0,0,0}; a3[ct][1]=(v4f){0,0,0,0}; }
      #pragma unroll
      for (int m=0;m<2;m++)
        #pragma unroll
        for (int kb=0;kb<4;kb++){
          v8s A = lds_frag8(s_h1b + (m*16+lr)*HDS + kb*32 + q*8);
          #pragma unroll
          for (int ct=0;ct<2;ct++) a3[ct][m] = mfma16(A, w1f[ct][kb], a3[ct][m]);
        }
      #pragma unroll
      for (int m=0;m<2;m++)
        #pragma unroll
        for (int r=0;r<4;r++){
          float p0 = 0.f, p1v = 0.f;
          #pragma unroll
          for (int ct=0;ct<2;ct++){
            float hv = a3[ct][m][r] + b1v[ct]; hv = hv > 0.f ? hv : 0.f;
            p0 += hv*w20v[ct]; p1v += hv*w21v[ct];
          }
          #pragma unroll
          for (int mm=1;mm<16;mm<<=1){ p0 += __shfl_xor(p0,mm,64); p1v += __shfl_xor(p1v,mm,64); }
          if (lr == 0){
            int row = m*16 + q*4 + r;
            s_red[(w-5)*64 + row*2]   = p0;
            s_red[(w-5)*64 + row*2+1] = p1v;
          }
        }
    }
    __syncthreads();
    // ---- P4: combine + softplus + feedback + out ----
    if (tid < 64){
      int row = tid >> 1, c = tid & 1;
      float p = s_red[row*2 + c] + s_red[64 + row*2 + c];
      float v = softplusf(p + (c ? b21 : b20));
      s_inp[tid] = v;
      st_out(out, N0v + ((size_t)(rowbase+row)*64 + (k+1))*2 + c, v, isbf);
    }
    __syncthreads();
  }
}

// ---------- encoder-part output assembly ----------
__global__ void k_assemble_enc(char* ws, void* out){
  int isbf = *(const int*)(ws+wsoff::FLAG);
  const float* encp = f32p(ws,wsoff::ENCP);
  constexpr size_t N0v = (size_t)NS*NB*127*2;
  for (size_t i = (size_t)blockIdx.x*blockDim.x + threadIdx.x; i < N0v;
       i += (size_t)gridDim.x*blockDim.x){
    int c = (int)(i & 1); size_t qq = i >> 1;
    int tt = (int)(qq % 127); size_t q2 = qq / 127; int b = (int)(q2 & 1023);
    st_out(out, i, encp[((size_t)tt*NB + b)*2 + c], isbf);
  }
}

extern "C" void kernel_launch(void* const* d_in, const int* in_sizes, int n_in,
                              void* d_out, int out_size, void* d_ws, size_t ws_size,
                              hipStream_t stream) {
  char* ws = (char*)d_ws;
  const int* mask = (const int*)d_in[2];
  auto gb = [](size_t n){ return dim3((unsigned)((n + 255)/256)); };

  hipMemsetAsync(ws+wsoff::BARF, 0, 112*64, stream);
  hipMemsetAsync(ws+wsoff::H0B0, 0, (size_t)NB*HE*2, stream);
  hipMemsetAsync(ws+wsoff::H1B0, 0, (size_t)NB*HE*2, stream);

  k_detect<<<1,64,0,stream>>>(ws, d_in[3]);

  k_stage_xs <<<gb((size_t)NT*NB*KX),256,0,stream>>>(ws, d_in[0], d_in[1]);
  k_stage_pad<<<gb(768*32) ,256,0,stream>>>(ws, d_in[7],  wsoff::WIH0, 768, 18, 32);
  k_stage_pad<<<gb(768*256),256,0,stream>>>(ws, d_in[8],  wsoff::WHH0, 768, 256, 256);
  k_stage_pad<<<gb(768*256),256,0,stream>>>(ws, d_in[11], wsoff::WIH1, 768, 256, 256);
  k_stage_pad<<<gb(768*256),256,0,stream>>>(ws, d_in[12], wsoff::WHH1, 768, 256, 256);
  k_stage_pad<<<gb(64*128) ,256,0,stream>>>(ws, d_in[23], wsoff::W1B,  64, 128, 128);
  k_stage_dec<<<gb(432*HDP),256,0,stream>>>(ws, d_in[16], wsoff::WDHH0);
  k_stage_dec<<<gb(432*HDP),256,0,stream>>>(ws, d_in[19], wsoff::WDIH1);
  k_stage_dec<<<gb(432*HDP),256,0,stream>>>(ws, d_in[20], wsoff::WDHH1);

  SmallSegs ss;
  const void* srcs[12] = {d_in[9],d_in[10],d_in[13],d_in[14],d_in[15],
                          d_in[17],d_in[18],d_in[21],d_in[22],
                          d_in[24],d_in[25],d_in[26]};
  const size_t offs[12] = {wsoff::BIH0,wsoff::BHH0,wsoff::BIH1,wsoff::BHH1,wsoff::WDIH0F,
                           wsoff::BDIH0,wsoff::BDHH0,wsoff::BDIH1,wsoff::BDHH1,
                           wsoff::B1F,wsoff::W2F,wsoff::B2F};
  const int ns[12] = {768,768,768,768,792,396,396,396,396,64,128,2};
  for (int i=0;i<12;i++){ ss.src[i]=srcs[i]; ss.dstoff[i]=(int)offs[i]; ss.n[i]=ns[i]; }
  k_stage_small<<<12,256,0,stream>>>(ws, ss);

  hipFuncSetAttribute(reinterpret_cast<const void*>(k_encoder),
                      hipFuncAttributeMaxDynamicSharedMemorySize, 143360);
  // decoder LDS: state 20992 + inp 256 + red 512 + wh 138240 = 160000
  hipFuncSetAttribute(reinterpret_cast<const void*>(k_decoder),
                      hipFuncAttributeMaxDynamicSharedMemorySize, 160000);

  // persistent encoder: 112 blocks, all co-resident (1 block/CU by LDS)
  k_encoder<<<EBLOCKS,256,143360,stream>>>(ws, mask);

  // decoder: 9-wave blocks, uniform tile ownership, weights resident RF+LDS
  k_decoder<<<256,576,160000,stream>>>(ws, d_in[3], d_in[1], d_out);

  k_assemble_enc<<<2048,256,0,stream>>>(ws, d_out);
}

// Round 7
// 3187.598 us; speedup vs baseline: 2.3595x; 1.2323x over previous
//
#include <hip/hip_runtime.h>
#include <hip/hip_bf16.h>
#include <math.h>

typedef __hip_bfloat16 bf16;
typedef short v8s __attribute__((ext_vector_type(8)));
typedef float v4f __attribute__((ext_vector_type(4)));

#define NB   1024
#define NT   128
#define NH   128
#define HE   256
#define HD   132
#define HDP  160
#define HDS  164
#define GDP  144
#define NS   8
#define SB   8192
#define KX   32
#define EBLOCKS 112
#define HBUFSZ ((size_t)NB*HE*2)

namespace wsoff {
constexpr size_t al(size_t x){ return (x + 255) & ~size_t(255); }
constexpr size_t FLAG  = 0;
constexpr size_t CNT   = 256;                  // 24 counters x 64B
constexpr size_t XS    = al(CNT + 24*64);
constexpr size_t MASKT = al(XS    + (size_t)NT*NB*KX*2);   // int32 [NT][NB]
constexpr size_t WIH0  = al(MASKT + (size_t)NT*NB*4);
constexpr size_t WHH0  = al(WIH0  + 768*32*2);
constexpr size_t WIH1  = al(WHH0  + 768*256*2);
constexpr size_t WHH1  = al(WIH1  + 768*256*2);
constexpr size_t BIH0  = al(WHH1  + 768*256*2);
constexpr size_t BHH0  = al(BIH0  + 768*4);
constexpr size_t BIH1  = al(BHH0  + 768*4);
constexpr size_t BHH1  = al(BIH1  + 768*4);
constexpr size_t WDHH0 = al(BHH1  + 768*4);
constexpr size_t WDIH1 = al(WDHH0 + 432*HDP*2);
constexpr size_t WDHH1 = al(WDIH1 + 432*HDP*2);
constexpr size_t WDIH0F= al(WDHH1 + 432*HDP*2);
constexpr size_t BDIH0 = al(WDIH0F+ 792*4);
constexpr size_t BDHH0 = al(BDIH0 + 396*4);
constexpr size_t BDIH1 = al(BDHH0 + 396*4);
constexpr size_t BDHH1 = al(BDIH1 + 396*4);
constexpr size_t W1B   = al(BDHH1 + 396*4);
constexpr size_t B1F   = al(W1B   + 64*128*2);
constexpr size_t W2F   = al(B1F   + 64*4);
constexpr size_t B2F   = al(W2F   + 128*4);
constexpr size_t H0F0  = al(B2F   + 2*4);
constexpr size_t H1F0  = al(H0F0  + (size_t)NB*HE*4);
constexpr size_t H0B   = al(H1F0  + (size_t)NB*HE*4);   // 4 buffers x 512KB
constexpr size_t H1B   = al(H0B   + 4*HBUFSZ);
constexpr size_t ENCP  = al(H1B   + 4*HBUFSZ);
}

// ---------- helpers ----------
__device__ __forceinline__ float ld_any(const void* p, size_t i, int isbf){
  return isbf ? __bfloat162float(((const bf16*)p)[i]) : ((const float*)p)[i];
}
__device__ __forceinline__ void st_out(void* out, size_t i, float v, int isbf){
  if (isbf) ((bf16*)out)[i] = __float2bfloat16(v); else ((float*)out)[i] = v;
}
__device__ __forceinline__ float sigm(float x){ return 1.0f/(1.0f + __expf(-x)); }
__device__ __forceinline__ float tanh_f(float x){
  float t = __expf(2.0f*x); return 1.0f - 2.0f/(t+1.0f);
}
__device__ __forceinline__ float softplusf(float x){ return x>20.f ? x : log1pf(__expf(x)); }
__device__ __forceinline__ v4f mfma16(v8s a, v8s b, v4f c){
  return __builtin_amdgcn_mfma_f32_16x16x32_bf16(a,b,c,0,0,0);
}
__device__ __forceinline__ v8s fragld(const bf16* base, size_t elem_off){
  return *reinterpret_cast<const v8s*>(base + elem_off);
}
__device__ __forceinline__ v8s ldsfrag(const short* sm, int unit, int lane){
  return *reinterpret_cast<const v8s*>(sm + (unit<<9) + (lane<<3));
}
__device__ __forceinline__ v8s lds_frag8(const short* p){
  union { long long l[2]; v8s s; } r;
  r.l[0] = *(const long long*)(p);
  r.l[1] = *(const long long*)(p + 4);
  return r.s;
}
__device__ __forceinline__ short bf16bits(float v){
  bf16 h = __float2bfloat16(v); short s; __builtin_memcpy(&s,&h,2); return s;
}
__device__ __forceinline__ float uasf(unsigned u){ float f; __builtin_memcpy(&f,&u,4); return f; }
__device__ __forceinline__ v8s ldg_coh16(const bf16* p){
  union { unsigned long long u[2]; v8s s; } r;
  const unsigned long long* q = (const unsigned long long*)p;
  r.u[0] = __hip_atomic_load(q+0, __ATOMIC_RELAXED, __HIP_MEMORY_SCOPE_AGENT);
  r.u[1] = __hip_atomic_load(q+1, __ATOMIC_RELAXED, __HIP_MEMORY_SCOPE_AGENT);
  return r.s;
}
__device__ __forceinline__ void stg_coh_pair(bf16* base_even, int lr, float v){
  bf16 h = __float2bfloat16(v);
  unsigned vv; { unsigned short b; __builtin_memcpy(&b, &h, 2); vv = b; }
  unsigned ov = (unsigned)__shfl_xor((int)vv, 1, 64);
  if (!(lr & 1))
    __hip_atomic_store((unsigned*)base_even, vv | (ov<<16), __ATOMIC_RELAXED, __HIP_MEMORY_SCOPE_AGENT);
}
__device__ __forceinline__ float*  f32p(char* ws, size_t off){ return (float*)(ws+off); }
__device__ __forceinline__ bf16*   bfp (char* ws, size_t off){ return (bf16*)(ws+off); }
__device__ __forceinline__ bf16*   H0Bb(char* ws,int j){ return bfp(ws, wsoff::H0B + (size_t)j*HBUFSZ); }
__device__ __forceinline__ bf16*   H1Bb(char* ws,int j){ return bfp(ws, wsoff::H1B + (size_t)j*HBUFSZ); }

// ---------- counters ----------
__device__ __forceinline__ int* cntp(char* ws, int idx){
  return (int*)(ws + wsoff::CNT + (size_t)idx*64);
}
__device__ __forceinline__ void pollge(int* f, int v){
  while (__hip_atomic_load(f, __ATOMIC_RELAXED, __HIP_MEMORY_SCOPE_AGENT) < v)
    __builtin_amdgcn_s_sleep(1);
}
__device__ __forceinline__ void cntbump(int* f){
  __hip_atomic_fetch_add(f, 1, __ATOMIC_RELAXED, __HIP_MEMORY_SCOPE_AGENT);
}

// ---------- dtype detection ----------
__global__ void k_detect(char* ws, const void* eps){
  const unsigned short* p = (const unsigned short*)eps;
  int lane = threadIdx.x;
  unsigned short u = p[2*lane];
  int e = (u>>7)&0xFF;
  bool pl = (e>=118 && e<=130);
  unsigned long long m = __ballot(pl);
  if (lane==0) *(int*)(ws+wsoff::FLAG) = (__popcll(m) >= 32) ? 1 : 0;
}

// ---------- staging ----------
__global__ void k_stage_xs(char* ws, const void* x, const void* feat){
  int isbf = *(const int*)(ws+wsoff::FLAG);
  size_t i = (size_t)blockIdx.x*blockDim.x + threadIdx.x;
  if (i >= (size_t)NT*NB*KX) return;
  int c = i % KX; size_t q = i / KX; int b = q % NB; int t = q / NB;
  float v = 0.f;
  if (c < 2)        v = ld_any(x,    ((size_t)b*NT + t)*2 + c, isbf);
  else if (c < 18)  v = ld_any(feat, ((size_t)b*192 + t)*16 + (c-2), isbf);
  ((bf16*)(ws+wsoff::XS))[i] = __float2bfloat16(v);
}
__global__ void k_stage_maskT(char* ws, const int* mask){
  size_t i = (size_t)blockIdx.x*blockDim.x + threadIdx.x;
  if (i >= (size_t)NT*NB) return;
  int b = i % NB, t = i / NB;
  ((int*)(ws+wsoff::MASKT))[i] = mask[(size_t)b*NT + t];
}
__global__ void k_stage_pad(char* ws, const void* src, size_t dstoff, int R, int SC, int DC){
  int isbf = *(const int*)(ws+wsoff::FLAG);
  size_t i = (size_t)blockIdx.x*blockDim.x + threadIdx.x;
  if (i >= (size_t)R*DC) return;
  int r = i / DC, c = i % DC;
  float v = (c < SC) ? ld_any(src, (size_t)r*SC + c, isbf) : 0.f;
  ((bf16*)(ws+dstoff))[i] = __float2bfloat16(v);
}
__global__ void k_stage_dec(char* ws, const void* src, size_t dstoff){
  int isbf = *(const int*)(ws+wsoff::FLAG);
  size_t i = (size_t)blockIdx.x*blockDim.x + threadIdx.x;
  if (i >= (size_t)432*HDP) return;
  int R = i / HDP, c = i % HDP;
  int g = R / GDP, ii = R % GDP;
  float v = (ii < HD && c < HD) ? ld_any(src, ((size_t)(g*HD+ii))*HD + c, isbf) : 0.f;
  ((bf16*)(ws+dstoff))[i] = __float2bfloat16(v);
}
struct SmallSegs { const void* src[12]; int dstoff[12]; int n[12]; };
__global__ void k_stage_small(char* ws, SmallSegs segs){
  int isbf = *(const int*)(ws+wsoff::FLAG);
  int s = blockIdx.x;
  float* dst = (float*)(ws + (size_t)segs.dstoff[s]);
  for (int i = threadIdx.x; i < segs.n[s]; i += blockDim.x)
    dst[i] = ld_any(segs.src[s], i, isbf);
}

// ================= persistent encoder: counter dataflow, 4-deep buffers =================
// counters: cntL0[rb]=idx rb, cntL1[rb]=8+rb, cntM[rb]=16+rb
__global__ __launch_bounds__(256,1) void k_encoder(char* ws){
  extern __shared__ __align__(16) char smem[];
  const int bid = blockIdx.x, tid = threadIdx.x;
  const int lane = tid & 63, w = tid >> 6, lr = lane & 15, q = lane >> 4;
  const int* maskT = (const int*)(ws + wsoff::MASKT);

  if (bid < 32){
    // ---- LAYER0 ----
    const int rb = bid >> 2, cb = bid & 3;
    int* cL0 = cntp(ws, rb);
    int* cL1 = cntp(ws, 8+rb);
    short* wsm = (short*)smem;
    float* hf  = (float*)(smem + 110592);
    const short* WH = (const short*)(ws + wsoff::WHH0);
    const short* WI = (const short*)(ws + wsoff::WIH0);
    for (int idx = tid; idx < 108*512; idx += 256){
      int u = idx >> 9, le = idx & 511, ln = le >> 3, j = le & 7, lrr = ln & 15, qq = ln >> 4;
      int g = u / 36, rem = u % 36, ct = rem / 9, kb = rem % 9;
      int row = g*HE + cb*64 + ct*16 + lrr;
      wsm[idx] = (kb < 8) ? WH[(size_t)row*256 + kb*32 + qq*8 + j]
                          : WI[(size_t)row*32  + qq*8 + j];
    }
    for (int idx = tid; idx < 128*64; idx += 256) hf[idx] = 0.f;
    const float* bih = f32p(ws,wsoff::BIH0);
    const float* bhh = f32p(ws,wsoff::BHH0);
    float birv[4], bizv[4], binv[4], bhnv[4];
    #pragma unroll
    for (int ct=0;ct<4;ct++){
      int d = cb*64 + ct*16 + lr;
      birv[ct]=bih[d]+bhh[d]; bizv[ct]=bih[HE+d]+bhh[HE+d];
      binv[ct]=bih[2*HE+d];   bhnv[ct]=bhh[2*HE+d];
    }
    __syncthreads();
    const int rowloc = w*32, rowg = rb*128 + rowloc;
    float* hTf = f32p(ws, wsoff::H0F0);
    for (int t = 0; t < 128; ++t){
      if (tid == 0){
        pollge(cL0, 4*t);
        if (t >= 4) pollge(cL1, 8*(t-3));
      }
      __syncthreads();
      const bf16* hbO = H0Bb(ws, (t+3)&3);
      bf16* hbN = H0Bb(ws, t&3);
      const bf16* Xs = bfp(ws,wsoff::XS) + (size_t)t*NB*KX;
      v8s hA0[8], hA1[8];
      v8s x0 = fragld(Xs, (size_t)(rowg+lr)*KX + q*8);
      v8s x1 = fragld(Xs, (size_t)(rowg+16+lr)*KX + q*8);
      #pragma unroll
      for (int kb=0;kb<8;kb++){
        hA0[kb] = ldg_coh16(hbO + (size_t)(rowg+lr)*HE + kb*32 + q*8);
        hA1[kb] = ldg_coh16(hbO + (size_t)(rowg+16+lr)*HE + kb*32 + q*8);
      }
      v4f accr[2][4], accz[2][4], acchn[2][4], accxn[2][4];
      #pragma unroll
      for (int mt=0;mt<2;mt++)
        #pragma unroll
        for (int ct=0;ct<4;ct++){
          accr[mt][ct]=(v4f){0,0,0,0}; accz[mt][ct]=(v4f){0,0,0,0};
          acchn[mt][ct]=(v4f){0,0,0,0}; accxn[mt][ct]=(v4f){0,0,0,0};
        }
      #pragma unroll
      for (int g=0;g<3;g++)
        #pragma unroll
        for (int ct=0;ct<4;ct++){
          v8s b = ldsfrag(wsm, (g*4+ct)*9 + 8, lane);
          v4f* A0 = (g==0)?&accr[0][ct]:(g==1)?&accz[0][ct]:&accxn[0][ct];
          v4f* A1 = (g==0)?&accr[1][ct]:(g==1)?&accz[1][ct]:&accxn[1][ct];
          *A0 = mfma16(x0,b,*A0); *A1 = mfma16(x1,b,*A1);
        }
      #pragma unroll
      for (int kb=0;kb<8;kb++){
        #pragma unroll
        for (int g=0;g<3;g++)
          #pragma unroll
          for (int ct=0;ct<4;ct++){
            v8s b = ldsfrag(wsm, (g*4+ct)*9 + kb, lane);
            v4f* A0 = (g==0)?&accr[0][ct]:(g==1)?&accz[0][ct]:&acchn[0][ct];
            v4f* A1 = (g==0)?&accr[1][ct]:(g==1)?&accz[1][ct]:&acchn[1][ct];
            *A0 = mfma16(hA0[kb],b,*A0); *A1 = mfma16(hA1[kb],b,*A1);
          }
      }
      int mk[2][4];
      #pragma unroll
      for (int mt=0;mt<2;mt++)
        #pragma unroll
        for (int r=0;r<4;r++)
          mk[mt][r] = maskT[(size_t)t*NB + rowg + mt*16 + q*4 + r];
      #pragma unroll
      for (int ct=0;ct<4;ct++){
        const int d = cb*64 + ct*16 + lr;
        #pragma unroll
        for (int mt=0;mt<2;mt++)
          #pragma unroll
          for (int r=0;r<4;r++){
            const int rl = rowloc + mt*16 + q*4 + r;
            float rr = sigm(accr[mt][ct][r] + birv[ct]);
            float zz = sigm(accz[mt][ct][r] + bizv[ct]);
            float nn = tanh_f(accxn[mt][ct][r] + binv[ct] + rr*(acchn[mt][ct][r]+bhnv[ct]));
            float ho = hf[rl*64 + ct*16 + lr];
            float hv = (1.f-zz)*nn + zz*ho;
            float h2 = mk[mt][r] ? hv : ho;
            hf[rl*64 + ct*16 + lr] = h2;
            stg_coh_pair(hbN + ((size_t)(rb*128+rl)*HE + (d & ~1)), lr, h2);
            if (t == 127) hTf[(size_t)(rb*128+rl)*HE + d] = h2;
          }
      }
      __syncthreads();   // drains state stores before counter bump
      if (tid == 0) cntbump(cL0);
    }
  } else if (bid < 96){
    // ---- LAYER1 ----
    const int id = bid - 32, rb = id >> 3, cb = id & 7;
    int* cL0 = cntp(ws, rb);
    int* cL1 = cntp(ws, 8+rb);
    int* cM  = cntp(ws, 16+rb);
    short* wsm = (short*)smem;
    float* hf  = (float*)(smem + 98304);
    const short* WX = (const short*)(ws + wsoff::WIH1);
    const short* WHs= (const short*)(ws + wsoff::WHH1);
    for (int idx = tid; idx < 96*512; idx += 256){
      int u = idx >> 9, le = idx & 511, ln = le >> 3, j = le & 7, lrr = ln & 15, qq = ln >> 4;
      int g = u / 32, rem = u % 32, ct = rem >> 4, kb = rem & 15;
      int row = g*HE + cb*32 + ct*16 + lrr;
      wsm[idx] = (kb < 8) ? WX [(size_t)row*256 + kb*32 + qq*8 + j]
                          : WHs[(size_t)row*256 + (kb-8)*32 + qq*8 + j];
    }
    for (int idx = tid; idx < 128*32; idx += 256) hf[idx] = 0.f;
    const float* bih = f32p(ws,wsoff::BIH1);
    const float* bhh = f32p(ws,wsoff::BHH1);
    float birv[2], bizv[2], binv[2], bhnv[2];
    #pragma unroll
    for (int ct=0;ct<2;ct++){
      int d = cb*32 + ct*16 + lr;
      birv[ct]=bih[d]+bhh[d]; bizv[ct]=bih[HE+d]+bhh[HE+d];
      binv[ct]=bih[2*HE+d];   bhnv[ct]=bhh[2*HE+d];
    }
    __syncthreads();
    const int rowloc = w*32, rowg = rb*128 + rowloc;
    float* hTf = f32p(ws, wsoff::H1F0);
    for (int s = 0; s < 128; ++s){
      if (tid == 0){
        pollge(cL0, 4*(s+1));
        pollge(cL1, 8*s);
        if (s >= 4) pollge(cM, 2*(s-3));
      }
      __syncthreads();
      const bf16* Ax = H0Bb(ws, s&3);
      const bf16* Ah = H1Bb(ws, (s+3)&3);
      bf16* hbN = H1Bb(ws, s&3);
      v8s Ax0[8], Ax1[8], Ah0[8], Ah1[8];
      #pragma unroll
      for (int kb=0;kb<8;kb++){
        Ax0[kb] = ldg_coh16(Ax + (size_t)(rowg+lr)*HE + kb*32 + q*8);
        Ax1[kb] = ldg_coh16(Ax + (size_t)(rowg+16+lr)*HE + kb*32 + q*8);
        Ah0[kb] = ldg_coh16(Ah + (size_t)(rowg+lr)*HE + kb*32 + q*8);
        Ah1[kb] = ldg_coh16(Ah + (size_t)(rowg+16+lr)*HE + kb*32 + q*8);
      }
      v4f accr[2][2], accz[2][2], accxn[2][2], acchn[2][2];
      #pragma unroll
      for (int mt=0;mt<2;mt++)
        #pragma unroll
        for (int ct=0;ct<2;ct++){
          accr[mt][ct]=(v4f){0,0,0,0}; accz[mt][ct]=(v4f){0,0,0,0};
          accxn[mt][ct]=(v4f){0,0,0,0}; acchn[mt][ct]=(v4f){0,0,0,0};
        }
      #pragma unroll
      for (int kb=0;kb<8;kb++){
        #pragma unroll
        for (int g=0;g<3;g++)
          #pragma unroll
          for (int ct=0;ct<2;ct++){
            v8s bx = ldsfrag(wsm, (g*2+ct)*16 + kb, lane);
            v8s bh = ldsfrag(wsm, (g*2+ct)*16 + 8 + kb, lane);
            v4f* X0 = (g==0)?&accr[0][ct]:(g==1)?&accz[0][ct]:&accxn[0][ct];
            v4f* X1 = (g==0)?&accr[1][ct]:(g==1)?&accz[1][ct]:&accxn[1][ct];
            v4f* H0v= (g==0)?&accr[0][ct]:(g==1)?&accz[0][ct]:&acchn[0][ct];
            v4f* H1v= (g==0)?&accr[1][ct]:(g==1)?&accz[1][ct]:&acchn[1][ct];
            *X0 = mfma16(Ax0[kb],bx,*X0); *X1 = mfma16(Ax1[kb],bx,*X1);
            *H0v= mfma16(Ah0[kb],bh,*H0v); *H1v= mfma16(Ah1[kb],bh,*H1v);
          }
      }
      int mk[2][4];
      #pragma unroll
      for (int mt=0;mt<2;mt++)
        #pragma unroll
        for (int r=0;r<4;r++)
          mk[mt][r] = maskT[(size_t)s*NB + rowg + mt*16 + q*4 + r];
      #pragma unroll
      for (int ct=0;ct<2;ct++){
        const int d = cb*32 + ct*16 + lr;
        #pragma unroll
        for (int mt=0;mt<2;mt++)
          #pragma unroll
          for (int r=0;r<4;r++){
            const int rl = rowloc + mt*16 + q*4 + r;
            float rr = sigm(accr[mt][ct][r] + birv[ct]);
            float zz = sigm(accz[mt][ct][r] + bizv[ct]);
            float nn = tanh_f(accxn[mt][ct][r] + binv[ct] + rr*(acchn[mt][ct][r]+bhnv[ct]));
            float ho = hf[rl*32 + ct*16 + lr];
            float hv = (1.f-zz)*nn + zz*ho;
            float h2 = mk[mt][r] ? hv : ho;
            hf[rl*32 + ct*16 + lr] = h2;
            stg_coh_pair(hbN + ((size_t)(rb*128+rl)*HE + (d & ~1)), lr, h2);
            if (s == 127) hTf[(size_t)(rb*128+rl)*HE + d] = h2;
          }
      }
      __syncthreads();
      if (tid == 0) cntbump(cL1);
    }
  } else {
    // ---- MLP ----
    const int mb = bid - 96, rb = mb >> 1;
    int* cL1 = cntp(ws, 8+rb);
    int* cM  = cntp(ws, 16+rb);
    short* wsm = (short*)smem;
    const short* W1s = (const short*)(ws + wsoff::W1B);
    for (int idx = tid; idx < 16*512; idx += 256){
      int u = idx >> 9, le = idx & 511, ln = le >> 3, j = le & 7, lrr = ln & 15, qq = ln >> 4;
      int c = u >> 2, kb = u & 3;
      wsm[idx] = W1s[(size_t)(c*16 + lrr)*NH + kb*32 + qq*8 + j];
    }
    float b1v[4], w20[4], w21[4];
    const float* B1 = f32p(ws,wsoff::B1F);
    const float* W2 = f32p(ws,wsoff::W2F);
    const float* B2 = f32p(ws,wsoff::B2F);
    #pragma unroll
    for (int c=0;c<4;c++){ int col=c*16+lr; b1v[c]=B1[col]; w20[c]=W2[col]; w21[c]=W2[64+col]; }
    const float b20 = B2[0], b21 = B2[1];
    __syncthreads();
    const int rowbase = mb*64 + w*16, rowA = rowbase + lr;
    for (int s = 0; s < 128; ++s){
      if (tid == 0) pollge(cL1, 8*(s+1));
      __syncthreads();
      const bf16* A = H1Bb(ws, s&3);
      const bool valid = maskT[(size_t)s*NB + rowA] != 0;
      v8s af[4];
      #pragma unroll
      for (int kb=0;kb<4;kb++)
        af[kb] = valid ? ldg_coh16(A + (size_t)rowA*HE + kb*32 + q*8) : (v8s){0,0,0,0,0,0,0,0};
      v4f acc[4];
      #pragma unroll
      for (int c=0;c<4;c++) acc[c]=(v4f){0,0,0,0};
      #pragma unroll
      for (int kb=0;kb<4;kb++)
        #pragma unroll
        for (int c=0;c<4;c++)
          acc[c] = mfma16(af[kb], ldsfrag(wsm, c*4 + kb, lane), acc[c]);
      float* outp = f32p(ws,wsoff::ENCP) + (size_t)s*NB*2;
      #pragma unroll
      for (int r=0;r<4;r++){
        float p0 = 0.f, p1 = 0.f;
        #pragma unroll
        for (int c=0;c<4;c++){
          float hv = acc[c][r] + b1v[c]; hv = hv>0.f ? hv : 0.f;
          p0 += hv*w20[c]; p1 += hv*w21[c];
        }
        #pragma unroll
        for (int m=1;m<16;m<<=1){ p0 += __shfl_xor(p0,m,64); p1 += __shfl_xor(p1,m,64); }
        if (lr == 0){
          const int grow = rowbase + q*4 + r;
          outp[(size_t)grow*2]   = softplusf(p0+b20);
          outp[(size_t)grow*2+1] = softplusf(p1+b21);
        }
      }
      __syncthreads();
      if (tid == 0) cntbump(cM);
    }
  }
}

// ================= decoder: 8 waves + VALU tail for cols 128..131 =================
__global__ __launch_bounds__(512,1) void k_decoder(char* ws, const void* eps, const void* feat, void* out){
  extern __shared__ __align__(16) char dsm[];
  short* s_h0b = (short*)dsm;                       // [32][HDS]      @0      10496
  short* s_h1b = s_h0b + 32*HDS;                    //                @10496  10496
  float* s_inp = (float*)(dsm + 20992);             // [64]           @20992  256
  float* s_red = (float*)(dsm + 21248);             // [128]          @21248  512
  short* s_wh  = (short*)(dsm + 21760);             // WH1 t0..7 frag @21760  122880
  short* s_cw0 = (short*)(dsm + 144640);            // [3][4][132]    @144640 3168
  short* s_cwx = (short*)(dsm + 147808);            //                        3168
  short* s_cwh = (short*)(dsm + 150976);            //                        3168
  float* s_tail= (float*)(dsm + 154144);            // [512]                  2048
  float* s_th  = (float*)(dsm + 156192);            // [2][32][4]             1024
  float* s_tt0 = (float*)(dsm + 157216);            // [4][10]                160
  float* s_tt1 = (float*)(dsm + 157376);            // [4][4]                 64

  const int isbf = *(const int*)(ws+wsoff::FLAG);
  const int tid = threadIdx.x;
  const int lane = tid & 63, w = tid >> 6, lr = lane & 15, q = lane >> 4;
  const int rowbase = blockIdx.x*32;
  constexpr size_t N0v = (size_t)NS*NB*127*2;

  const bf16* W0g  = bfp(ws,wsoff::WDHH0);
  const bf16* WX1g = bfp(ws,wsoff::WDIH1);

  // ---- phase A: zero + LDS staging ----
  for (int i = tid; i < 2*32*HDS; i += 512) s_h0b[i] = 0;
  {
    const short* src = (const short*)(ws + wsoff::WDHH1);
    for (int idx = tid; idx < 120*512; idx += 512){
      int u = idx >> 9, le = idx & 511, ln = le >> 3, e = le & 7, lrr = ln & 15, qq = ln >> 4;
      int kb = u % 5, t2 = u / 5, cc = t2 & 7, g = t2 >> 3;
      s_wh[idx] = src[(size_t)(g*GDP + cc*16 + lrr)*HDP + kb*32 + qq*8 + e];
    }
    const short* g0 = (const short*)(ws + wsoff::WDHH0);
    const short* gx = (const short*)(ws + wsoff::WDIH1);
    const short* gh = (const short*)(ws + wsoff::WDHH1);
    for (int i = tid; i < 3*4*132; i += 512){
      int k = i % 132, t2 = i / 132, c4 = t2 & 3, g = t2 >> 2;
      size_t so = (size_t)(g*GDP + 128 + c4)*HDP + k;
      s_cw0[i] = g0[so]; s_cwx[i] = gx[so]; s_cwh[i] = gh[so];
    }
  }
  if (tid < 4){
    const float* wih = f32p(ws,wsoff::WDIH0F);
    const float* bi0 = f32p(ws,wsoff::BDIH0); const float* bh0 = f32p(ws,wsoff::BDHH0);
    const float* bi1 = f32p(ws,wsoff::BDIH1); const float* bh1 = f32p(ws,wsoff::BDHH1);
    int dd = 128 + tid;
    float* T = s_tt0 + tid*10;
    T[0]=wih[(0*HD+dd)*2]; T[1]=wih[(0*HD+dd)*2+1];
    T[2]=wih[(1*HD+dd)*2]; T[3]=wih[(1*HD+dd)*2+1];
    T[4]=wih[(2*HD+dd)*2]; T[5]=wih[(2*HD+dd)*2+1];
    T[6]=bi0[dd]+bh0[dd]; T[7]=bi0[HD+dd]+bh0[HD+dd]; T[8]=bi0[2*HD+dd]; T[9]=bh0[2*HD+dd];
    float* T1 = s_tt1 + tid*4;
    T1[0]=bi1[dd]+bh1[dd]; T1[1]=bi1[HD+dd]+bh1[HD+dd]; T1[2]=bi1[2*HD+dd]; T1[3]=bh1[2*HD+dd];
  }
  if (tid < 64){
    int r0 = tid >> 1, c = tid & 1;
    int b = (rowbase + r0) & 1023;
    float v = f32p(ws,wsoff::ENCP)[((size_t)127*NB + b)*2 + c];
    s_inp[tid] = v;
    st_out(out, N0v + ((size_t)(rowbase+r0)*64)*2 + c, v, isbf);
  }
  __syncthreads();

  // ---- phase B: per-thread state init + RF weights ----
  const int d = w*16 + lr;   // always < 128
  float e0a[10], e1a[4];
  {
    const float* wih = f32p(ws,wsoff::WDIH0F);
    const float* bi0 = f32p(ws,wsoff::BDIH0); const float* bh0 = f32p(ws,wsoff::BDHH0);
    const float* bi1 = f32p(ws,wsoff::BDIH1); const float* bh1 = f32p(ws,wsoff::BDHH1);
    e0a[0]=wih[(0*HD+d)*2]; e0a[1]=wih[(0*HD+d)*2+1];
    e0a[2]=wih[(1*HD+d)*2]; e0a[3]=wih[(1*HD+d)*2+1];
    e0a[4]=wih[(2*HD+d)*2]; e0a[5]=wih[(2*HD+d)*2+1];
    e0a[6]=bi0[d]+bh0[d]; e0a[7]=bi0[HD+d]+bh0[HD+d]; e0a[8]=bi0[2*HD+d]; e0a[9]=bh0[2*HD+d];
    e1a[0]=bi1[d]+bh1[d]; e1a[1]=bi1[HD+d]+bh1[HD+d]; e1a[2]=bi1[2*HD+d]; e1a[3]=bh1[2*HD+d];
  }
  float h0a[2][4], h1a[2][4];
  {
    const float* h0T = f32p(ws,wsoff::H0F0);
    const float* h1T = f32p(ws,wsoff::H1F0);
    #pragma unroll
    for (int m=0;m<2;m++)
      #pragma unroll
      for (int r=0;r<4;r++){
        int row = m*16 + q*4 + r, grow = rowbase + row;
        int s = grow >> 10, b = grow & 1023;
        float e0 = ld_any(eps, ((size_t)(s*2+0)*NB + b)*NH + d, isbf);
        float e1 = ld_any(eps, ((size_t)(s*2+1)*NB + b)*NH + d, isbf);
        float v0 = e0*__expf(0.5f*h0T[(size_t)b*HE + NH + d]) + h0T[(size_t)b*HE + d];
        float v1 = e1*__expf(0.5f*h1T[(size_t)b*HE + NH + d]) + h1T[(size_t)b*HE + d];
        h0a[m][r] = v0; h1a[m][r] = v1;
        s_h0b[row*HDS + d] = bf16bits(v0);
        s_h1b[row*HDS + d] = bf16bits(v1);
      }
  }
  if (tid < 128){
    int c4 = tid >> 5, row = tid & 31;
    int b = (rowbase + row) & 1023;
    float fc = ld_any(feat, (size_t)b*3072 + 2048 + c4, isbf);
    s_th[row*4 + c4] = fc;
    s_th[128 + row*4 + c4] = fc;
    s_h0b[row*HDS + 128 + c4] = bf16bits(fc);
    s_h1b[row*HDS + 128 + c4] = bf16bits(fc);
  }
  v8s w0f[3][5], wxf[3][5];
  #pragma unroll
  for (int g=0;g<3;g++)
    #pragma unroll
    for (int kb=0;kb<5;kb++){
      size_t off = (size_t)(g*GDP + w*16 + lr)*HDP + kb*32 + q*8;
      w0f[g][kb] = fragld(W0g, off);
      wxf[g][kb] = fragld(WX1g, off);
    }
  v8s w1f[2][4]; float b1v[2], w20v[2], w21v[2];
  if (w == 5 || w == 6){
    const int tb = (w-5)*2;
    const bf16* W1g = bfp(ws,wsoff::W1B);
    #pragma unroll
    for (int ct=0;ct<2;ct++){
      #pragma unroll
      for (int kb=0;kb<4;kb++)
        w1f[ct][kb] = fragld(W1g, (size_t)((tb+ct)*16+lr)*NH + kb*32 + q*8);
      b1v[ct]  = f32p(ws,wsoff::B1F)[(tb+ct)*16+lr];
      w20v[ct] = f32p(ws,wsoff::W2F)[(tb+ct)*16+lr];
      w21v[ct] = f32p(ws,wsoff::W2F)[64+(tb+ct)*16+lr];
    }
  }
  const float b20 = f32p(ws,wsoff::B2F)[0], b21 = f32p(ws,wsoff::B2F)[1];
  __syncthreads();

  const int ttg = tid >> 7, ttc4 = (tid >> 5) & 3, ttrow = tid & 31;
  for (int k = 0; k < 63; ++k){
    // ---- P1: main MFMA + tail dots (read s_h0b old) ----
    v4f p1[3][2];
    #pragma unroll
    for (int g=0;g<3;g++){ p1[g][0]=(v4f){0,0,0,0}; p1[g][1]=(v4f){0,0,0,0}; }
    #pragma unroll
    for (int m=0;m<2;m++)
      #pragma unroll
      for (int kb=0;kb<5;kb++){
        v8s A = lds_frag8(s_h0b + (m*16+lr)*HDS + kb*32 + q*8);
        #pragma unroll
        for (int g=0;g<3;g++) p1[g][m] = mfma16(A, w0f[g][kb], p1[g][m]);
      }
    if (tid < 384){
      const unsigned* st = (const unsigned*)s_h0b + ttrow*(HDS/2);
      const unsigned* wp = (const unsigned*)s_cw0 + (ttg*4+ttc4)*66;
      float td = 0.f;
      #pragma unroll 2
      for (int k2 = 0; k2 < 66; ++k2){
        unsigned sv = st[k2], wv = wp[k2];
        td += uasf(sv<<16)*uasf(wv<<16) + uasf(sv & 0xffff0000u)*uasf(wv & 0xffff0000u);
      }
      s_tail[(ttg*4+ttc4)*32 + ttrow] = td;
    }
    __syncthreads();
    // ---- P1 epilogue (write s_h0b new) ----
    #pragma unroll
    for (int m=0;m<2;m++)
      #pragma unroll
      for (int r=0;r<4;r++){
        int row = m*16 + q*4 + r;
        float i0 = s_inp[row*2], i1 = s_inp[row*2+1];
        float rr = sigm(i0*e0a[0]+i1*e0a[1] + p1[0][m][r] + e0a[6]);
        float zz = sigm(i0*e0a[2]+i1*e0a[3] + p1[1][m][r] + e0a[7]);
        float nn = tanh_f(i0*e0a[4]+i1*e0a[5] + e0a[8] + rr*(p1[2][m][r] + e0a[9]));
        float h = (1.f-zz)*nn + zz*h0a[m][r];
        h0a[m][r] = h;
        s_h0b[row*HDS + d] = bf16bits(h);
      }
    if (tid < 128){
      int c4 = tid >> 5, row = tid & 31;
      float ar = s_tail[(0*4+c4)*32+row], az = s_tail[(1*4+c4)*32+row], an = s_tail[(2*4+c4)*32+row];
      const float* T = s_tt0 + c4*10;
      float i0 = s_inp[row*2], i1 = s_inp[row*2+1];
      float rr = sigm(i0*T[0]+i1*T[1] + ar + T[6]);
      float zz = sigm(i0*T[2]+i1*T[3] + az + T[7]);
      float nn = tanh_f(i0*T[4]+i1*T[5] + T[8] + rr*(an + T[9]));
      float ho = s_th[row*4 + c4];
      float h = (1.f-zz)*nn + zz*ho;
      s_th[row*4 + c4] = h;
      s_h0b[row*HDS + 128 + c4] = bf16bits(h);
    }
    __syncthreads();
    // ---- P2: main MFMA + tail dots (read s_h0b new, s_h1b old) ----
    v4f p2[4][2];
    #pragma unroll
    for (int g=0;g<4;g++){ p2[g][0]=(v4f){0,0,0,0}; p2[g][1]=(v4f){0,0,0,0}; }
    #pragma unroll
    for (int m=0;m<2;m++)
      #pragma unroll
      for (int kb=0;kb<5;kb++){
        v8s ax = lds_frag8(s_h0b + (m*16+lr)*HDS + kb*32 + q*8);
        v8s ah = lds_frag8(s_h1b + (m*16+lr)*HDS + kb*32 + q*8);
        #pragma unroll
        for (int g=0;g<3;g++){
          int aix = (g==2) ? 2 : g, aih = (g==2) ? 3 : g;
          p2[aix][m] = mfma16(ax, wxf[g][kb], p2[aix][m]);
          p2[aih][m] = mfma16(ah, ldsfrag(s_wh, (g*8+w)*5 + kb, lane), p2[aih][m]);
        }
      }
    {
      const unsigned* h0p = (const unsigned*)s_h0b + ttrow*(HDS/2);
      const unsigned* h1p = (const unsigned*)s_h1b + ttrow*(HDS/2);
      float td = 0.f;
      if (ttg <= 1){
        const unsigned* wx = (const unsigned*)s_cwx + (ttg*4+ttc4)*66;
        const unsigned* wh = (const unsigned*)s_cwh + (ttg*4+ttc4)*66;
        #pragma unroll 2
        for (int k2 = 0; k2 < 66; ++k2){
          unsigned sv = h0p[k2], wv = wx[k2];
          td += uasf(sv<<16)*uasf(wv<<16) + uasf(sv & 0xffff0000u)*uasf(wv & 0xffff0000u);
          unsigned sh = h1p[k2], wh2 = wh[k2];
          td += uasf(sh<<16)*uasf(wh2<<16) + uasf(sh & 0xffff0000u)*uasf(wh2 & 0xffff0000u);
        }
      } else if (ttg == 2){
        const unsigned* wx = (const unsigned*)s_cwx + (2*4+ttc4)*66;
        #pragma unroll 2
        for (int k2 = 0; k2 < 66; ++k2){
          unsigned sv = h0p[k2], wv = wx[k2];
          td += uasf(sv<<16)*uasf(wv<<16) + uasf(sv & 0xffff0000u)*uasf(wv & 0xffff0000u);
        }
      } else {
        const unsigned* wh = (const unsigned*)s_cwh + (2*4+ttc4)*66;
        #pragma unroll 2
        for (int k2 = 0; k2 < 66; ++k2){
          unsigned sv = h1p[k2], wv = wh[k2];
          td += uasf(sv<<16)*uasf(wv<<16) + uasf(sv & 0xffff0000u)*uasf(wv & 0xffff0000u);
        }
      }
      s_tail[(ttg*4+ttc4)*32 + ttrow] = td;
    }
    __syncthreads();
    // ---- P2 epilogue (write s_h1b new) ----
    #pragma unroll
    for (int m=0;m<2;m++)
      #pragma unroll
      for (int r=0;r<4;r++){
        int row = m*16 + q*4 + r;
        float rr = sigm(p2[0][m][r] + e1a[0]);
        float zz = sigm(p2[1][m][r] + e1a[1]);
        float nn = tanh_f(p2[2][m][r] + e1a[2] + rr*(p2[3][m][r] + e1a[3]));
        float h = (1.f-zz)*nn + zz*h1a[m][r];
        h1a[m][r] = h;
        s_h1b[row*HDS + d] = bf16bits(h);
      }
    if (tid < 128){
      int c4 = tid >> 5, row = tid & 31;
      float tr = s_tail[(0*4+c4)*32+row], tz = s_tail[(1*4+c4)*32+row];
      float txn = s_tail[(2*4+c4)*32+row], thn = s_tail[(3*4+c4)*32+row];
      const float* T1 = s_tt1 + c4*4;
      float rr = sigm(tr + T1[0]);
      float zz = sigm(tz + T1[1]);
      float nn = tanh_f(txn + T1[2] + rr*(thn + T1[3]));
      float ho = s_th[128 + row*4 + c4];
      float h = (1.f-zz)*nn + zz*ho;
      s_th[128 + row*4 + c4] = h;
      s_h1b[row*HDS + 128 + c4] = bf16bits(h);
    }
    __syncthreads();
    // ---- P3: MLP halves on waves 5,6 ----
    if (w == 5 || w == 6){
      v4f a3[2][2];
      #pragma unroll
      for (int ct=0;ct<2;ct++){ a3[ct][0]=(v4f){0,0,0,0}; a3[ct][1]=(v4f){0,0,0,0}; }
      #pragma unroll
      for (int m=0;m<2;m++)
        #pragma unroll
        for (int kb=0;kb<4;kb++){
          v8s A = lds_frag8(s_h1b + (m*16+lr)*HDS + kb*32 + q*8);
          #pragma unroll
          for (int ct=0;ct<2;ct++) a3[ct][m] = mfma16(A, w1f[ct][kb], a3[ct][m]);
        }
      #pragma unroll
      for (int m=0;m<2;m++)
        #pragma unroll
        for (int r=0;r<4;r++){
          float p0 = 0.f, p1v = 0.f;
          #pragma unroll
          for (int ct=0;ct<2;ct++){
            float hv = a3[ct][m][r] + b1v[ct]; hv = hv > 0.f ? hv : 0.f;
            p0 += hv*w20v[ct]; p1v += hv*w21v[ct];
          }
          #pragma unroll
          for (int mm=1;mm<16;mm<<=1){ p0 += __shfl_xor(p0,mm,64); p1v += __shfl_xor(p1v,mm,64); }
          if (lr == 0){
            int row = m*16 + q*4 + r;
            s_red[(w-5)*64 + row*2]   = p0;
            s_red[(w-5)*64 + row*2+1] = p1v;
          }
        }
    }
    __syncthreads();
    // ---- P4: combine + feedback + out ----
    if (tid < 64){
      int row = tid >> 1, c = tid & 1;
      float p = s_red[row*2 + c] + s_red[64 + row*2 + c];
      float v = softplusf(p + (c ? b21 : b20));
      s_inp[tid] = v;
      st_out(out, N0v + ((size_t)(rowbase+row)*64 + (k+1))*2 + c, v, isbf);
    }
    __syncthreads();
  }
}

// ---------- encoder-part output assembly ----------
__global__ void k_assemble_enc(char* ws, void* out){
  int isbf = *(const int*)(ws+wsoff::FLAG);
  const float* encp = f32p(ws,wsoff::ENCP);
  constexpr size_t N0v = (size_t)NS*NB*127*2;
  for (size_t i = (size_t)blockIdx.x*blockDim.x + threadIdx.x; i < N0v;
       i += (size_t)gridDim.x*blockDim.x){
    int c = (int)(i & 1); size_t qq = i >> 1;
    int tt = (int)(qq % 127); size_t q2 = qq / 127; int b = (int)(q2 & 1023);
    st_out(out, i, encp[((size_t)tt*NB + b)*2 + c], isbf);
  }
}

extern "C" void kernel_launch(void* const* d_in, const int* in_sizes, int n_in,
                              void* d_out, int out_size, void* d_ws, size_t ws_size,
                              hipStream_t stream) {
  char* ws = (char*)d_ws;
  const int* mask = (const int*)d_in[2];
  auto gb = [](size_t n){ return dim3((unsigned)((n + 255)/256)); };

  hipMemsetAsync(ws+wsoff::CNT, 0, 24*64, stream);
  hipMemsetAsync(ws+wsoff::H0B + 3*HBUFSZ, 0, HBUFSZ, stream);
  hipMemsetAsync(ws+wsoff::H1B + 3*HBUFSZ, 0, HBUFSZ, stream);

  k_detect<<<1,64,0,stream>>>(ws, d_in[3]);

  k_stage_xs   <<<gb((size_t)NT*NB*KX),256,0,stream>>>(ws, d_in[0], d_in[1]);
  k_stage_maskT<<<gb((size_t)NT*NB),256,0,stream>>>(ws, mask);
  k_stage_pad<<<gb(768*32) ,256,0,stream>>>(ws, d_in[7],  wsoff::WIH0, 768, 18, 32);
  k_stage_pad<<<gb(768*256),256,0,stream>>>(ws, d_in[8],  wsoff::WHH0, 768, 256, 256);
  k_stage_pad<<<gb(768*256),256,0,stream>>>(ws, d_in[11], wsoff::WIH1, 768, 256, 256);
  k_stage_pad<<<gb(768*256),256,0,stream>>>(ws, d_in[12], wsoff::WHH1, 768, 256, 256);
  k_stage_pad<<<gb(64*128) ,256,0,stream>>>(ws, d_in[23], wsoff::W1B,  64, 128, 128);
  k_stage_dec<<<gb(432*HDP),256,0,stream>>>(ws, d_in[16], wsoff::WDHH0);
  k_stage_dec<<<gb(432*HDP),256,0,stream>>>(ws, d_in[19], wsoff::WDIH1);
  k_stage_dec<<<gb(432*HDP),256,0,stream>>>(ws, d_in[20], wsoff::WDHH1);

  SmallSegs ss;
  const void* srcs[12] = {d_in[9],d_in[10],d_in[13],d_in[14],d_in[15],
                          d_in[17],d_in[18],d_in[21],d_in[22],
                          d_in[24],d_in[25],d_in[26]};
  const size_t offs[12] = {wsoff::BIH0,wsoff::BHH0,wsoff::BIH1,wsoff::BHH1,wsoff::WDIH0F,
                           wsoff::BDIH0,wsoff::BDHH0,wsoff::BDIH1,wsoff::BDHH1,
                           wsoff::B1F,wsoff::W2F,wsoff::B2F};
  const int ns[12] = {768,768,768,768,792,396,396,396,396,64,128,2};
  for (int i=0;i<12;i++){ ss.src[i]=srcs[i]; ss.dstoff[i]=(int)offs[i]; ss.n[i]=ns[i]; }
  k_stage_small<<<12,256,0,stream>>>(ws, ss);

  hipFuncSetAttribute(reinterpret_cast<const void*>(k_encoder),
                      hipFuncAttributeMaxDynamicSharedMemorySize, 143360);
  hipFuncSetAttribute(reinterpret_cast<const void*>(k_decoder),
                      hipFuncAttributeMaxDynamicSharedMemorySize, 157440);

  k_encoder<<<EBLOCKS,256,143360,stream>>>(ws);
  k_decoder<<<256,512,157440,stream>>>(ws, d_in[3], d_in[1], d_out);
  k_assemble_enc<<<2048,256,0,stream>>>(ws, d_out);
}